// Round 2
// baseline (3712.580 us; speedup 1.0000x reference)
//
#include <hip/hip_runtime.h>
#include <hip/hip_bf16.h>

#define N_NODES 20000
#define N_EDGES 320000
#define DIN     256
#define DMODEL  512
#define TD      1536   // 3*D
#define FFD     2048
#define DOUT    128

typedef __hip_bfloat16 bf16;

__device__ __forceinline__ float toF(float v) { return v; }
__device__ __forceinline__ float toF(bf16 v)  { return __bfloat162float(v); }
__device__ __forceinline__ void storeC(float* p, float v) { *p = v; }
__device__ __forceinline__ void storeC(bf16* p, float v)  { *p = __float2bfloat16(v); }

// ---------------------------------------------------------------------------
// Generic GEMM: C = act(A[MxK] @ B[KxN] + bias [+ addmat])
// 64x64 tile, 256 threads, 4x4 micro-tile. K % 16 == 0, N % 64 == 0.
// A: float or bf16.  C: float or bf16.  B/bias/addmat: float.
// ---------------------------------------------------------------------------
template<typename TA, typename TC>
__global__ void gemm_t(const TA* __restrict__ A, const float* __restrict__ B,
                       const float* __restrict__ bias, const float* __restrict__ addmat,
                       TC* __restrict__ C, int M, int N, int K, int doRelu)
{
    __shared__ float As[16][65];   // [k][m]
    __shared__ float Bs[16][65];   // [k][n]
    const int tid = threadIdx.x;
    const int tx = tid & 15, ty = tid >> 4;
    const int m0 = blockIdx.y * 64, n0 = blockIdx.x * 64;
    float acc[4][4] = {};
    const int ar = tid >> 2, ak = (tid & 3) * 4;   // A: row ar, k-chunk ak..ak+3
    const int bk = tid >> 4, bn = (tid & 15) * 4;  // B: k bk, n-chunk bn..bn+3

    for (int k0 = 0; k0 < K; k0 += 16) {
        const int grow = m0 + ar;
        if (grow < M) {
            const TA* ap = A + (size_t)grow * K + k0 + ak;
            #pragma unroll
            for (int i = 0; i < 4; ++i) As[ak + i][ar] = toF(ap[i]);
        } else {
            #pragma unroll
            for (int i = 0; i < 4; ++i) As[ak + i][ar] = 0.f;
        }
        const float* bp = B + (size_t)(k0 + bk) * N + n0 + bn;
        #pragma unroll
        for (int i = 0; i < 4; ++i) Bs[bk][bn + i] = bp[i];
        __syncthreads();
        #pragma unroll
        for (int kk = 0; kk < 16; ++kk) {
            float a[4], b[4];
            #pragma unroll
            for (int i = 0; i < 4; ++i) a[i] = As[kk][ty * 4 + i];
            #pragma unroll
            for (int j = 0; j < 4; ++j) b[j] = Bs[kk][tx * 4 + j];
            #pragma unroll
            for (int i = 0; i < 4; ++i)
                #pragma unroll
                for (int j = 0; j < 4; ++j)
                    acc[i][j] = fmaf(a[i], b[j], acc[i][j]);
        }
        __syncthreads();
    }

    #pragma unroll
    for (int i = 0; i < 4; ++i) {
        const int row = m0 + ty * 4 + i;
        if (row >= M) break;
        TC* cp = C + (size_t)row * N + n0 + tx * 4;
        const float* adp = addmat ? addmat + (size_t)row * N + n0 + tx * 4 : nullptr;
        #pragma unroll
        for (int j = 0; j < 4; ++j) {
            float v = acc[i][j];
            if (bias) v += bias[n0 + tx * 4 + j];
            if (adp) v += adp[j];
            if (doRelu) v = fmaxf(v, 0.f);
            storeC(cp + j, v);
        }
    }
}

// ---------------------------------------------------------------------------
// Inline depthwise conv over node axis (K=5, SAME zero pad, cross-correlation):
// ms[n][c] = sum_t cw[c*5+t] * qkv[n+t-2][c]
// ---------------------------------------------------------------------------
__device__ __forceinline__ float conv5(const bf16* __restrict__ qkv,
                                       const float* __restrict__ cw, int n, int c)
{
    float s = 0.f;
    #pragma unroll
    for (int t = 0; t < 5; ++t) {
        const int nn = n + t - 2;
        if (nn >= 0 && nn < N_NODES)
            s += cw[c * 5 + t] * __bfloat162float(qkv[(size_t)nn * TD + c]);
    }
    return s;
}

// ---------------------------------------------------------------------------
// kv[h,d,e] = sum_n relu(k[n,h,d]) * v1[n,h,e]   (v1[...,8]=1)
// full[n,j] = j<1536 ? qkv[n,j] : conv(qkv)[n,j-1536]
// k: j=h*24+8+d, v: j=h*24+16+d.  Thread owns h=tid>>1, d0=(tid&1)*4, 36 accs.
// ---------------------------------------------------------------------------
__global__ void kvsum_kernel(const bf16* __restrict__ qkv, const float* __restrict__ cw,
                             float* __restrict__ kvg)
{
    __shared__ float kb[1024], vb[1024];
    float acc[36] = {};
    const int tid = threadIdx.x;
    for (int n = blockIdx.x; n < N_NODES; n += gridDim.x) {
        const bf16* qrow = qkv + (size_t)n * TD;
        #pragma unroll
        for (int i = 0; i < 4; ++i) {
            const int idx = tid + i * 256;          // 0..1023 = h*8+d
            const int h = idx >> 3, d = idx & 7;
            float kvl, vvl;
            if (h < 64) {
                kvl = __bfloat162float(qrow[h * 24 + 8 + d]);
                vvl = __bfloat162float(qrow[h * 24 + 16 + d]);
            } else {
                kvl = conv5(qkv, cw, n, (h - 64) * 24 + 8 + d);
                vvl = conv5(qkv, cw, n, (h - 64) * 24 + 16 + d);
            }
            kb[idx] = fmaxf(kvl, 0.f);
            vb[idx] = vvl;
        }
        __syncthreads();
        const int h = tid >> 1, d0 = (tid & 1) * 4;
        #pragma unroll
        for (int dd = 0; dd < 4; ++dd) {
            const float kval = kb[h * 8 + d0 + dd];
            #pragma unroll
            for (int e = 0; e < 9; ++e) {
                const float vv = (e < 8) ? vb[h * 8 + e] : 1.f;
                acc[dd * 9 + e] += kval * vv;
            }
        }
        __syncthreads();
    }
    const int h = tid >> 1, d0 = (tid & 1) * 4;
    #pragma unroll
    for (int dd = 0; dd < 4; ++dd)
        #pragma unroll
        for (int e = 0; e < 9; ++e)
            atomicAdd(&kvg[h * 72 + (d0 + dd) * 9 + e], acc[dd * 9 + e]);
}

// ---------------------------------------------------------------------------
// o[n, h*8+e] = (sum_d q[n,h,d]*kv[h,d,e]) / (sum_d q[n,h,d]*kv[h,d,8] + 1e-15)
// q[n,h,d] = relu(full[n, h*24+d]).  256 threads = 2 nodes x 128 heads.
// ---------------------------------------------------------------------------
__global__ void attn_o_kernel(const bf16* __restrict__ qkv, const float* __restrict__ cw,
                              const float* __restrict__ kvg, bf16* __restrict__ o)
{
    __shared__ float kvs[9216];
    const int tid = threadIdx.x;
    for (int i = tid; i < 9216; i += 256) kvs[i] = kvg[i];
    __syncthreads();
    const int h = tid & 127, sub = tid >> 7;
    for (int nb = blockIdx.x; nb < N_NODES / 2; nb += gridDim.x) {
        const int n = nb * 2 + sub;
        float q[8];
        if (h < 64) {
            const bf16* row = qkv + (size_t)n * TD + h * 24;
            #pragma unroll
            for (int d = 0; d < 8; ++d) q[d] = fmaxf(__bfloat162float(row[d]), 0.f);
        } else {
            const int cb = (h - 64) * 24;
            #pragma unroll
            for (int d = 0; d < 8; ++d) q[d] = fmaxf(conv5(qkv, cw, n, cb + d), 0.f);
        }
        float num[8], den = 0.f;
        #pragma unroll
        for (int e = 0; e < 8; ++e) {
            float s = 0.f;
            #pragma unroll
            for (int d = 0; d < 8; ++d) s += q[d] * kvs[h * 72 + d * 9 + e];
            num[e] = s;
        }
        #pragma unroll
        for (int d = 0; d < 8; ++d) den += q[d] * kvs[h * 72 + d * 9 + 8];
        const float rinv = 1.f / (den + 1e-15f);
        bf16* orow = o + (size_t)n * 1024 + h * 8;
        #pragma unroll
        for (int e = 0; e < 8; ++e) orow[e] = __float2bfloat16(num[e] * rinv);
    }
}

// ---------------------------------------------------------------------------
// out = resid + LN(y)*g + b   (rows of 512, block=256, 2 cols/thread)
// Safe for out == resid (same-index elementwise).
// ---------------------------------------------------------------------------
template<typename TY>
__global__ void ln_res_kernel(const TY* __restrict__ y, const float* __restrict__ resid,
                              const float* __restrict__ g, const float* __restrict__ b,
                              float* __restrict__ out)
{
    const int row = blockIdx.x;
    const int tid = threadIdx.x;
    const TY* yr = y + (size_t)row * DMODEL;
    const float v0 = toF(yr[tid]), v1 = toF(yr[tid + 256]);
    __shared__ float red[4], red2[4];
    float s = v0 + v1;
    #pragma unroll
    for (int o = 32; o > 0; o >>= 1) s += __shfl_down(s, o);
    if ((tid & 63) == 0) red[tid >> 6] = s;
    __syncthreads();
    const float mean = (red[0] + red[1] + red[2] + red[3]) * (1.0f / DMODEL);
    const float d0 = v0 - mean, d1 = v1 - mean;
    float q = d0 * d0 + d1 * d1;
    #pragma unroll
    for (int o = 32; o > 0; o >>= 1) q += __shfl_down(q, o);
    if ((tid & 63) == 0) red2[tid >> 6] = q;
    __syncthreads();
    const float var = (red2[0] + red2[1] + red2[2] + red2[3]) * (1.0f / DMODEL);
    const float inv = rsqrtf(var + 1e-5f);
    const float* rr = resid + (size_t)row * DMODEL;
    float* orow = out + (size_t)row * DMODEL;
    orow[tid]       = rr[tid]       + d0 * inv * g[tid]       + b[tid];
    orow[tid + 256] = rr[tid + 256] + d1 * inv * g[tid + 256] + b[tid + 256];
}

// ---------------------------------------------------------------------------
// Graph normalization + counting sort + aggregation
// ---------------------------------------------------------------------------
__global__ void deg_init_kernel(float* __restrict__ deg)
{
    const int i = blockIdx.x * 256 + threadIdx.x;
    if (i < N_NODES) deg[i] = 1.0f;   // self-loop weight
}

__global__ void deg_acc_kernel(const int* __restrict__ eirow, const float* __restrict__ ea,
                               float* __restrict__ deg)
{
    const int e = blockIdx.x * 256 + threadIdx.x;
    if (e < N_EDGES) atomicAdd(&deg[eirow[e]], ea[e]);
}

__global__ void dis_kernel(const float* __restrict__ deg, float* __restrict__ dis)
{
    const int i = blockIdx.x * 256 + threadIdx.x;
    if (i < N_NODES) dis[i] = rsqrtf(deg[i]);   // deg >= 1 always
}

__global__ void count_kernel(const int* __restrict__ eirow, int* __restrict__ cnt)
{
    const int e = blockIdx.x * 256 + threadIdx.x;
    if (e < N_EDGES) atomicAdd(&cnt[eirow[e]], 1);
}

// Single-block exclusive scan of cnt[0..N) -> rowstart[0..N], cursor copy.
__global__ void scan_kernel(const int* __restrict__ cnt, int* __restrict__ rowstart,
                            int* __restrict__ cursor)
{
    __shared__ int ls[1024];
    const int tid = threadIdx.x;
    const int base = tid * 20;           // 1024*20 = 20480 >= 20000
    int local[20];
    int s = 0;
    #pragma unroll
    for (int i = 0; i < 20; ++i) {
        const int idx = base + i;
        const int v = (idx < N_NODES) ? cnt[idx] : 0;
        local[i] = s;
        s += v;
    }
    ls[tid] = s;
    __syncthreads();
    for (int off = 1; off < 1024; off <<= 1) {
        const int v = (tid >= off) ? ls[tid - off] : 0;
        __syncthreads();
        ls[tid] += v;
        __syncthreads();
    }
    const int excl = (tid == 0) ? 0 : ls[tid - 1];
    #pragma unroll
    for (int i = 0; i < 20; ++i) {
        const int idx = base + i;
        if (idx < N_NODES) {
            const int st = excl + local[i];
            rowstart[idx] = st;
            cursor[idx] = st;
        }
    }
    if (tid == 1023) rowstart[N_NODES] = ls[1023];
}

__global__ void scatter_kernel(const int* __restrict__ eirow, int* __restrict__ cursor,
                               int* __restrict__ sorted)
{
    const int e = blockIdx.x * 256 + threadIdx.x;
    if (e < N_EDGES) {
        const int r = eirow[e];
        const int p = atomicAdd(&cursor[r], 1);
        sorted[p] = e;
    }
}

// One block (256 threads) per destination row; gathers src[col]*nw + self-loop.
// Stores relu(agg).
__global__ void agg_kernel(const float* __restrict__ srcf, const int* __restrict__ eicol,
                           const float* __restrict__ ea, const float* __restrict__ dis,
                           const int* __restrict__ rowstart, const int* __restrict__ sorted,
                           float* __restrict__ agg)
{
    const int i = blockIdx.x;
    const int tid = threadIdx.x;
    float acc0 = 0.f, acc1 = 0.f;
    const float di = dis[i];
    const int s = rowstart[i], epos = rowstart[i + 1];
    for (int p = s; p < epos; ++p) {
        const int e = sorted[p];
        const int c = eicol[e];
        const float w = di * ea[e] * dis[c];
        const float* sr = srcf + (size_t)c * DMODEL;
        acc0 += w * sr[tid];
        acc1 += w * sr[tid + 256];
    }
    const float wself = di * di;
    const float* sr = srcf + (size_t)i * DMODEL;
    acc0 += wself * sr[tid];
    acc1 += wself * sr[tid + 256];
    float* ar = agg + (size_t)i * DMODEL;
    ar[tid]       = fmaxf(acc0, 0.f);
    ar[tid + 256] = fmaxf(acc1, 0.f);
}

// ---------------------------------------------------------------------------
// Workspace layout (bytes). Peak = 145,076,928 (~139 MiB).
// Region lifetimes:
//   [0, 41M)        h (f32, steps 1-6) -> src (steps 6-9, in-place) -> srcf (9-13)
//   [41M, 102.4M)   qkv bf16 (2-5); then src2 bf16 @41M (5-6); ff bf16 @41M (8-9)
//   [61.4M,143.4M)  ffh bf16 (7-8); then agg f32 @61.4M (11-12)
//   [102.4M,143.4M) attn_o bf16 (4-5)
//   [143.4M, ...)   kvg / deg / dis / rs / cur / cnt / sorted
// ---------------------------------------------------------------------------
static constexpr size_t OFF_H    = 0;              // f32 40,960,000
static constexpr size_t OFF_QKV  = 40960000ull;    // bf16 61,440,000
static constexpr size_t OFF_ATTN = 102400000ull;   // bf16 40,960,000
static constexpr size_t OFF_SRC2 = 40960000ull;    // bf16 20,480,000 (alias)
static constexpr size_t OFF_FFH  = 61440000ull;    // bf16 81,920,000 (alias)
static constexpr size_t OFF_FF   = 40960000ull;    // bf16 20,480,000 (alias)
static constexpr size_t OFF_AGG  = 61440000ull;    // f32 40,960,000 (alias)
static constexpr size_t OFF_KV   = 143360000ull;   // 36,864
static constexpr size_t OFF_DEG  = 143396864ull;   // 80,000
static constexpr size_t OFF_DIS  = 143476864ull;   // 80,000
static constexpr size_t OFF_RS   = 143556864ull;   // 80,064 (N+1 ints, padded)
static constexpr size_t OFF_CUR  = 143636928ull;   // 80,000
static constexpr size_t OFF_CNT  = 143716928ull;   // 80,000
static constexpr size_t OFF_SORT = 143796928ull;   // 1,280,000 -> end 145,076,928

extern "C" void kernel_launch(void* const* d_in, const int* in_sizes, int n_in,
                              void* d_out, int out_size, void* d_ws, size_t ws_size,
                              hipStream_t stream)
{
    const float* x      = (const float*)d_in[0];
    const int*   ei     = (const int*)d_in[1];       // (2, E)
    const float* ea     = (const float*)d_in[2];
    const float* pe     = (const float*)d_in[4];
    const float* W_in   = (const float*)d_in[5];
    const float* b_in   = (const float*)d_in[6];
    const float* W_qkv  = (const float*)d_in[7];
    const float* conv_w = (const float*)d_in[8];
    const float* W_proj = (const float*)d_in[9];
    const float* b_proj = (const float*)d_in[10];
    const float* g1     = (const float*)d_in[11];
    const float* beta1  = (const float*)d_in[12];
    const float* W1     = (const float*)d_in[13];
    const float* bf1    = (const float*)d_in[14];
    const float* W2     = (const float*)d_in[15];
    const float* bf2    = (const float*)d_in[16];
    const float* g2     = (const float*)d_in[17];
    const float* beta2  = (const float*)d_in[18];
    const float* W_out  = (const float*)d_in[19];
    const float* b_out  = (const float*)d_in[20];

    char* ws = (char*)d_ws;
    float* h      = (float*)(ws + OFF_H);
    bf16*  qkv    = (bf16*)(ws + OFF_QKV);
    bf16*  attn_o = (bf16*)(ws + OFF_ATTN);
    bf16*  src2   = (bf16*)(ws + OFF_SRC2);
    float* src    = (float*)(ws + OFF_H);      // in-place over h
    bf16*  ffh    = (bf16*)(ws + OFF_FFH);
    bf16*  ff     = (bf16*)(ws + OFF_FF);
    float* srcf   = (float*)(ws + OFF_H);      // in-place over src
    float* agg    = (float*)(ws + OFF_AGG);
    float* kvg    = (float*)(ws + OFF_KV);
    float* deg    = (float*)(ws + OFF_DEG);
    float* dis    = (float*)(ws + OFF_DIS);
    int*   rs     = (int*)(ws + OFF_RS);
    int*   cur    = (int*)(ws + OFF_CUR);
    int*   cnt    = (int*)(ws + OFF_CNT);
    int*   sorted = (int*)(ws + OFF_SORT);
    float* outp   = (float*)d_out;

    const int* eirow = ei;
    const int* eicol = ei + N_EDGES;

    hipMemsetAsync(kvg, 0, 9216 * sizeof(float), stream);
    hipMemsetAsync(cnt, 0, N_NODES * sizeof(int), stream);

    const int MT = (N_NODES + 63) / 64;   // 313

    // 1. h = x@W_in + b_in + pe                                  (f32 -> f32)
    gemm_t<float, float><<<dim3(DMODEL / 64, MT), 256, 0, stream>>>(
        x, W_in, b_in, pe, h, N_NODES, DMODEL, DIN, 0);
    // 2. qkv = h@W_qkv                                           (f32 -> bf16)
    gemm_t<float, bf16><<<dim3(TD / 64, MT), 256, 0, stream>>>(
        h, W_qkv, nullptr, nullptr, qkv, N_NODES, TD, DMODEL, 0);
    // 3. kv sums (conv inline)
    kvsum_kernel<<<256, 256, 0, stream>>>(qkv, conv_w, kvg);
    // 4. per-node attention readout (conv inline) -> attn_o (N x 1024, bf16)
    attn_o_kernel<<<1024, 256, 0, stream>>>(qkv, conv_w, kvg, attn_o);
    // 5. src2 = attn_o@W_proj + b_proj                           (bf16 -> bf16)
    gemm_t<bf16, bf16><<<dim3(DMODEL / 64, MT), 256, 0, stream>>>(
        attn_o, W_proj, b_proj, nullptr, src2, N_NODES, DMODEL, 1024, 0);
    // 6. src = h + LN(src2)   (in-place over h)
    ln_res_kernel<bf16><<<N_NODES, 256, 0, stream>>>(src2, h, g1, beta1, src);
    // 7. ffh = relu(src@W1 + bf1)                                (f32 -> bf16)
    gemm_t<float, bf16><<<dim3(FFD / 64, MT), 256, 0, stream>>>(
        src, W1, bf1, nullptr, ffh, N_NODES, FFD, DMODEL, 1);
    // 8. ff = ffh@W2 + bf2                                       (bf16 -> bf16)
    gemm_t<bf16, bf16><<<dim3(DMODEL / 64, MT), 256, 0, stream>>>(
        ffh, W2, bf2, nullptr, ff, N_NODES, DMODEL, FFD, 0);
    // 9. srcf = src + LN(ff)  (in-place over src)
    ln_res_kernel<bf16><<<N_NODES, 256, 0, stream>>>(ff, src, g2, beta2, srcf);
    // 10. degree / normalization
    deg_init_kernel<<<(N_NODES + 255) / 256, 256, 0, stream>>>(deg);
    deg_acc_kernel<<<(N_EDGES + 255) / 256, 256, 0, stream>>>(eirow, ea, deg);
    dis_kernel<<<(N_NODES + 255) / 256, 256, 0, stream>>>(deg, dis);
    // 11. counting sort of edges by destination row
    count_kernel<<<(N_EDGES + 255) / 256, 256, 0, stream>>>(eirow, cnt);
    scan_kernel<<<1, 1024, 0, stream>>>(cnt, rs, cur);
    scatter_kernel<<<(N_EDGES + 255) / 256, 256, 0, stream>>>(eirow, cur, sorted);
    // 12. aggregation (stores relu(agg))
    agg_kernel<<<N_NODES, 256, 0, stream>>>(srcf, eicol, ea, dis, rs, sorted, agg);
    // 13. out = relu(agg)@W_out + b_out                          (f32 -> f32)
    gemm_t<float, float><<<dim3(DOUT / 64, MT), 256, 0, stream>>>(
        agg, W_out, b_out, nullptr, outp, N_NODES, DOUT, DMODEL, 0);
}

// Round 5
// 1319.993 us; speedup vs baseline: 2.8126x; 2.8126x over previous
//
#include <hip/hip_runtime.h>

#define N_NODES 20000
#define N_EDGES 320000
#define DIN     256
#define DMODEL  512
#define TD      1536   // 3*D
#define FFD     2048
#define DOUT    128

typedef _Float16 f16;
typedef f16 f16x8 __attribute__((ext_vector_type(8)));
typedef float f32x4 __attribute__((ext_vector_type(4)));

__device__ __forceinline__ void cstore(float* p, float v) { *p = v; }
__device__ __forceinline__ void cstore(f16* p, float v)   { *p = (f16)v; }

// ---------------------------------------------------------------------------
// fp16 MFMA GEMM: C = act(A[MxK]f16 @ B + bias [+ addmat]) with B given as
// Bt[N][K] f16 (pre-transposed). 128x128 block tile, BK=32, 4 waves (2x2),
// 64x64 per wave via 4x4 frags of mfma_f32_16x16x32_f16, fp32 accum.
// LDS [row][32] f16 with chunk-XOR swizzle (kc ^= (row>>1)&3) on both sides.
// Requires: K%32==0, N%128==0. M guarded.
// ---------------------------------------------------------------------------
template<typename TC, int HAS_BIAS, int HAS_ADD, int DO_RELU>
__global__ __launch_bounds__(256)
void gemm_mfma(const f16* __restrict__ A, const f16* __restrict__ Bt,
               const float* __restrict__ bias, const float* __restrict__ addmat,
               TC* __restrict__ C, f16* __restrict__ Cbf,
               int M, int N, int K)
{
    __shared__ f16 As[128 * 32];
    __shared__ f16 Bs[128 * 32];
    const int tid  = threadIdx.x;
    const int lane = tid & 63;
    const int wid  = tid >> 6;
    const int wm = wid >> 1, wn = wid & 1;
    const int m0 = blockIdx.y * 128, n0 = blockIdx.x * 128;

    f32x4 acc[4][4];
    #pragma unroll
    for (int i = 0; i < 4; ++i)
        #pragma unroll
        for (int j = 0; j < 4; ++j)
            acc[i][j] = (f32x4)0.0f;

    const int r  = lane & 15;           // fragment row-within-16
    const int kg = lane >> 4;           // k-group 0..3
    const int px = (kg ^ ((r >> 1) & 3)) << 3;   // swizzled chunk (f16 units)

    for (int k0 = 0; k0 < K; k0 += 32) {
        #pragma unroll
        for (int it = 0; it < 2; ++it) {
            const int c   = tid + it * 256;      // 0..511 chunk id
            const int row = c >> 2, kc = c & 3;
            const int widx = row * 32 + ((kc ^ ((row >> 1) & 3)) << 3);
            f16x8 va = {0, 0, 0, 0, 0, 0, 0, 0};
            const int ga = m0 + row;
            if (ga < M) va = *(const f16x8*)(A + (size_t)ga * K + k0 + kc * 8);
            *(f16x8*)(&As[widx]) = va;
            const f16x8 vb = *(const f16x8*)(Bt + (size_t)(n0 + row) * K + k0 + kc * 8);
            *(f16x8*)(&Bs[widx]) = vb;
        }
        __syncthreads();
        f16x8 af[4], bfr[4];
        #pragma unroll
        for (int m = 0; m < 4; ++m)
            af[m] = *(const f16x8*)(&As[(wm * 64 + m * 16 + r) * 32 + px]);
        #pragma unroll
        for (int n = 0; n < 4; ++n)
            bfr[n] = *(const f16x8*)(&Bs[(wn * 64 + n * 16 + r) * 32 + px]);
        #pragma unroll
        for (int m = 0; m < 4; ++m)
            #pragma unroll
            for (int n = 0; n < 4; ++n)
                acc[m][n] = __builtin_amdgcn_mfma_f32_16x16x32_f16(
                    af[m], bfr[n], acc[m][n], 0, 0, 0);
        __syncthreads();
    }

    const int rq = lane >> 4;
    #pragma unroll
    for (int m = 0; m < 4; ++m) {
        #pragma unroll
        for (int rr = 0; rr < 4; ++rr) {
            const int row = m0 + wm * 64 + m * 16 + rq * 4 + rr;
            if (row >= M) continue;
            #pragma unroll
            for (int n = 0; n < 4; ++n) {
                const int col = n0 + wn * 64 + n * 16 + (lane & 15);
                float v = acc[m][n][rr];
                if (HAS_BIAS) v += bias[col];
                if (HAS_ADD)  v += addmat[(size_t)row * N + col];
                if (DO_RELU)  v = fmaxf(v, 0.f);
                cstore(&C[(size_t)row * N + col], v);
                if (Cbf) Cbf[(size_t)row * N + col] = (f16)v;
            }
        }
    }
}

// ---------------------------------------------------------------------------
// Weight transpose+convert: W[K][N] f32 -> Wt[N][K] f16. 32x32 LDS tiles.
// ---------------------------------------------------------------------------
__global__ void wt_kernel(const float* __restrict__ W, f16* __restrict__ Wt, int K, int N)
{
    __shared__ float t[32][33];
    const int k0 = blockIdx.x * 32, n0 = blockIdx.y * 32;
    const int tx = threadIdx.x & 31, ty = threadIdx.x >> 5;   // 256 thr: ty 0..7
    #pragma unroll
    for (int i = ty; i < 32; i += 8) {
        const int k = k0 + i;
        if (k < K && n0 + tx < N) t[i][tx] = W[(size_t)k * N + n0 + tx];
    }
    __syncthreads();
    #pragma unroll
    for (int i = ty; i < 32; i += 8) {
        const int n = n0 + i;
        if (n < N && k0 + tx < K) Wt[(size_t)n * K + k0 + tx] = (f16)t[tx][i];
    }
}

// f32 -> f16 elementwise (n % 4 == 0)
__global__ void f2h_kernel(const float* __restrict__ in, f16* __restrict__ out, int n)
{
    const int i = (blockIdx.x * 256 + threadIdx.x) * 4;
    if (i < n) {
        const float4 v = *(const float4*)(in + i);
        out[i + 0] = (f16)v.x; out[i + 1] = (f16)v.y;
        out[i + 2] = (f16)v.z; out[i + 3] = (f16)v.w;
    }
}

// ---------------------------------------------------------------------------
// Inline depthwise conv over node axis (K=5, SAME zero pad):
// ms[n][c] = sum_t cw[c*5+t] * qkv[n+t-2][c]
// ---------------------------------------------------------------------------
__device__ __forceinline__ float conv5(const f16* __restrict__ qkv,
                                       const float* __restrict__ cw, int n, int c)
{
    float s = 0.f;
    #pragma unroll
    for (int t = 0; t < 5; ++t) {
        const int nn = n + t - 2;
        if (nn >= 0 && nn < N_NODES)
            s += cw[c * 5 + t] * (float)qkv[(size_t)nn * TD + c];
    }
    return s;
}

// ---------------------------------------------------------------------------
// kv[h,d,e] = sum_n relu(k[n,h,d]) * v1[n,h,e]   (v1[...,8]=1)
// ---------------------------------------------------------------------------
__global__ void kvsum_kernel(const f16* __restrict__ qkv, const float* __restrict__ cw,
                             float* __restrict__ kvg)
{
    __shared__ float kb[1024], vb[1024];
    float acc[36] = {};
    const int tid = threadIdx.x;
    for (int n = blockIdx.x; n < N_NODES; n += gridDim.x) {
        const f16* qrow = qkv + (size_t)n * TD;
        #pragma unroll
        for (int i = 0; i < 4; ++i) {
            const int idx = tid + i * 256;          // 0..1023 = h*8+d
            const int h = idx >> 3, d = idx & 7;
            float kvl, vvl;
            if (h < 64) {
                kvl = (float)qrow[h * 24 + 8 + d];
                vvl = (float)qrow[h * 24 + 16 + d];
            } else {
                kvl = conv5(qkv, cw, n, (h - 64) * 24 + 8 + d);
                vvl = conv5(qkv, cw, n, (h - 64) * 24 + 16 + d);
            }
            kb[idx] = fmaxf(kvl, 0.f);
            vb[idx] = vvl;
        }
        __syncthreads();
        const int h = tid >> 1, d0 = (tid & 1) * 4;
        #pragma unroll
        for (int dd = 0; dd < 4; ++dd) {
            const float kval = kb[h * 8 + d0 + dd];
            #pragma unroll
            for (int e = 0; e < 9; ++e) {
                const float vv = (e < 8) ? vb[h * 8 + e] : 1.f;
                acc[dd * 9 + e] += kval * vv;
            }
        }
        __syncthreads();
    }
    const int h = tid >> 1, d0 = (tid & 1) * 4;
    #pragma unroll
    for (int dd = 0; dd < 4; ++dd)
        #pragma unroll
        for (int e = 0; e < 9; ++e)
            atomicAdd(&kvg[h * 72 + (d0 + dd) * 9 + e], acc[dd * 9 + e]);
}

// ---------------------------------------------------------------------------
// o[n, h*8+e] = (sum_d q*kv[h,d,e]) / (sum_d q*kv[h,d,8] + 1e-15)
// ---------------------------------------------------------------------------
__global__ void attn_o_kernel(const f16* __restrict__ qkv, const float* __restrict__ cw,
                              const float* __restrict__ kvg, f16* __restrict__ o)
{
    __shared__ float kvs[9216];
    const int tid = threadIdx.x;
    for (int i = tid; i < 9216; i += 256) kvs[i] = kvg[i];
    __syncthreads();
    const int h = tid & 127, sub = tid >> 7;
    for (int nb = blockIdx.x; nb < N_NODES / 2; nb += gridDim.x) {
        const int n = nb * 2 + sub;
        float q[8];
        if (h < 64) {
            const f16* row = qkv + (size_t)n * TD + h * 24;
            #pragma unroll
            for (int d = 0; d < 8; ++d) q[d] = fmaxf((float)row[d], 0.f);
        } else {
            const int cb = (h - 64) * 24;
            #pragma unroll
            for (int d = 0; d < 8; ++d) q[d] = fmaxf(conv5(qkv, cw, n, cb + d), 0.f);
        }
        float num[8], den = 0.f;
        #pragma unroll
        for (int e = 0; e < 8; ++e) {
            float s = 0.f;
            #pragma unroll
            for (int d = 0; d < 8; ++d) s += q[d] * kvs[h * 72 + d * 9 + e];
            num[e] = s;
        }
        #pragma unroll
        for (int d = 0; d < 8; ++d) den += q[d] * kvs[h * 72 + d * 9 + 8];
        const float rinv = 1.f / (den + 1e-15f);
        f16* orow = o + (size_t)n * 1024 + h * 8;
        #pragma unroll
        for (int e = 0; e < 8; ++e) orow[e] = (f16)(num[e] * rinv);
    }
}

// ---------------------------------------------------------------------------
// out = resid + LN(y)*g + b; optional f16 copy (out_h may alias y: same-index)
// ---------------------------------------------------------------------------
__global__ void ln_res_kernel(const f16* __restrict__ y, const float* __restrict__ resid,
                              const float* __restrict__ g, const float* __restrict__ b,
                              float* __restrict__ out, f16* __restrict__ out_h)
{
    const int row = blockIdx.x;
    const int tid = threadIdx.x;
    const f16* yr = y + (size_t)row * DMODEL;
    const float v0 = (float)yr[tid], v1 = (float)yr[tid + 256];
    __shared__ float red[4], red2[4];
    float s = v0 + v1;
    #pragma unroll
    for (int o = 32; o > 0; o >>= 1) s += __shfl_down(s, o);
    if ((tid & 63) == 0) red[tid >> 6] = s;
    __syncthreads();
    const float mean = (red[0] + red[1] + red[2] + red[3]) * (1.0f / DMODEL);
    const float d0 = v0 - mean, d1 = v1 - mean;
    float q = d0 * d0 + d1 * d1;
    #pragma unroll
    for (int o = 32; o > 0; o >>= 1) q += __shfl_down(q, o);
    if ((tid & 63) == 0) red2[tid >> 6] = q;
    __syncthreads();
    const float var = (red2[0] + red2[1] + red2[2] + red2[3]) * (1.0f / DMODEL);
    const float inv = rsqrtf(var + 1e-5f);
    const float* rr = resid + (size_t)row * DMODEL;
    float* orow = out + (size_t)row * DMODEL;
    const float o0 = rr[tid]       + d0 * inv * g[tid]       + b[tid];
    const float o1 = rr[tid + 256] + d1 * inv * g[tid + 256] + b[tid + 256];
    orow[tid] = o0;
    orow[tid + 256] = o1;
    if (out_h) {
        f16* oh = out_h + (size_t)row * DMODEL;
        oh[tid] = (f16)o0;
        oh[tid + 256] = (f16)o1;
    }
}

// ---------------------------------------------------------------------------
// Graph normalization + counting sort + aggregation
// ---------------------------------------------------------------------------
__global__ void deg_init_kernel(float* __restrict__ deg)
{
    const int i = blockIdx.x * 256 + threadIdx.x;
    if (i < N_NODES) deg[i] = 1.0f;
}

__global__ void deg_acc_kernel(const int* __restrict__ eirow, const float* __restrict__ ea,
                               float* __restrict__ deg)
{
    const int e = blockIdx.x * 256 + threadIdx.x;
    if (e < N_EDGES) atomicAdd(&deg[eirow[e]], ea[e]);
}

__global__ void dis_kernel(const float* __restrict__ deg, float* __restrict__ dis)
{
    const int i = blockIdx.x * 256 + threadIdx.x;
    if (i < N_NODES) dis[i] = rsqrtf(deg[i]);
}

__global__ void count_kernel(const int* __restrict__ eirow, int* __restrict__ cnt)
{
    const int e = blockIdx.x * 256 + threadIdx.x;
    if (e < N_EDGES) atomicAdd(&cnt[eirow[e]], 1);
}

__global__ void scan_kernel(const int* __restrict__ cnt, int* __restrict__ rowstart,
                            int* __restrict__ cursor)
{
    __shared__ int ls[1024];
    const int tid = threadIdx.x;
    const int base = tid * 20;
    int local[20];
    int s = 0;
    #pragma unroll
    for (int i = 0; i < 20; ++i) {
        const int idx = base + i;
        const int v = (idx < N_NODES) ? cnt[idx] : 0;
        local[i] = s;
        s += v;
    }
    ls[tid] = s;
    __syncthreads();
    for (int off = 1; off < 1024; off <<= 1) {
        const int v = (tid >= off) ? ls[tid - off] : 0;
        __syncthreads();
        ls[tid] += v;
        __syncthreads();
    }
    const int excl = (tid == 0) ? 0 : ls[tid - 1];
    #pragma unroll
    for (int i = 0; i < 20; ++i) {
        const int idx = base + i;
        if (idx < N_NODES) {
            const int st = excl + local[i];
            rowstart[idx] = st;
            cursor[idx] = st;
        }
    }
    if (tid == 1023) rowstart[N_NODES] = ls[1023];
}

__global__ void scatter_kernel(const int* __restrict__ eirow, int* __restrict__ cursor,
                               int* __restrict__ sorted)
{
    const int e = blockIdx.x * 256 + threadIdx.x;
    if (e < N_EDGES) {
        const int r = eirow[e];
        const int p = atomicAdd(&cursor[r], 1);
        sorted[p] = e;
    }
}

// One block per dest row; gathers src[col]*nw + self-loop; stores relu as f16.
__global__ void agg_kernel(const float* __restrict__ srcf, const int* __restrict__ eicol,
                           const float* __restrict__ ea, const float* __restrict__ dis,
                           const int* __restrict__ rowstart, const int* __restrict__ sorted,
                           f16* __restrict__ agg)
{
    const int i = blockIdx.x;
    const int tid = threadIdx.x;
    float acc0 = 0.f, acc1 = 0.f;
    const float di = dis[i];
    const int s = rowstart[i], epos = rowstart[i + 1];
    for (int p = s; p < epos; ++p) {
        const int e = sorted[p];
        const int c = eicol[e];
        const float w = di * ea[e] * dis[c];
        const float* sr = srcf + (size_t)c * DMODEL;
        acc0 += w * sr[tid];
        acc1 += w * sr[tid + 256];
    }
    const float wself = di * di;
    const float* sr = srcf + (size_t)i * DMODEL;
    acc0 += wself * sr[tid];
    acc1 += wself * sr[tid + 256];
    f16* ar = agg + (size_t)i * DMODEL;
    ar[tid]       = (f16)fmaxf(acc0, 0.f);
    ar[tid + 256] = (f16)fmaxf(acc1, 0.f);
}

// ---------------------------------------------------------------------------
// Workspace layout (bytes). Peak = 152,285,888 (~145 MiB).
//   [0, 40.96M)       h f32 (1-6) -> src (6-9, in-place) -> srcf (9-13)
//   [40.96M, 102.4M)  qkv f16 (2-5); src2 f16 @40.96M (5-6, ->src_h in-place
//                     6-7); ff f16 @40.96M (8-9)
//   [61.44M, 143.36M) ffh f16 (7-8); agg f16 @61.44M (12-13)
//   [102.4M, 143.36M) x_h (pre-1), h_h @112.64M (1-2), attn_o f16 (4-5)
//   [143.36M, ...)    Wt_* f16, kvg, deg, dis, rs, cur, cnt, sorted
// ---------------------------------------------------------------------------
static constexpr size_t OFF_H     = 0;
static constexpr size_t OFF_QKV   = 40960000ull;
static constexpr size_t OFF_SRC2  = 40960000ull;
static constexpr size_t OFF_FF    = 40960000ull;
static constexpr size_t OFF_FFH   = 61440000ull;
static constexpr size_t OFF_AGG   = 61440000ull;
static constexpr size_t OFF_ATTN  = 102400000ull;
static constexpr size_t OFF_XH    = 102400000ull;
static constexpr size_t OFF_HH    = 112640000ull;
static constexpr size_t WT_IN     = 143360000ull;   //   262,144
static constexpr size_t WT_QKV    = 143622144ull;   // 1,572,864
static constexpr size_t WT_PROJ   = 145195008ull;   // 1,048,576
static constexpr size_t WT_W1     = 146243584ull;   // 2,097,152
static constexpr size_t WT_W2     = 148340736ull;   // 2,097,152
static constexpr size_t WT_OUT    = 150437888ull;   //   131,072
static constexpr size_t OFF_KV    = 150568960ull;   //    36,864
static constexpr size_t OFF_DEG   = 150605824ull;
static constexpr size_t OFF_DIS   = 150685824ull;
static constexpr size_t OFF_RS    = 150765824ull;
static constexpr size_t OFF_CUR   = 150845888ull;
static constexpr size_t OFF_CNT   = 150925888ull;
static constexpr size_t OFF_SORT  = 151005888ull;   // 1,280,000 -> 152,285,888

extern "C" void kernel_launch(void* const* d_in, const int* in_sizes, int n_in,
                              void* d_out, int out_size, void* d_ws, size_t ws_size,
                              hipStream_t stream)
{
    const float* x      = (const float*)d_in[0];
    const int*   ei     = (const int*)d_in[1];
    const float* ea     = (const float*)d_in[2];
    const float* pe     = (const float*)d_in[4];
    const float* W_in   = (const float*)d_in[5];
    const float* b_in   = (const float*)d_in[6];
    const float* W_qkv  = (const float*)d_in[7];
    const float* conv_w = (const float*)d_in[8];
    const float* W_proj = (const float*)d_in[9];
    const float* b_proj = (const float*)d_in[10];
    const float* g1     = (const float*)d_in[11];
    const float* beta1  = (const float*)d_in[12];
    const float* W1     = (const float*)d_in[13];
    const float* bf1    = (const float*)d_in[14];
    const float* W2     = (const float*)d_in[15];
    const float* bf2    = (const float*)d_in[16];
    const float* g2     = (const float*)d_in[17];
    const float* beta2  = (const float*)d_in[18];
    const float* W_out  = (const float*)d_in[19];
    const float* b_out  = (const float*)d_in[20];

    char* ws = (char*)d_ws;
    float* h      = (float*)(ws + OFF_H);
    float* src    = (float*)(ws + OFF_H);
    float* srcf   = (float*)(ws + OFF_H);
    f16*   qkv    = (f16*)(ws + OFF_QKV);
    f16*   src2   = (f16*)(ws + OFF_SRC2);
    f16*   ff     = (f16*)(ws + OFF_FF);
    f16*   ffh    = (f16*)(ws + OFF_FFH);
    f16*   agg    = (f16*)(ws + OFF_AGG);
    f16*   attn_o = (f16*)(ws + OFF_ATTN);
    f16*   x_h    = (f16*)(ws + OFF_XH);
    f16*   h_h    = (f16*)(ws + OFF_HH);
    f16*   wt_in   = (f16*)(ws + WT_IN);
    f16*   wt_qkv  = (f16*)(ws + WT_QKV);
    f16*   wt_proj = (f16*)(ws + WT_PROJ);
    f16*   wt_w1   = (f16*)(ws + WT_W1);
    f16*   wt_w2   = (f16*)(ws + WT_W2);
    f16*   wt_out  = (f16*)(ws + WT_OUT);
    float* kvg    = (float*)(ws + OFF_KV);
    float* deg    = (float*)(ws + OFF_DEG);
    float* dis    = (float*)(ws + OFF_DIS);
    int*   rs     = (int*)(ws + OFF_RS);
    int*   cur    = (int*)(ws + OFF_CUR);
    int*   cnt    = (int*)(ws + OFF_CNT);
    int*   sorted = (int*)(ws + OFF_SORT);
    float* outp   = (float*)d_out;

    const int* eirow = ei;
    const int* eicol = ei + N_EDGES;

    hipMemsetAsync(kvg, 0, 9216 * sizeof(float), stream);
    hipMemsetAsync(cnt, 0, N_NODES * sizeof(int), stream);

    // 0. weight transpose+convert (f32 [K][N] -> f16 [N][K])
    wt_kernel<<<dim3(DIN / 32,   DMODEL / 32), 256, 0, stream>>>(W_in,   wt_in,   DIN,    DMODEL);
    wt_kernel<<<dim3(DMODEL / 32, TD / 32),    256, 0, stream>>>(W_qkv,  wt_qkv,  DMODEL, TD);
    wt_kernel<<<dim3(1024 / 32,  DMODEL / 32), 256, 0, stream>>>(W_proj, wt_proj, 1024,   DMODEL);
    wt_kernel<<<dim3(DMODEL / 32, FFD / 32),   256, 0, stream>>>(W1,     wt_w1,   DMODEL, FFD);
    wt_kernel<<<dim3(FFD / 32,   DMODEL / 32), 256, 0, stream>>>(W2,     wt_w2,   FFD,    DMODEL);
    wt_kernel<<<dim3(DMODEL / 32, DOUT / 32),  256, 0, stream>>>(W_out,  wt_out,  DMODEL, DOUT);
    // 0b. x -> f16
    f2h_kernel<<<(N_NODES * DIN) / 1024, 256, 0, stream>>>(x, x_h, N_NODES * DIN);

    const int GY = (N_NODES + 127) / 128;   // 157

    // 1. h = x@W_in + b_in + pe (f32 out + f16 copy)
    gemm_mfma<float, 1, 1, 0><<<dim3(DMODEL / 128, GY), 256, 0, stream>>>(
        x_h, wt_in, b_in, pe, h, h_h, N_NODES, DMODEL, DIN);
    // 2. qkv = h@W_qkv (f16)
    gemm_mfma<f16, 0, 0, 0><<<dim3(TD / 128, GY), 256, 0, stream>>>(
        h_h, wt_qkv, nullptr, nullptr, qkv, nullptr, N_NODES, TD, DMODEL);
    // 3. kv sums + 4. attention readout (conv inline)
    kvsum_kernel<<<256, 256, 0, stream>>>(qkv, conv_w, kvg);
    attn_o_kernel<<<1024, 256, 0, stream>>>(qkv, conv_w, kvg, attn_o);
    // 5. src2 = attn_o@W_proj + b_proj (f16)
    gemm_mfma<f16, 1, 0, 0><<<dim3(DMODEL / 128, GY), 256, 0, stream>>>(
        attn_o, wt_proj, b_proj, nullptr, src2, nullptr, N_NODES, DMODEL, 1024);
    // 6. src = h + LN(src2)  (f32 in-place over h; f16 in-place over src2)
    ln_res_kernel<<<N_NODES, 256, 0, stream>>>(src2, h, g1, beta1, src, src2);
    // 7. ffh = relu(src@W1 + bf1) (f16)
    gemm_mfma<f16, 1, 0, 1><<<dim3(FFD / 128, GY), 256, 0, stream>>>(
        src2, wt_w1, bf1, nullptr, ffh, nullptr, N_NODES, FFD, DMODEL);
    // 8. ff = ffh@W2 + bf2 (f16)
    gemm_mfma<f16, 1, 0, 0><<<dim3(DMODEL / 128, GY), 256, 0, stream>>>(
        ffh, wt_w2, bf2, nullptr, ff, nullptr, N_NODES, DMODEL, FFD);
    // 9. srcf = src + LN(ff)  (f32 in-place over src)
    ln_res_kernel<<<N_NODES, 256, 0, stream>>>(ff, src, g2, beta2, srcf, nullptr);
    // 10. degree / normalization
    deg_init_kernel<<<(N_NODES + 255) / 256, 256, 0, stream>>>(deg);
    deg_acc_kernel<<<(N_EDGES + 255) / 256, 256, 0, stream>>>(eirow, ea, deg);
    dis_kernel<<<(N_NODES + 255) / 256, 256, 0, stream>>>(deg, dis);
    // 11. counting sort of edges by destination row
    count_kernel<<<(N_EDGES + 255) / 256, 256, 0, stream>>>(eirow, cnt);
    scan_kernel<<<1, 1024, 0, stream>>>(cnt, rs, cur);
    scatter_kernel<<<(N_EDGES + 255) / 256, 256, 0, stream>>>(eirow, cur, sorted);
    // 12. aggregation (stores relu as f16)
    agg_kernel<<<N_NODES, 256, 0, stream>>>(srcf, eicol, ea, dis, rs, sorted, agg);
    // 13. out = relu(agg)@W_out + b_out (f32)
    gemm_mfma<float, 1, 0, 0><<<dim3(DOUT / 128, GY), 256, 0, stream>>>(
        agg, wt_out, b_out, nullptr, outp, nullptr, N_NODES, DOUT, DMODEL);
}

// Round 8
// 1314.321 us; speedup vs baseline: 2.8247x; 1.0043x over previous
//
#include <hip/hip_runtime.h>

#define N_NODES 20000
#define N_EDGES 320000
#define DIN     256
#define DMODEL  512
#define TD      1536   // 3*D
#define FFD     2048
#define DOUT    128

typedef _Float16 f16;
typedef f16 f16x8 __attribute__((ext_vector_type(8)));
typedef float f32x4 __attribute__((ext_vector_type(4)));

__device__ __forceinline__ void cstore(float* p, float v) { *p = v; }
__device__ __forceinline__ void cstore(f16* p, float v)   { *p = (f16)v; }

// ---------------------------------------------------------------------------
// fp16 MFMA GEMM: C = act(A[MxK]f16 @ B + bias [+ addmat]) with B given as
// Bt[N][K] f16 (pre-transposed). 128x128 block tile, BK=32, 4 waves (2x2),
// 64x64 per wave via 4x4 frags of mfma_f32_16x16x32_f16, fp32 accum.
// LDS [row][32] f16 with chunk-XOR swizzle (kc ^= (row>>1)&3) on both sides.
// Requires: K%32==0, N%128==0. M guarded.
// ---------------------------------------------------------------------------
template<typename TC, int HAS_BIAS, int HAS_ADD, int DO_RELU>
__global__ __launch_bounds__(256)
void gemm_mfma(const f16* __restrict__ A, const f16* __restrict__ Bt,
               const float* __restrict__ bias, const float* __restrict__ addmat,
               TC* __restrict__ C, f16* __restrict__ Cbf,
               int M, int N, int K)
{
    __shared__ f16 As[128 * 32];
    __shared__ f16 Bs[128 * 32];
    const int tid  = threadIdx.x;
    const int lane = tid & 63;
    const int wid  = tid >> 6;
    const int wm = wid >> 1, wn = wid & 1;
    const int m0 = blockIdx.y * 128, n0 = blockIdx.x * 128;

    f32x4 acc[4][4];
    #pragma unroll
    for (int i = 0; i < 4; ++i)
        #pragma unroll
        for (int j = 0; j < 4; ++j)
            acc[i][j] = (f32x4)0.0f;

    const int r  = lane & 15;           // fragment row-within-16
    const int kg = lane >> 4;           // k-group 0..3
    const int px = (kg ^ ((r >> 1) & 3)) << 3;   // swizzled chunk (f16 units)

    for (int k0 = 0; k0 < K; k0 += 32) {
        #pragma unroll
        for (int it = 0; it < 2; ++it) {
            const int c   = tid + it * 256;      // 0..511 chunk id
            const int row = c >> 2, kc = c & 3;
            const int widx = row * 32 + ((kc ^ ((row >> 1) & 3)) << 3);
            f16x8 va = {0, 0, 0, 0, 0, 0, 0, 0};
            const int ga = m0 + row;
            if (ga < M) va = *(const f16x8*)(A + (size_t)ga * K + k0 + kc * 8);
            *(f16x8*)(&As[widx]) = va;
            const f16x8 vb = *(const f16x8*)(Bt + (size_t)(n0 + row) * K + k0 + kc * 8);
            *(f16x8*)(&Bs[widx]) = vb;
        }
        __syncthreads();
        f16x8 af[4], bfr[4];
        #pragma unroll
        for (int m = 0; m < 4; ++m)
            af[m] = *(const f16x8*)(&As[(wm * 64 + m * 16 + r) * 32 + px]);
        #pragma unroll
        for (int n = 0; n < 4; ++n)
            bfr[n] = *(const f16x8*)(&Bs[(wn * 64 + n * 16 + r) * 32 + px]);
        #pragma unroll
        for (int m = 0; m < 4; ++m)
            #pragma unroll
            for (int n = 0; n < 4; ++n)
                acc[m][n] = __builtin_amdgcn_mfma_f32_16x16x32_f16(
                    af[m], bfr[n], acc[m][n], 0, 0, 0);
        __syncthreads();
    }

    const int rq = lane >> 4;
    #pragma unroll
    for (int m = 0; m < 4; ++m) {
        #pragma unroll
        for (int rr = 0; rr < 4; ++rr) {
            const int row = m0 + wm * 64 + m * 16 + rq * 4 + rr;
            if (row >= M) continue;
            #pragma unroll
            for (int n = 0; n < 4; ++n) {
                const int col = n0 + wn * 64 + n * 16 + (lane & 15);
                float v = acc[m][n][rr];
                if (HAS_BIAS) v += bias[col];
                if (HAS_ADD)  v += addmat[(size_t)row * N + col];
                if (DO_RELU)  v = fmaxf(v, 0.f);
                cstore(&C[(size_t)row * N + col], v);
                if (Cbf) Cbf[(size_t)row * N + col] = (f16)v;
            }
        }
    }
}

// ---------------------------------------------------------------------------
// Weight transpose+convert: W[K][N] f32 -> Wt[N][K] f16. 32x32 LDS tiles.
// ---------------------------------------------------------------------------
__global__ void wt_kernel(const float* __restrict__ W, f16* __restrict__ Wt, int K, int N)
{
    __shared__ float t[32][33];
    const int k0 = blockIdx.x * 32, n0 = blockIdx.y * 32;
    const int tx = threadIdx.x & 31, ty = threadIdx.x >> 5;   // 256 thr: ty 0..7
    #pragma unroll
    for (int i = ty; i < 32; i += 8) {
        const int k = k0 + i;
        if (k < K && n0 + tx < N) t[i][tx] = W[(size_t)k * N + n0 + tx];
    }
    __syncthreads();
    #pragma unroll
    for (int i = ty; i < 32; i += 8) {
        const int n = n0 + i;
        if (n < N && k0 + tx < K) Wt[(size_t)n * K + k0 + tx] = (f16)t[tx][i];
    }
}

// f32 -> f16 elementwise (n % 4 == 0)
__global__ void f2h_kernel(const float* __restrict__ in, f16* __restrict__ out, int n)
{
    const int i = (blockIdx.x * 256 + threadIdx.x) * 4;
    if (i < n) {
        const float4 v = *(const float4*)(in + i);
        out[i + 0] = (f16)v.x; out[i + 1] = (f16)v.y;
        out[i + 2] = (f16)v.z; out[i + 3] = (f16)v.w;
    }
}

// ---------------------------------------------------------------------------
// Fused conv + kv-sum + q materialization.
// Each block: CHUNK consecutive nodes, rolling 5-row qkv window in LDS.
// full[n,j] = j<1536 ? qkv[n,j] : conv5(qkv)[n,j-1536]; head h: q=full[h*24+d],
// k=full[h*24+8+d], v=full[h*24+16+d].
// kv[h,d,e] += relu(k)*v1 (v1[8]=1), accumulated in regs, atomic at end.
// q_all[n][h*8+d] = relu(q) written f16 (coalesced), consumed by attn_o.
// ---------------------------------------------------------------------------
#define KV_CHUNK 32
__global__ __launch_bounds__(256)
void kv_fused_kernel(const f16* __restrict__ qkv, const float* __restrict__ cw,
                     f16* __restrict__ q_all, float* __restrict__ kvg)
{
    __shared__ f16 rows[5][TD];
    const int tid = threadIdx.x;
    const int n0 = blockIdx.x * KV_CHUNK;

    // preload rows n0-2 .. n0+2
    for (int r = n0 - 2; r <= n0 + 2; ++r) {
        const int slot = ((r % 5) + 5) % 5;
        if (tid < 192) {
            f16x8 v = {0, 0, 0, 0, 0, 0, 0, 0};
            if (r >= 0 && r < N_NODES)
                v = *(const f16x8*)(qkv + (size_t)r * TD + tid * 8);
            *(f16x8*)(&rows[slot][tid * 8]) = v;
        }
    }
    __syncthreads();

    float acc[36] = {};
    const int h = tid >> 1, d0 = (tid & 1) * 4;

    for (int i = 0; i < KV_CHUNK; ++i) {
        const int n = n0 + i;
        // window row pointers (uniform across block)
        const f16* w0 = rows[(((n - 2) % 5) + 5) % 5];
        const f16* w1 = rows[(((n - 1) % 5) + 5) % 5];
        const f16* w2 = rows[n % 5];
        const f16* w3 = rows[(n + 1) % 5];
        const f16* w4 = rows[(n + 2) % 5];

        // ---- kv accumulation (all 256 threads; thread owns (h, d-half)) ----
        float kv4[4], vv[8];
        if (h < 64) {
            const int cb = h * 24;
            #pragma unroll
            for (int dd = 0; dd < 4; ++dd)
                kv4[dd] = fmaxf((float)w2[cb + 8 + d0 + dd], 0.f);
            #pragma unroll
            for (int e = 0; e < 8; ++e)
                vv[e] = (float)w2[cb + 16 + e];
        } else {
            const int cb = (h - 64) * 24;
            #pragma unroll
            for (int dd = 0; dd < 4; ++dd) {
                const int c = cb + 8 + d0 + dd;
                const float s = cw[c*5+0]*(float)w0[c] + cw[c*5+1]*(float)w1[c]
                              + cw[c*5+2]*(float)w2[c] + cw[c*5+3]*(float)w3[c]
                              + cw[c*5+4]*(float)w4[c];
                kv4[dd] = fmaxf(s, 0.f);
            }
            #pragma unroll
            for (int e = 0; e < 8; ++e) {
                const int c = cb + 16 + e;
                vv[e] = cw[c*5+0]*(float)w0[c] + cw[c*5+1]*(float)w1[c]
                      + cw[c*5+2]*(float)w2[c] + cw[c*5+3]*(float)w3[c]
                      + cw[c*5+4]*(float)w4[c];
            }
        }
        #pragma unroll
        for (int dd = 0; dd < 4; ++dd) {
            #pragma unroll
            for (int e = 0; e < 8; ++e)
                acc[dd * 9 + e] = fmaf(kv4[dd], vv[e], acc[dd * 9 + e]);
            acc[dd * 9 + 8] += kv4[dd];
        }

        // ---- q materialization (threads 0..127, head = tid) ----
        if (tid < 128) {
            f16x8 qv;
            if (tid < 64) {
                qv = *(const f16x8*)(&w2[tid * 24]);
                #pragma unroll
                for (int d = 0; d < 8; ++d)
                    qv[d] = qv[d] > (f16)0 ? qv[d] : (f16)0;
            } else {
                const int cb = (tid - 64) * 24;
                #pragma unroll
                for (int d = 0; d < 8; ++d) {
                    const int c = cb + d;
                    const float s = cw[c*5+0]*(float)w0[c] + cw[c*5+1]*(float)w1[c]
                                  + cw[c*5+2]*(float)w2[c] + cw[c*5+3]*(float)w3[c]
                                  + cw[c*5+4]*(float)w4[c];
                    qv[d] = (f16)fmaxf(s, 0.f);
                }
            }
            *(f16x8*)(q_all + (size_t)n * 1024 + tid * 8) = qv;
        }

        __syncthreads();   // row n-2 consumers done
        // load row n+3 into the freed slot
        if (i < KV_CHUNK - 1 && tid < 192) {
            const int r = n + 3;
            const int slot = r % 5;
            f16x8 v = {0, 0, 0, 0, 0, 0, 0, 0};
            if (r < N_NODES)
                v = *(const f16x8*)(qkv + (size_t)r * TD + tid * 8);
            *(f16x8*)(&rows[slot][tid * 8]) = v;
        }
        __syncthreads();
    }

    #pragma unroll
    for (int dd = 0; dd < 4; ++dd)
        #pragma unroll
        for (int e = 0; e < 9; ++e)
            atomicAdd(&kvg[h * 72 + (d0 + dd) * 9 + e], acc[dd * 9 + e]);
}

// ---------------------------------------------------------------------------
// o[n, h*8+e] = (sum_d q*kv[h,d,e]) / (sum_d q*kv[h,d,8] + 1e-15)
// q_all pre-relu'd f16; kv staged transposed in LDS (conflict-free reads).
// o may alias q_all (each (n,h) slot read-then-written by one thread).
// ---------------------------------------------------------------------------
__global__ __launch_bounds__(256)
void attn_o_kernel(const f16* __restrict__ q_all, const float* __restrict__ kvg,
                   f16* __restrict__ o)
{
    __shared__ float kvt[72][128];   // [d*9+e][h]
    const int tid = threadIdx.x;
    for (int i = tid; i < 9216; i += 256) {
        const int hh = i & 127, j = i >> 7;    // j = 0..71
        kvt[j][hh] = kvg[hh * 72 + j];
    }
    __syncthreads();
    const int h = tid & 127, sub = tid >> 7;
    for (int nb = blockIdx.x; nb < N_NODES / 2; nb += gridDim.x) {
        const int n = nb * 2 + sub;
        const f16x8 qv8 = *(const f16x8*)(q_all + (size_t)n * 1024 + h * 8);
        float q[8];
        #pragma unroll
        for (int d = 0; d < 8; ++d) q[d] = (float)qv8[d];
        float num[8], den = 0.f;
        #pragma unroll
        for (int e = 0; e < 8; ++e) {
            float s = 0.f;
            #pragma unroll
            for (int d = 0; d < 8; ++d) s = fmaf(q[d], kvt[d * 9 + e][h], s);
            num[e] = s;
        }
        #pragma unroll
        for (int d = 0; d < 8; ++d) den = fmaf(q[d], kvt[d * 9 + 8][h], den);
        const float rinv = 1.f / (den + 1e-15f);
        f16x8 ov;
        #pragma unroll
        for (int e = 0; e < 8; ++e) ov[e] = (f16)(num[e] * rinv);
        *(f16x8*)(o + (size_t)n * 1024 + h * 8) = ov;
    }
}

// ---------------------------------------------------------------------------
// out = resid + LN(y)*g + b; optional f16 copy (out_h may alias y: same-index)
// ---------------------------------------------------------------------------
__global__ void ln_res_kernel(const f16* __restrict__ y, const float* __restrict__ resid,
                              const float* __restrict__ g, const float* __restrict__ b,
                              float* __restrict__ out, f16* __restrict__ out_h)
{
    const int row = blockIdx.x;
    const int tid = threadIdx.x;
    const f16* yr = y + (size_t)row * DMODEL;
    const float v0 = (float)yr[tid], v1 = (float)yr[tid + 256];
    __shared__ float red[4], red2[4];
    float s = v0 + v1;
    #pragma unroll
    for (int o = 32; o > 0; o >>= 1) s += __shfl_down(s, o);
    if ((tid & 63) == 0) red[tid >> 6] = s;
    __syncthreads();
    const float mean = (red[0] + red[1] + red[2] + red[3]) * (1.0f / DMODEL);
    const float d0 = v0 - mean, d1 = v1 - mean;
    float q = d0 * d0 + d1 * d1;
    #pragma unroll
    for (int o = 32; o > 0; o >>= 1) q += __shfl_down(q, o);
    if ((tid & 63) == 0) red2[tid >> 6] = q;
    __syncthreads();
    const float var = (red2[0] + red2[1] + red2[2] + red2[3]) * (1.0f / DMODEL);
    const float inv = rsqrtf(var + 1e-5f);
    const float* rr = resid + (size_t)row * DMODEL;
    float* orow = out + (size_t)row * DMODEL;
    const float o0 = rr[tid]       + d0 * inv * g[tid]       + b[tid];
    const float o1 = rr[tid + 256] + d1 * inv * g[tid + 256] + b[tid + 256];
    orow[tid] = o0;
    orow[tid + 256] = o1;
    if (out_h) {
        f16* oh = out_h + (size_t)row * DMODEL;
        oh[tid] = (f16)o0;
        oh[tid + 256] = (f16)o1;
    }
}

// ---------------------------------------------------------------------------
// Graph normalization + counting sort + aggregation
// ---------------------------------------------------------------------------
__global__ void deg_init_kernel(float* __restrict__ deg)
{
    const int i = blockIdx.x * 256 + threadIdx.x;
    if (i < N_NODES) deg[i] = 1.0f;
}

__global__ void deg_acc_kernel(const int* __restrict__ eirow, const float* __restrict__ ea,
                               float* __restrict__ deg)
{
    const int e = blockIdx.x * 256 + threadIdx.x;
    if (e < N_EDGES) atomicAdd(&deg[eirow[e]], ea[e]);
}

__global__ void dis_kernel(const float* __restrict__ deg, float* __restrict__ dis)
{
    const int i = blockIdx.x * 256 + threadIdx.x;
    if (i < N_NODES) dis[i] = rsqrtf(deg[i]);
}

__global__ void count_kernel(const int* __restrict__ eirow, int* __restrict__ cnt)
{
    const int e = blockIdx.x * 256 + threadIdx.x;
    if (e < N_EDGES) atomicAdd(&cnt[eirow[e]], 1);
}

__global__ void scan_kernel(const int* __restrict__ cnt, int* __restrict__ rowstart,
                            int* __restrict__ cursor)
{
    __shared__ int ls[1024];
    const int tid = threadIdx.x;
    const int base = tid * 20;
    int local[20];
    int s = 0;
    #pragma unroll
    for (int i = 0; i < 20; ++i) {
        const int idx = base + i;
        const int v = (idx < N_NODES) ? cnt[idx] : 0;
        local[i] = s;
        s += v;
    }
    ls[tid] = s;
    __syncthreads();
    for (int off = 1; off < 1024; off <<= 1) {
        const int v = (tid >= off) ? ls[tid - off] : 0;
        __syncthreads();
        ls[tid] += v;
        __syncthreads();
    }
    const int excl = (tid == 0) ? 0 : ls[tid - 1];
    #pragma unroll
    for (int i = 0; i < 20; ++i) {
        const int idx = base + i;
        if (idx < N_NODES) {
            const int st = excl + local[i];
            rowstart[idx] = st;
            cursor[idx] = st;
        }
    }
    if (tid == 1023) rowstart[N_NODES] = ls[1023];
}

__global__ void scatter_kernel(const int* __restrict__ eirow, int* __restrict__ cursor,
                               int* __restrict__ sorted)
{
    const int e = blockIdx.x * 256 + threadIdx.x;
    if (e < N_EDGES) {
        const int r = eirow[e];
        const int p = atomicAdd(&cursor[r], 1);
        sorted[p] = e;
    }
}

// One block per dest row; gathers src[col]*nw + self-loop; stores relu as f16.
__global__ void agg_kernel(const float* __restrict__ srcf, const int* __restrict__ eicol,
                           const float* __restrict__ ea, const float* __restrict__ dis,
                           const int* __restrict__ rowstart, const int* __restrict__ sorted,
                           f16* __restrict__ agg)
{
    const int i = blockIdx.x;
    const int tid = threadIdx.x;
    float acc0 = 0.f, acc1 = 0.f;
    const float di = dis[i];
    const int s = rowstart[i], epos = rowstart[i + 1];
    for (int p = s; p < epos; ++p) {
        const int e = sorted[p];
        const int c = eicol[e];
        const float w = di * ea[e] * dis[c];
        const float* sr = srcf + (size_t)c * DMODEL;
        acc0 += w * sr[tid];
        acc1 += w * sr[tid + 256];
    }
    const float wself = di * di;
    const float* sr = srcf + (size_t)i * DMODEL;
    acc0 += wself * sr[tid];
    acc1 += wself * sr[tid + 256];
    f16* ar = agg + (size_t)i * DMODEL;
    ar[tid]       = (f16)fmaxf(acc0, 0.f);
    ar[tid + 256] = (f16)fmaxf(acc1, 0.f);
}

// ---------------------------------------------------------------------------
// Workspace layout (bytes). Peak = 152,285,888 (~145 MiB).
//   [0, 40.96M)       h f32 (1-6) -> src (6-9, in-place) -> srcf (9-13)
//   [40.96M, 102.4M)  qkv f16 (2-4); src2 f16 @40.96M (5-6, ->src_h in-place
//                     6-7); ff f16 @40.96M (8-9)
//   [61.44M, 143.36M) ffh f16 (7-8); agg f16 @61.44M (12-13)
//   [102.4M, 143.36M) x_h (pre-1), h_h @112.64M (1-2), q_all f16 (3-4,
//                     overwritten in-place by attn_o output, consumed step 5)
//   [143.36M, ...)    Wt_* f16, kvg, deg, dis, rs, cur, cnt, sorted
// ---------------------------------------------------------------------------
static constexpr size_t OFF_H     = 0;
static constexpr size_t OFF_QKV   = 40960000ull;
static constexpr size_t OFF_SRC2  = 40960000ull;
static constexpr size_t OFF_FF    = 40960000ull;
static constexpr size_t OFF_FFH   = 61440000ull;
static constexpr size_t OFF_AGG   = 61440000ull;
static constexpr size_t OFF_ATTN  = 102400000ull;
static constexpr size_t OFF_XH    = 102400000ull;
static constexpr size_t OFF_HH    = 112640000ull;
static constexpr size_t WT_IN     = 143360000ull;   //   262,144
static constexpr size_t WT_QKV    = 143622144ull;   // 1,572,864
static constexpr size_t WT_PROJ   = 145195008ull;   // 1,048,576
static constexpr size_t WT_W1     = 146243584ull;   // 2,097,152
static constexpr size_t WT_W2     = 148340736ull;   // 2,097,152
static constexpr size_t WT_OUT    = 150437888ull;   //   131,072
static constexpr size_t OFF_KV    = 150568960ull;   //    36,864
static constexpr size_t OFF_DEG   = 150605824ull;
static constexpr size_t OFF_DIS   = 150685824ull;
static constexpr size_t OFF_RS    = 150765824ull;
static constexpr size_t OFF_CUR   = 150845888ull;
static constexpr size_t OFF_CNT   = 150925888ull;
static constexpr size_t OFF_SORT  = 151005888ull;   // 1,280,000 -> 152,285,888

extern "C" void kernel_launch(void* const* d_in, const int* in_sizes, int n_in,
                              void* d_out, int out_size, void* d_ws, size_t ws_size,
                              hipStream_t stream)
{
    const float* x      = (const float*)d_in[0];
    const int*   ei     = (const int*)d_in[1];
    const float* ea     = (const float*)d_in[2];
    const float* pe     = (const float*)d_in[4];
    const float* W_in   = (const float*)d_in[5];
    const float* b_in   = (const float*)d_in[6];
    const float* W_qkv  = (const float*)d_in[7];
    const float* conv_w = (const float*)d_in[8];
    const float* W_proj = (const float*)d_in[9];
    const float* b_proj = (const float*)d_in[10];
    const float* g1     = (const float*)d_in[11];
    const float* beta1  = (const float*)d_in[12];
    const float* W1     = (const float*)d_in[13];
    const float* bf1    = (const float*)d_in[14];
    const float* W2     = (const float*)d_in[15];
    const float* bf2    = (const float*)d_in[16];
    const float* g2     = (const float*)d_in[17];
    const float* beta2  = (const float*)d_in[18];
    const float* W_out  = (const float*)d_in[19];
    const float* b_out  = (const float*)d_in[20];

    char* ws = (char*)d_ws;
    float* h      = (float*)(ws + OFF_H);
    float* src    = (float*)(ws + OFF_H);
    float* srcf   = (float*)(ws + OFF_H);
    f16*   qkv    = (f16*)(ws + OFF_QKV);
    f16*   src2   = (f16*)(ws + OFF_SRC2);
    f16*   ff     = (f16*)(ws + OFF_FF);
    f16*   ffh    = (f16*)(ws + OFF_FFH);
    f16*   agg    = (f16*)(ws + OFF_AGG);
    f16*   q_all  = (f16*)(ws + OFF_ATTN);     // q -> (in-place) attn output
    f16*   x_h    = (f16*)(ws + OFF_XH);
    f16*   h_h    = (f16*)(ws + OFF_HH);
    f16*   wt_in   = (f16*)(ws + WT_IN);
    f16*   wt_qkv  = (f16*)(ws + WT_QKV);
    f16*   wt_proj = (f16*)(ws + WT_PROJ);
    f16*   wt_w1   = (f16*)(ws + WT_W1);
    f16*   wt_w2   = (f16*)(ws + WT_W2);
    f16*   wt_out  = (f16*)(ws + WT_OUT);
    float* kvg    = (float*)(ws + OFF_KV);
    float* deg    = (float*)(ws + OFF_DEG);
    float* dis    = (float*)(ws + OFF_DIS);
    int*   rs     = (int*)(ws + OFF_RS);
    int*   cur    = (int*)(ws + OFF_CUR);
    int*   cnt    = (int*)(ws + OFF_CNT);
    int*   sorted = (int*)(ws + OFF_SORT);
    float* outp   = (float*)d_out;

    const int* eirow = ei;
    const int* eicol = ei + N_EDGES;

    hipMemsetAsync(kvg, 0, 9216 * sizeof(float), stream);
    hipMemsetAsync(cnt, 0, N_NODES * sizeof(int), stream);

    // 0. weight transpose+convert (f32 [K][N] -> f16 [N][K])
    wt_kernel<<<dim3(DIN / 32,   DMODEL / 32), 256, 0, stream>>>(W_in,   wt_in,   DIN,    DMODEL);
    wt_kernel<<<dim3(DMODEL / 32, TD / 32),    256, 0, stream>>>(W_qkv,  wt_qkv,  DMODEL, TD);
    wt_kernel<<<dim3(1024 / 32,  DMODEL / 32), 256, 0, stream>>>(W_proj, wt_proj, 1024,   DMODEL);
    wt_kernel<<<dim3(DMODEL / 32, FFD / 32),   256, 0, stream>>>(W1,     wt_w1,   DMODEL, FFD);
    wt_kernel<<<dim3(FFD / 32,   DMODEL / 32), 256, 0, stream>>>(W2,     wt_w2,   FFD,    DMODEL);
    wt_kernel<<<dim3(DMODEL / 32, DOUT / 32),  256, 0, stream>>>(W_out,  wt_out,  DMODEL, DOUT);
    // 0b. x -> f16
    f2h_kernel<<<(N_NODES * DIN) / 1024, 256, 0, stream>>>(x, x_h, N_NODES * DIN);

    const int GY = (N_NODES + 127) / 128;   // 157

    // 1. h = x@W_in + b_in + pe (f32 out + f16 copy)
    gemm_mfma<float, 1, 1, 0><<<dim3(DMODEL / 128, GY), 256, 0, stream>>>(
        x_h, wt_in, b_in, pe, h, h_h, N_NODES, DMODEL, DIN);
    // 2. qkv = h@W_qkv (f16)
    gemm_mfma<f16, 0, 0, 0><<<dim3(TD / 128, GY), 256, 0, stream>>>(
        h_h, wt_qkv, nullptr, nullptr, qkv, nullptr, N_NODES, TD, DMODEL);
    // 3. fused conv + kv sums + q materialization
    kv_fused_kernel<<<N_NODES / KV_CHUNK, 256, 0, stream>>>(qkv, conv_w, q_all, kvg);
    // 4. attention readout (in-place over q_all)
    attn_o_kernel<<<2500, 256, 0, stream>>>(q_all, kvg, q_all);
    // 5. src2 = attn_o@W_proj + b_proj (f16)
    gemm_mfma<f16, 1, 0, 0><<<dim3(DMODEL / 128, GY), 256, 0, stream>>>(
        q_all, wt_proj, b_proj, nullptr, src2, nullptr, N_NODES, DMODEL, 1024);
    // 6. src = h + LN(src2)  (f32 in-place over h; f16 in-place over src2)
    ln_res_kernel<<<N_NODES, 256, 0, stream>>>(src2, h, g1, beta1, src, src2);
    // 7. ffh = relu(src@W1 + bf1) (f16)
    gemm_mfma<f16, 1, 0, 1><<<dim3(FFD / 128, GY), 256, 0, stream>>>(
        src2, wt_w1, bf1, nullptr, ffh, nullptr, N_NODES, FFD, DMODEL);
    // 8. ff = ffh@W2 + bf2 (f16)
    gemm_mfma<f16, 1, 0, 0><<<dim3(DMODEL / 128, GY), 256, 0, stream>>>(
        ffh, wt_w2, bf2, nullptr, ff, nullptr, N_NODES, DMODEL, FFD);
    // 9. srcf = src + LN(ff)  (f32 in-place over src)
    ln_res_kernel<<<N_NODES, 256, 0, stream>>>(ff, src, g2, beta2, srcf, nullptr);
    // 10. degree / normalization
    deg_init_kernel<<<(N_NODES + 255) / 256, 256, 0, stream>>>(deg);
    deg_acc_kernel<<<(N_EDGES + 255) / 256, 256, 0, stream>>>(eirow, ea, deg);
    dis_kernel<<<(N_NODES + 255) / 256, 256, 0, stream>>>(deg, dis);
    // 11. counting sort of edges by destination row
    count_kernel<<<(N_EDGES + 255) / 256, 256, 0, stream>>>(eirow, cnt);
    scan_kernel<<<1, 1024, 0, stream>>>(cnt, rs, cur);
    scatter_kernel<<<(N_EDGES + 255) / 256, 256, 0, stream>>>(eirow, cur, sorted);
    // 12. aggregation (stores relu as f16)
    agg_kernel<<<N_NODES, 256, 0, stream>>>(srcf, eicol, ea, dis, rs, sorted, agg);
    // 13. out = relu(agg)@W_out + b_out (f32)
    gemm_mfma<float, 1, 0, 0><<<dim3(DOUT / 128, GY), 256, 0, stream>>>(
        agg, wt_out, b_out, nullptr, outp, nullptr, N_NODES, DOUT, DMODEL);
}

// Round 9
// 1228.036 us; speedup vs baseline: 3.0232x; 1.0703x over previous
//
#include <hip/hip_runtime.h>

#define N_NODES 20000
#define N_EDGES 320000
#define DIN     256
#define DMODEL  512
#define TD      1536   // 3*D
#define FFD     2048
#define DOUT    128

typedef _Float16 f16;
typedef f16 f16x8 __attribute__((ext_vector_type(8)));
typedef f16 f16x4 __attribute__((ext_vector_type(4)));
typedef float f32x4 __attribute__((ext_vector_type(4)));

__device__ __forceinline__ void cstore(float* p, float v) { *p = v; }
__device__ __forceinline__ void cstore(f16* p, float v)   { *p = (f16)v; }

// ---------------------------------------------------------------------------
// fp16 MFMA GEMM: C = act(A[MxK]f16 @ B + bias [+ addmat]) with B given as
// Bt[N][K] f16 (pre-transposed). 128x128 block tile, BK=32, 4 waves (2x2),
// 64x64 per wave via 4x4 frags of mfma_f32_16x16x32_f16, fp32 accum.
// LDS [row][32] f16 with chunk-XOR swizzle (kc ^= (row>>1)&3) on both sides.
// Requires: K%32==0, N%128==0. M guarded.
// ---------------------------------------------------------------------------
template<typename TC, int HAS_BIAS, int HAS_ADD, int DO_RELU>
__global__ __launch_bounds__(256)
void gemm_mfma(const f16* __restrict__ A, const f16* __restrict__ Bt,
               const float* __restrict__ bias, const float* __restrict__ addmat,
               TC* __restrict__ C, f16* __restrict__ Cbf,
               int M, int N, int K)
{
    __shared__ f16 As[128 * 32];
    __shared__ f16 Bs[128 * 32];
    const int tid  = threadIdx.x;
    const int lane = tid & 63;
    const int wid  = tid >> 6;
    const int wm = wid >> 1, wn = wid & 1;
    const int m0 = blockIdx.y * 128, n0 = blockIdx.x * 128;

    f32x4 acc[4][4];
    #pragma unroll
    for (int i = 0; i < 4; ++i)
        #pragma unroll
        for (int j = 0; j < 4; ++j)
            acc[i][j] = (f32x4)0.0f;

    const int r  = lane & 15;           // fragment row-within-16
    const int kg = lane >> 4;           // k-group 0..3
    const int px = (kg ^ ((r >> 1) & 3)) << 3;   // swizzled chunk (f16 units)

    for (int k0 = 0; k0 < K; k0 += 32) {
        #pragma unroll
        for (int it = 0; it < 2; ++it) {
            const int c   = tid + it * 256;      // 0..511 chunk id
            const int row = c >> 2, kc = c & 3;
            const int widx = row * 32 + ((kc ^ ((row >> 1) & 3)) << 3);
            f16x8 va = {0, 0, 0, 0, 0, 0, 0, 0};
            const int ga = m0 + row;
            if (ga < M) va = *(const f16x8*)(A + (size_t)ga * K + k0 + kc * 8);
            *(f16x8*)(&As[widx]) = va;
            const f16x8 vb = *(const f16x8*)(Bt + (size_t)(n0 + row) * K + k0 + kc * 8);
            *(f16x8*)(&Bs[widx]) = vb;
        }
        __syncthreads();
        f16x8 af[4], bfr[4];
        #pragma unroll
        for (int m = 0; m < 4; ++m)
            af[m] = *(const f16x8*)(&As[(wm * 64 + m * 16 + r) * 32 + px]);
        #pragma unroll
        for (int n = 0; n < 4; ++n)
            bfr[n] = *(const f16x8*)(&Bs[(wn * 64 + n * 16 + r) * 32 + px]);
        #pragma unroll
        for (int m = 0; m < 4; ++m)
            #pragma unroll
            for (int n = 0; n < 4; ++n)
                acc[m][n] = __builtin_amdgcn_mfma_f32_16x16x32_f16(
                    af[m], bfr[n], acc[m][n], 0, 0, 0);
        __syncthreads();
    }

    const int rq = lane >> 4;
    #pragma unroll
    for (int m = 0; m < 4; ++m) {
        #pragma unroll
        for (int rr = 0; rr < 4; ++rr) {
            const int row = m0 + wm * 64 + m * 16 + rq * 4 + rr;
            if (row >= M) continue;
            #pragma unroll
            for (int n = 0; n < 4; ++n) {
                const int col = n0 + wn * 64 + n * 16 + (lane & 15);
                float v = acc[m][n][rr];
                if (HAS_BIAS) v += bias[col];
                if (HAS_ADD)  v += addmat[(size_t)row * N + col];
                if (DO_RELU)  v = fmaxf(v, 0.f);
                cstore(&C[(size_t)row * N + col], v);
                if (Cbf) Cbf[(size_t)row * N + col] = (f16)v;
            }
        }
    }
}

// ---------------------------------------------------------------------------
// Weight transpose+convert: W[K][N] f32 -> Wt[N][K] f16. 32x32 LDS tiles.
// ---------------------------------------------------------------------------
__global__ void wt_kernel(const float* __restrict__ W, f16* __restrict__ Wt, int K, int N)
{
    __shared__ float t[32][33];
    const int k0 = blockIdx.x * 32, n0 = blockIdx.y * 32;
    const int tx = threadIdx.x & 31, ty = threadIdx.x >> 5;   // 256 thr: ty 0..7
    #pragma unroll
    for (int i = ty; i < 32; i += 8) {
        const int k = k0 + i;
        if (k < K && n0 + tx < N) t[i][tx] = W[(size_t)k * N + n0 + tx];
    }
    __syncthreads();
    #pragma unroll
    for (int i = ty; i < 32; i += 8) {
        const int n = n0 + i;
        if (n < N && k0 + tx < K) Wt[(size_t)n * K + k0 + tx] = (f16)t[tx][i];
    }
}

// f32 -> f16 elementwise (n % 4 == 0)
__global__ void f2h_kernel(const float* __restrict__ in, f16* __restrict__ out, int n)
{
    const int i = (blockIdx.x * 256 + threadIdx.x) * 4;
    if (i < n) {
        const float4 v = *(const float4*)(in + i);
        out[i + 0] = (f16)v.x; out[i + 1] = (f16)v.y;
        out[i + 2] = (f16)v.z; out[i + 3] = (f16)v.w;
    }
}

// ---------------------------------------------------------------------------
// Fused conv + kv-sum + q materialization. v2:
//  - conv weights hoisted to registers (loop-invariant per thread)
//  - vectorized f16x4/f16x8 LDS window reads
//  - next-row prefetch into registers (latency hidden under compute)
// Each block: KV_CHUNK consecutive nodes, rolling 5-row qkv window in LDS.
// full[n,j] = j<1536 ? qkv[n,j] : conv5(qkv)[n,j-1536]; head h: q=full[h*24+d],
// k=full[h*24+8+d], v=full[h*24+16+d].
// kv[h,d,e] += relu(k)*v1 (v1[8]=1) in regs; atomics once at block end.
// q_all[n][h*8+d] = relu(q) f16 (coalesced), consumed by attn_o.
// ---------------------------------------------------------------------------
#define KV_CHUNK 32
__global__ __launch_bounds__(256, 2)
void kv_fused_kernel(const f16* __restrict__ qkv, const float* __restrict__ cw,
                     f16* __restrict__ q_all, float* __restrict__ kvg)
{
    __shared__ f16 rows[5][TD];
    const int tid = threadIdx.x;
    const int n0 = blockIdx.x * KV_CHUNK;
    const int h = tid >> 1, d0 = (tid & 1) * 4;

    // ---- hoist conv weights into registers (fixed channels per thread) ----
    float wk[4][5], wv[8][5], wq[8][5];
    if (h >= 64) {
        const int cb = (h - 64) * 24;
        #pragma unroll
        for (int dd = 0; dd < 4; ++dd)
            #pragma unroll
            for (int t = 0; t < 5; ++t)
                wk[dd][t] = cw[(cb + 8 + d0 + dd) * 5 + t];
        #pragma unroll
        for (int e = 0; e < 8; ++e)
            #pragma unroll
            for (int t = 0; t < 5; ++t)
                wv[e][t] = cw[(cb + 16 + e) * 5 + t];
    }
    if (tid >= 64 && tid < 128) {
        const int cb = (tid - 64) * 24;
        #pragma unroll
        for (int d = 0; d < 8; ++d)
            #pragma unroll
            for (int t = 0; t < 5; ++t)
                wq[d][t] = cw[(cb + d) * 5 + t];
    }

    // ---- preload rows n0-2 .. n0+2 ----
    for (int r = n0 - 2; r <= n0 + 2; ++r) {
        const int slot = ((r % 5) + 5) % 5;
        if (tid < 192) {
            f16x8 v = {0, 0, 0, 0, 0, 0, 0, 0};
            if (r >= 0 && r < N_NODES)
                v = *(const f16x8*)(qkv + (size_t)r * TD + tid * 8);
            *(f16x8*)(&rows[slot][tid * 8]) = v;
        }
    }
    __syncthreads();

    float acc[36] = {};

    for (int i = 0; i < KV_CHUNK; ++i) {
        const int n = n0 + i;

        // prefetch row n+3 into registers; latency overlaps compute below
        f16x8 pre = {0, 0, 0, 0, 0, 0, 0, 0};
        const bool doPre = (i < KV_CHUNK - 1) && (tid < 192);
        if (doPre && (n + 3) < N_NODES)
            pre = *(const f16x8*)(qkv + (size_t)(n + 3) * TD + tid * 8);

        const f16* wr[5] = { rows[(((n - 2) % 5) + 5) % 5],
                             rows[(((n - 1) % 5) + 5) % 5],
                             rows[n % 5],
                             rows[(n + 1) % 5],
                             rows[(n + 2) % 5] };

        // ---- kv accumulation (thread owns (h, d-half)) ----
        float kv4[4], vv[8];
        if (h < 64) {
            const int cb = h * 24;
            const f16x4 kd = *(const f16x4*)(wr[2] + cb + 8 + d0);
            const f16x8 vd = *(const f16x8*)(wr[2] + cb + 16);
            #pragma unroll
            for (int dd = 0; dd < 4; ++dd) kv4[dd] = fmaxf((float)kd[dd], 0.f);
            #pragma unroll
            for (int e = 0; e < 8; ++e) vv[e] = (float)vd[e];
        } else {
            const int cb = (h - 64) * 24;
            f16x4 ka[5]; f16x8 va[5];
            #pragma unroll
            for (int t = 0; t < 5; ++t) {
                ka[t] = *(const f16x4*)(wr[t] + cb + 8 + d0);
                va[t] = *(const f16x8*)(wr[t] + cb + 16);
            }
            #pragma unroll
            for (int dd = 0; dd < 4; ++dd) {
                float s = 0.f;
                #pragma unroll
                for (int t = 0; t < 5; ++t) s = fmaf(wk[dd][t], (float)ka[t][dd], s);
                kv4[dd] = fmaxf(s, 0.f);
            }
            #pragma unroll
            for (int e = 0; e < 8; ++e) {
                float s = 0.f;
                #pragma unroll
                for (int t = 0; t < 5; ++t) s = fmaf(wv[e][t], (float)va[t][e], s);
                vv[e] = s;
            }
        }
        #pragma unroll
        for (int dd = 0; dd < 4; ++dd) {
            #pragma unroll
            for (int e = 0; e < 8; ++e)
                acc[dd * 9 + e] = fmaf(kv4[dd], vv[e], acc[dd * 9 + e]);
            acc[dd * 9 + 8] += kv4[dd];
        }

        // ---- q materialization (threads 0..127, head = tid) ----
        if (tid < 128) {
            f16x8 qv;
            if (tid < 64) {
                qv = *(const f16x8*)(wr[2] + tid * 24);
                #pragma unroll
                for (int d = 0; d < 8; ++d)
                    qv[d] = qv[d] > (f16)0 ? qv[d] : (f16)0;
            } else {
                const int cb = (tid - 64) * 24;
                f16x8 qa[5];
                #pragma unroll
                for (int t = 0; t < 5; ++t) qa[t] = *(const f16x8*)(wr[t] + cb);
                #pragma unroll
                for (int d = 0; d < 8; ++d) {
                    float s = 0.f;
                    #pragma unroll
                    for (int t = 0; t < 5; ++t) s = fmaf(wq[d][t], (float)qa[t][d], s);
                    qv[d] = (f16)fmaxf(s, 0.f);
                }
            }
            *(f16x8*)(q_all + (size_t)n * 1024 + tid * 8) = qv;
        }

        __syncthreads();   // row n-2 consumers done
        if (doPre)
            *(f16x8*)(&rows[(n + 3) % 5][tid * 8]) = pre;
        __syncthreads();
    }

    #pragma unroll
    for (int dd = 0; dd < 4; ++dd)
        #pragma unroll
        for (int e = 0; e < 9; ++e)
            atomicAdd(&kvg[h * 72 + (d0 + dd) * 9 + e], acc[dd * 9 + e]);
}

// ---------------------------------------------------------------------------
// o[n, h*8+e] = (sum_d q*kv[h,d,e]) / (sum_d q*kv[h,d,8] + 1e-15)
// q_all pre-relu'd f16; kv staged transposed in LDS (conflict-free reads).
// o may alias q_all (each (n,h) slot read-then-written by one thread).
// ---------------------------------------------------------------------------
__global__ __launch_bounds__(256)
void attn_o_kernel(const f16* __restrict__ q_all, const float* __restrict__ kvg,
                   f16* __restrict__ o)
{
    __shared__ float kvt[72][128];   // [d*9+e][h]
    const int tid = threadIdx.x;
    for (int i = tid; i < 9216; i += 256) {
        const int hh = i & 127, j = i >> 7;    // j = 0..71
        kvt[j][hh] = kvg[hh * 72 + j];
    }
    __syncthreads();
    const int h = tid & 127, sub = tid >> 7;
    for (int nb = blockIdx.x; nb < N_NODES / 2; nb += gridDim.x) {
        const int n = nb * 2 + sub;
        const f16x8 qv8 = *(const f16x8*)(q_all + (size_t)n * 1024 + h * 8);
        float q[8];
        #pragma unroll
        for (int d = 0; d < 8; ++d) q[d] = (float)qv8[d];
        float num[8], den = 0.f;
        #pragma unroll
        for (int e = 0; e < 8; ++e) {
            float s = 0.f;
            #pragma unroll
            for (int d = 0; d < 8; ++d) s = fmaf(q[d], kvt[d * 9 + e][h], s);
            num[e] = s;
        }
        #pragma unroll
        for (int d = 0; d < 8; ++d) den = fmaf(q[d], kvt[d * 9 + 8][h], den);
        const float rinv = 1.f / (den + 1e-15f);
        f16x8 ov;
        #pragma unroll
        for (int e = 0; e < 8; ++e) ov[e] = (f16)(num[e] * rinv);
        *(f16x8*)(o + (size_t)n * 1024 + h * 8) = ov;
    }
}

// ---------------------------------------------------------------------------
// out = resid + LN(y)*g + b; optional f16 copy (out_h may alias y: same-index)
// ---------------------------------------------------------------------------
__global__ void ln_res_kernel(const f16* __restrict__ y, const float* __restrict__ resid,
                              const float* __restrict__ g, const float* __restrict__ b,
                              float* __restrict__ out, f16* __restrict__ out_h)
{
    const int row = blockIdx.x;
    const int tid = threadIdx.x;
    const f16* yr = y + (size_t)row * DMODEL;
    const float v0 = (float)yr[tid], v1 = (float)yr[tid + 256];
    __shared__ float red[4], red2[4];
    float s = v0 + v1;
    #pragma unroll
    for (int o = 32; o > 0; o >>= 1) s += __shfl_down(s, o);
    if ((tid & 63) == 0) red[tid >> 6] = s;
    __syncthreads();
    const float mean = (red[0] + red[1] + red[2] + red[3]) * (1.0f / DMODEL);
    const float d0 = v0 - mean, d1 = v1 - mean;
    float q = d0 * d0 + d1 * d1;
    #pragma unroll
    for (int o = 32; o > 0; o >>= 1) q += __shfl_down(q, o);
    if ((tid & 63) == 0) red2[tid >> 6] = q;
    __syncthreads();
    const float var = (red2[0] + red2[1] + red2[2] + red2[3]) * (1.0f / DMODEL);
    const float inv = rsqrtf(var + 1e-5f);
    const float* rr = resid + (size_t)row * DMODEL;
    float* orow = out + (size_t)row * DMODEL;
    const float o0 = rr[tid]       + d0 * inv * g[tid]       + b[tid];
    const float o1 = rr[tid + 256] + d1 * inv * g[tid + 256] + b[tid + 256];
    orow[tid] = o0;
    orow[tid + 256] = o1;
    if (out_h) {
        f16* oh = out_h + (size_t)row * DMODEL;
        oh[tid] = (f16)o0;
        oh[tid + 256] = (f16)o1;
    }
}

// ---------------------------------------------------------------------------
// Graph normalization + counting sort + aggregation
// ---------------------------------------------------------------------------
__global__ void deg_init_kernel(float* __restrict__ deg)
{
    const int i = blockIdx.x * 256 + threadIdx.x;
    if (i < N_NODES) deg[i] = 1.0f;
}

__global__ void deg_acc_kernel(const int* __restrict__ eirow, const float* __restrict__ ea,
                               float* __restrict__ deg)
{
    const int e = blockIdx.x * 256 + threadIdx.x;
    if (e < N_EDGES) atomicAdd(&deg[eirow[e]], ea[e]);
}

__global__ void dis_kernel(const float* __restrict__ deg, float* __restrict__ dis)
{
    const int i = blockIdx.x * 256 + threadIdx.x;
    if (i < N_NODES) dis[i] = rsqrtf(deg[i]);
}

__global__ void count_kernel(const int* __restrict__ eirow, int* __restrict__ cnt)
{
    const int e = blockIdx.x * 256 + threadIdx.x;
    if (e < N_EDGES) atomicAdd(&cnt[eirow[e]], 1);
}

__global__ void scan_kernel(const int* __restrict__ cnt, int* __restrict__ rowstart,
                            int* __restrict__ cursor)
{
    __shared__ int ls[1024];
    const int tid = threadIdx.x;
    const int base = tid * 20;
    int local[20];
    int s = 0;
    #pragma unroll
    for (int i = 0; i < 20; ++i) {
        const int idx = base + i;
        const int v = (idx < N_NODES) ? cnt[idx] : 0;
        local[i] = s;
        s += v;
    }
    ls[tid] = s;
    __syncthreads();
    for (int off = 1; off < 1024; off <<= 1) {
        const int v = (tid >= off) ? ls[tid - off] : 0;
        __syncthreads();
        ls[tid] += v;
        __syncthreads();
    }
    const int excl = (tid == 0) ? 0 : ls[tid - 1];
    #pragma unroll
    for (int i = 0; i < 20; ++i) {
        const int idx = base + i;
        if (idx < N_NODES) {
            const int st = excl + local[i];
            rowstart[idx] = st;
            cursor[idx] = st;
        }
    }
    if (tid == 1023) rowstart[N_NODES] = ls[1023];
}

__global__ void scatter_kernel(const int* __restrict__ eirow, int* __restrict__ cursor,
                               int* __restrict__ sorted)
{
    const int e = blockIdx.x * 256 + threadIdx.x;
    if (e < N_EDGES) {
        const int r = eirow[e];
        const int p = atomicAdd(&cursor[r], 1);
        sorted[p] = e;
    }
}

// One block per dest row; gathers src[col]*nw + self-loop; stores relu as f16.
__global__ void agg_kernel(const float* __restrict__ srcf, const int* __restrict__ eicol,
                           const float* __restrict__ ea, const float* __restrict__ dis,
                           const int* __restrict__ rowstart, const int* __restrict__ sorted,
                           f16* __restrict__ agg)
{
    const int i = blockIdx.x;
    const int tid = threadIdx.x;
    float acc0 = 0.f, acc1 = 0.f;
    const float di = dis[i];
    const int s = rowstart[i], epos = rowstart[i + 1];
    for (int p = s; p < epos; ++p) {
        const int e = sorted[p];
        const int c = eicol[e];
        const float w = di * ea[e] * dis[c];
        const float* sr = srcf + (size_t)c * DMODEL;
        acc0 += w * sr[tid];
        acc1 += w * sr[tid + 256];
    }
    const float wself = di * di;
    const float* sr = srcf + (size_t)i * DMODEL;
    acc0 += wself * sr[tid];
    acc1 += wself * sr[tid + 256];
    f16* ar = agg + (size_t)i * DMODEL;
    ar[tid]       = (f16)fmaxf(acc0, 0.f);
    ar[tid + 256] = (f16)fmaxf(acc1, 0.f);
}

// ---------------------------------------------------------------------------
// Workspace layout (bytes). Peak = 152,285,888 (~145 MiB).
//   [0, 40.96M)       h f32 (1-6) -> src (6-9, in-place) -> srcf (9-13)
//   [40.96M, 102.4M)  qkv f16 (2-4); src2 f16 @40.96M (5-6, ->src_h in-place
//                     6-7); ff f16 @40.96M (8-9)
//   [61.44M, 143.36M) ffh f16 (7-8); agg f16 @61.44M (12-13)
//   [102.4M, 143.36M) x_h (pre-1), h_h @112.64M (1-2), q_all f16 (3-4,
//                     overwritten in-place by attn_o output, consumed step 5)
//   [143.36M, ...)    Wt_* f16, kvg, deg, dis, rs, cur, cnt, sorted
// ---------------------------------------------------------------------------
static constexpr size_t OFF_H     = 0;
static constexpr size_t OFF_QKV   = 40960000ull;
static constexpr size_t OFF_SRC2  = 40960000ull;
static constexpr size_t OFF_FF    = 40960000ull;
static constexpr size_t OFF_FFH   = 61440000ull;
static constexpr size_t OFF_AGG   = 61440000ull;
static constexpr size_t OFF_ATTN  = 102400000ull;
static constexpr size_t OFF_XH    = 102400000ull;
static constexpr size_t OFF_HH    = 112640000ull;
static constexpr size_t WT_IN     = 143360000ull;   //   262,144
static constexpr size_t WT_QKV    = 143622144ull;   // 1,572,864
static constexpr size_t WT_PROJ   = 145195008ull;   // 1,048,576
static constexpr size_t WT_W1     = 146243584ull;   // 2,097,152
static constexpr size_t WT_W2     = 148340736ull;   // 2,097,152
static constexpr size_t WT_OUT    = 150437888ull;   //   131,072
static constexpr size_t OFF_KV    = 150568960ull;   //    36,864
static constexpr size_t OFF_DEG   = 150605824ull;
static constexpr size_t OFF_DIS   = 150685824ull;
static constexpr size_t OFF_RS    = 150765824ull;
static constexpr size_t OFF_CUR   = 150845888ull;
static constexpr size_t OFF_CNT   = 150925888ull;
static constexpr size_t OFF_SORT  = 151005888ull;   // 1,280,000 -> 152,285,888

extern "C" void kernel_launch(void* const* d_in, const int* in_sizes, int n_in,
                              void* d_out, int out_size, void* d_ws, size_t ws_size,
                              hipStream_t stream)
{
    const float* x      = (const float*)d_in[0];
    const int*   ei     = (const int*)d_in[1];
    const float* ea     = (const float*)d_in[2];
    const float* pe     = (const float*)d_in[4];
    const float* W_in   = (const float*)d_in[5];
    const float* b_in   = (const float*)d_in[6];
    const float* W_qkv  = (const float*)d_in[7];
    const float* conv_w = (const float*)d_in[8];
    const float* W_proj = (const float*)d_in[9];
    const float* b_proj = (const float*)d_in[10];
    const float* g1     = (const float*)d_in[11];
    const float* beta1  = (const float*)d_in[12];
    const float* W1     = (const float*)d_in[13];
    const float* bf1    = (const float*)d_in[14];
    const float* W2     = (const float*)d_in[15];
    const float* bf2    = (const float*)d_in[16];
    const float* g2     = (const float*)d_in[17];
    const float* beta2  = (const float*)d_in[18];
    const float* W_out  = (const float*)d_in[19];
    const float* b_out  = (const float*)d_in[20];

    char* ws = (char*)d_ws;
    float* h      = (float*)(ws + OFF_H);
    float* src    = (float*)(ws + OFF_H);
    float* srcf   = (float*)(ws + OFF_H);
    f16*   qkv    = (f16*)(ws + OFF_QKV);
    f16*   src2   = (f16*)(ws + OFF_SRC2);
    f16*   ff     = (f16*)(ws + OFF_FF);
    f16*   ffh    = (f16*)(ws + OFF_FFH);
    f16*   agg    = (f16*)(ws + OFF_AGG);
    f16*   q_all  = (f16*)(ws + OFF_ATTN);     // q -> (in-place) attn output
    f16*   x_h    = (f16*)(ws + OFF_XH);
    f16*   h_h    = (f16*)(ws + OFF_HH);
    f16*   wt_in   = (f16*)(ws + WT_IN);
    f16*   wt_qkv  = (f16*)(ws + WT_QKV);
    f16*   wt_proj = (f16*)(ws + WT_PROJ);
    f16*   wt_w1   = (f16*)(ws + WT_W1);
    f16*   wt_w2   = (f16*)(ws + WT_W2);
    f16*   wt_out  = (f16*)(ws + WT_OUT);
    float* kvg    = (float*)(ws + OFF_KV);
    float* deg    = (float*)(ws + OFF_DEG);
    float* dis    = (float*)(ws + OFF_DIS);
    int*   rs     = (int*)(ws + OFF_RS);
    int*   cur    = (int*)(ws + OFF_CUR);
    int*   cnt    = (int*)(ws + OFF_CNT);
    int*   sorted = (int*)(ws + OFF_SORT);
    float* outp   = (float*)d_out;

    const int* eirow = ei;
    const int* eicol = ei + N_EDGES;

    hipMemsetAsync(kvg, 0, 9216 * sizeof(float), stream);
    hipMemsetAsync(cnt, 0, N_NODES * sizeof(int), stream);

    // 0. weight transpose+convert (f32 [K][N] -> f16 [N][K])
    wt_kernel<<<dim3(DIN / 32,   DMODEL / 32), 256, 0, stream>>>(W_in,   wt_in,   DIN,    DMODEL);
    wt_kernel<<<dim3(DMODEL / 32, TD / 32),    256, 0, stream>>>(W_qkv,  wt_qkv,  DMODEL, TD);
    wt_kernel<<<dim3(1024 / 32,  DMODEL / 32), 256, 0, stream>>>(W_proj, wt_proj, 1024,   DMODEL);
    wt_kernel<<<dim3(DMODEL / 32, FFD / 32),   256, 0, stream>>>(W1,     wt_w1,   DMODEL, FFD);
    wt_kernel<<<dim3(FFD / 32,   DMODEL / 32), 256, 0, stream>>>(W2,     wt_w2,   FFD,    DMODEL);
    wt_kernel<<<dim3(DMODEL / 32, DOUT / 32),  256, 0, stream>>>(W_out,  wt_out,  DMODEL, DOUT);
    // 0b. x -> f16
    f2h_kernel<<<(N_NODES * DIN) / 1024, 256, 0, stream>>>(x, x_h, N_NODES * DIN);

    const int GY = (N_NODES + 127) / 128;   // 157

    // 1. h = x@W_in + b_in + pe (f32 out + f16 copy)
    gemm_mfma<float, 1, 1, 0><<<dim3(DMODEL / 128, GY), 256, 0, stream>>>(
        x_h, wt_in, b_in, pe, h, h_h, N_NODES, DMODEL, DIN);
    // 2. qkv = h@W_qkv (f16)
    gemm_mfma<f16, 0, 0, 0><<<dim3(TD / 128, GY), 256, 0, stream>>>(
        h_h, wt_qkv, nullptr, nullptr, qkv, nullptr, N_NODES, TD, DMODEL);
    // 3. fused conv + kv sums + q materialization
    kv_fused_kernel<<<N_NODES / KV_CHUNK, 256, 0, stream>>>(qkv, conv_w, q_all, kvg);
    // 4. attention readout (in-place over q_all)
    attn_o_kernel<<<2500, 256, 0, stream>>>(q_all, kvg, q_all);
    // 5. src2 = attn_o@W_proj + b_proj (f16)
    gemm_mfma<f16, 1, 0, 0><<<dim3(DMODEL / 128, GY), 256, 0, stream>>>(
        q_all, wt_proj, b_proj, nullptr, src2, nullptr, N_NODES, DMODEL, 1024);
    // 6. src = h + LN(src2)  (f32 in-place over h; f16 in-place over src2)
    ln_res_kernel<<<N_NODES, 256, 0, stream>>>(src2, h, g1, beta1, src, src2);
    // 7. ffh = relu(src@W1 + bf1) (f16)
    gemm_mfma<f16, 1, 0, 1><<<dim3(FFD / 128, GY), 256, 0, stream>>>(
        src2, wt_w1, bf1, nullptr, ffh, nullptr, N_NODES, FFD, DMODEL);
    // 8. ff = ffh@W2 + bf2 (f16)
    gemm_mfma<f16, 1, 0, 0><<<dim3(DMODEL / 128, GY), 256, 0, stream>>>(
        ffh, wt_w2, bf2, nullptr, ff, nullptr, N_NODES, DMODEL, FFD);
    // 9. srcf = src + LN(ff)  (f32 in-place over src)
    ln_res_kernel<<<N_NODES, 256, 0, stream>>>(ff, src, g2, beta2, srcf, nullptr);
    // 10. degree / normalization
    deg_init_kernel<<<(N_NODES + 255) / 256, 256, 0, stream>>>(deg);
    deg_acc_kernel<<<(N_EDGES + 255) / 256, 256, 0, stream>>>(eirow, ea, deg);
    dis_kernel<<<(N_NODES + 255) / 256, 256, 0, stream>>>(deg, dis);
    // 11. counting sort of edges by destination row
    count_kernel<<<(N_EDGES + 255) / 256, 256, 0, stream>>>(eirow, cnt);
    scan_kernel<<<1, 1024, 0, stream>>>(cnt, rs, cur);
    scatter_kernel<<<(N_EDGES + 255) / 256, 256, 0, stream>>>(eirow, cur, sorted);
    // 12. aggregation (stores relu as f16)
    agg_kernel<<<N_NODES, 256, 0, stream>>>(srcf, eicol, ea, dis, rs, sorted, agg);
    // 13. out = relu(agg)@W_out + b_out (f32)
    gemm_mfma<float, 1, 0, 0><<<dim3(DOUT / 128, GY), 256, 0, stream>>>(
        agg, wt_out, b_out, nullptr, outp, nullptr, N_NODES, DOUT, DMODEL);
}

// Round 10
// 802.338 us; speedup vs baseline: 4.6272x; 1.5306x over previous
//
#include <hip/hip_runtime.h>

#define N_NODES 20000
#define N_EDGES 320000
#define DIN     256
#define DMODEL  512
#define TD      1536   // 3*D
#define FFD     2048
#define DOUT    128

typedef _Float16 f16;
typedef f16 f16x8 __attribute__((ext_vector_type(8)));
typedef f16 f16x4 __attribute__((ext_vector_type(4)));
typedef float f32x4 __attribute__((ext_vector_type(4)));

__device__ __forceinline__ void cstore(float* p, float v) { *p = v; }
__device__ __forceinline__ void cstore(f16* p, float v)   { *p = (f16)v; }

// ---------------------------------------------------------------------------
// fp16 MFMA GEMM: C = act(A[MxK]f16 @ B + bias [+ addmat]) with B given as
// Bt[N][K] f16 (pre-transposed). 128x128 block tile, BK=32, 4 waves (2x2),
// 64x64 per wave via 4x4 frags of mfma_f32_16x16x32_f16, fp32 accum.
// LDS [row][32] f16 with chunk-XOR swizzle (kc ^= (row>>1)&3) on both sides.
// Requires: K%32==0, N%128==0. M guarded.
// ---------------------------------------------------------------------------
template<typename TC, int HAS_BIAS, int HAS_ADD, int DO_RELU>
__global__ __launch_bounds__(256)
void gemm_mfma(const f16* __restrict__ A, const f16* __restrict__ Bt,
               const float* __restrict__ bias, const float* __restrict__ addmat,
               TC* __restrict__ C, f16* __restrict__ Cbf,
               int M, int N, int K)
{
    __shared__ f16 As[128 * 32];
    __shared__ f16 Bs[128 * 32];
    const int tid  = threadIdx.x;
    const int lane = tid & 63;
    const int wid  = tid >> 6;
    const int wm = wid >> 1, wn = wid & 1;
    const int m0 = blockIdx.y * 128, n0 = blockIdx.x * 128;

    f32x4 acc[4][4];
    #pragma unroll
    for (int i = 0; i < 4; ++i)
        #pragma unroll
        for (int j = 0; j < 4; ++j)
            acc[i][j] = (f32x4)0.0f;

    const int r  = lane & 15;           // fragment row-within-16
    const int kg = lane >> 4;           // k-group 0..3
    const int px = (kg ^ ((r >> 1) & 3)) << 3;   // swizzled chunk (f16 units)

    for (int k0 = 0; k0 < K; k0 += 32) {
        #pragma unroll
        for (int it = 0; it < 2; ++it) {
            const int c   = tid + it * 256;      // 0..511 chunk id
            const int row = c >> 2, kc = c & 3;
            const int widx = row * 32 + ((kc ^ ((row >> 1) & 3)) << 3);
            f16x8 va = {0, 0, 0, 0, 0, 0, 0, 0};
            const int ga = m0 + row;
            if (ga < M) va = *(const f16x8*)(A + (size_t)ga * K + k0 + kc * 8);
            *(f16x8*)(&As[widx]) = va;
            const f16x8 vb = *(const f16x8*)(Bt + (size_t)(n0 + row) * K + k0 + kc * 8);
            *(f16x8*)(&Bs[widx]) = vb;
        }
        __syncthreads();
        f16x8 af[4], bfr[4];
        #pragma unroll
        for (int m = 0; m < 4; ++m)
            af[m] = *(const f16x8*)(&As[(wm * 64 + m * 16 + r) * 32 + px]);
        #pragma unroll
        for (int n = 0; n < 4; ++n)
            bfr[n] = *(const f16x8*)(&Bs[(wn * 64 + n * 16 + r) * 32 + px]);
        #pragma unroll
        for (int m = 0; m < 4; ++m)
            #pragma unroll
            for (int n = 0; n < 4; ++n)
                acc[m][n] = __builtin_amdgcn_mfma_f32_16x16x32_f16(
                    af[m], bfr[n], acc[m][n], 0, 0, 0);
        __syncthreads();
    }

    const int rq = lane >> 4;
    #pragma unroll
    for (int m = 0; m < 4; ++m) {
        #pragma unroll
        for (int rr = 0; rr < 4; ++rr) {
            const int row = m0 + wm * 64 + m * 16 + rq * 4 + rr;
            if (row >= M) continue;
            #pragma unroll
            for (int n = 0; n < 4; ++n) {
                const int col = n0 + wn * 64 + n * 16 + (lane & 15);
                float v = acc[m][n][rr];
                if (HAS_BIAS) v += bias[col];
                if (HAS_ADD)  v += addmat[(size_t)row * N + col];
                if (DO_RELU)  v = fmaxf(v, 0.f);
                cstore(&C[(size_t)row * N + col], v);
                if (Cbf) Cbf[(size_t)row * N + col] = (f16)v;
            }
        }
    }
}

// ---------------------------------------------------------------------------
// Weight transpose+convert: W[K][N] f32 -> Wt[N][K] f16. 32x32 LDS tiles.
// ---------------------------------------------------------------------------
__global__ void wt_kernel(const float* __restrict__ W, f16* __restrict__ Wt, int K, int N)
{
    __shared__ float t[32][33];
    const int k0 = blockIdx.x * 32, n0 = blockIdx.y * 32;
    const int tx = threadIdx.x & 31, ty = threadIdx.x >> 5;   // 256 thr: ty 0..7
    #pragma unroll
    for (int i = ty; i < 32; i += 8) {
        const int k = k0 + i;
        if (k < K && n0 + tx < N) t[i][tx] = W[(size_t)k * N + n0 + tx];
    }
    __syncthreads();
    #pragma unroll
    for (int i = ty; i < 32; i += 8) {
        const int n = n0 + i;
        if (n < N && k0 + tx < K) Wt[(size_t)n * K + k0 + tx] = (f16)t[tx][i];
    }
}

// f32 -> f16 elementwise (n % 4 == 0)
__global__ void f2h_kernel(const float* __restrict__ in, f16* __restrict__ out, int n)
{
    const int i = (blockIdx.x * 256 + threadIdx.x) * 4;
    if (i < n) {
        const float4 v = *(const float4*)(in + i);
        out[i + 0] = (f16)v.x; out[i + 1] = (f16)v.y;
        out[i + 2] = (f16)v.z; out[i + 3] = (f16)v.w;
    }
}

// ---------------------------------------------------------------------------
// Fused conv + kv-sum + q materialization. v3:
//  - per-block NON-ATOMIC partial writes (kv_part[block][9216]) when
//    workspace permits; atomic fallback otherwise. Round-9 profile showed
//    5.76M device-scope atomics -> 180 MB memory-side RMW dominating.
// Each block: KV_CHUNK consecutive nodes, rolling 5-row qkv window in LDS.
// kv[h,d,e] += relu(k)*v1 (v1[8]=1) in regs; partials written at block end.
// q_all[n][h*8+d] = relu(q) f16 (coalesced), consumed by attn_o.
// ---------------------------------------------------------------------------
#define KV_CHUNK 32
#define KV_BLOCKS (N_NODES / KV_CHUNK)   // 625
__global__ __launch_bounds__(256, 2)
void kv_fused_kernel(const f16* __restrict__ qkv, const float* __restrict__ cw,
                     f16* __restrict__ q_all, float* __restrict__ kvg,
                     float* __restrict__ kv_part)
{
    __shared__ f16 rows[5][TD];
    const int tid = threadIdx.x;
    const int n0 = blockIdx.x * KV_CHUNK;
    const int h = tid >> 1, d0 = (tid & 1) * 4;

    // ---- hoist conv weights into registers (fixed channels per thread) ----
    float wk[4][5], wv[8][5], wq[8][5];
    if (h >= 64) {
        const int cb = (h - 64) * 24;
        #pragma unroll
        for (int dd = 0; dd < 4; ++dd)
            #pragma unroll
            for (int t = 0; t < 5; ++t)
                wk[dd][t] = cw[(cb + 8 + d0 + dd) * 5 + t];
        #pragma unroll
        for (int e = 0; e < 8; ++e)
            #pragma unroll
            for (int t = 0; t < 5; ++t)
                wv[e][t] = cw[(cb + 16 + e) * 5 + t];
    }
    if (tid >= 64 && tid < 128) {
        const int cb = (tid - 64) * 24;
        #pragma unroll
        for (int d = 0; d < 8; ++d)
            #pragma unroll
            for (int t = 0; t < 5; ++t)
                wq[d][t] = cw[(cb + d) * 5 + t];
    }

    // ---- preload rows n0-2 .. n0+2 ----
    for (int r = n0 - 2; r <= n0 + 2; ++r) {
        const int slot = ((r % 5) + 5) % 5;
        if (tid < 192) {
            f16x8 v = {0, 0, 0, 0, 0, 0, 0, 0};
            if (r >= 0 && r < N_NODES)
                v = *(const f16x8*)(qkv + (size_t)r * TD + tid * 8);
            *(f16x8*)(&rows[slot][tid * 8]) = v;
        }
    }
    __syncthreads();

    float acc[36] = {};

    for (int i = 0; i < KV_CHUNK; ++i) {
        const int n = n0 + i;

        // prefetch row n+3 into registers; latency overlaps compute below
        f16x8 pre = {0, 0, 0, 0, 0, 0, 0, 0};
        const bool doPre = (i < KV_CHUNK - 1) && (tid < 192);
        if (doPre && (n + 3) < N_NODES)
            pre = *(const f16x8*)(qkv + (size_t)(n + 3) * TD + tid * 8);

        const f16* wr[5] = { rows[(((n - 2) % 5) + 5) % 5],
                             rows[(((n - 1) % 5) + 5) % 5],
                             rows[n % 5],
                             rows[(n + 1) % 5],
                             rows[(n + 2) % 5] };

        // ---- kv accumulation (thread owns (h, d-half)) ----
        float kv4[4], vv[8];
        if (h < 64) {
            const int cb = h * 24;
            const f16x4 kd = *(const f16x4*)(wr[2] + cb + 8 + d0);
            const f16x8 vd = *(const f16x8*)(wr[2] + cb + 16);
            #pragma unroll
            for (int dd = 0; dd < 4; ++dd) kv4[dd] = fmaxf((float)kd[dd], 0.f);
            #pragma unroll
            for (int e = 0; e < 8; ++e) vv[e] = (float)vd[e];
        } else {
            const int cb = (h - 64) * 24;
            f16x4 ka[5]; f16x8 va[5];
            #pragma unroll
            for (int t = 0; t < 5; ++t) {
                ka[t] = *(const f16x4*)(wr[t] + cb + 8 + d0);
                va[t] = *(const f16x8*)(wr[t] + cb + 16);
            }
            #pragma unroll
            for (int dd = 0; dd < 4; ++dd) {
                float s = 0.f;
                #pragma unroll
                for (int t = 0; t < 5; ++t) s = fmaf(wk[dd][t], (float)ka[t][dd], s);
                kv4[dd] = fmaxf(s, 0.f);
            }
            #pragma unroll
            for (int e = 0; e < 8; ++e) {
                float s = 0.f;
                #pragma unroll
                for (int t = 0; t < 5; ++t) s = fmaf(wv[e][t], (float)va[t][e], s);
                vv[e] = s;
            }
        }
        #pragma unroll
        for (int dd = 0; dd < 4; ++dd) {
            #pragma unroll
            for (int e = 0; e < 8; ++e)
                acc[dd * 9 + e] = fmaf(kv4[dd], vv[e], acc[dd * 9 + e]);
            acc[dd * 9 + 8] += kv4[dd];
        }

        // ---- q materialization (threads 0..127, head = tid) ----
        if (tid < 128) {
            f16x8 qv;
            if (tid < 64) {
                qv = *(const f16x8*)(wr[2] + tid * 24);
                #pragma unroll
                for (int d = 0; d < 8; ++d)
                    qv[d] = qv[d] > (f16)0 ? qv[d] : (f16)0;
            } else {
                const int cb = (tid - 64) * 24;
                f16x8 qa[5];
                #pragma unroll
                for (int t = 0; t < 5; ++t) qa[t] = *(const f16x8*)(wr[t] + cb);
                #pragma unroll
                for (int d = 0; d < 8; ++d) {
                    float s = 0.f;
                    #pragma unroll
                    for (int t = 0; t < 5; ++t) s = fmaf(wq[d][t], (float)qa[t][d], s);
                    qv[d] = (f16)fmaxf(s, 0.f);
                }
            }
            *(f16x8*)(q_all + (size_t)n * 1024 + tid * 8) = qv;
        }

        __syncthreads();   // row n-2 consumers done
        if (doPre)
            *(f16x8*)(&rows[(n + 3) % 5][tid * 8]) = pre;
        __syncthreads();
    }

    // ---- epilogue: partial write (non-atomic) or atomic fallback ----
    // acc[dd*9+e] maps to kvg offset h*72 + (d0+dd)*9 + e = tid*36 + (dd*9+e),
    // so thread tid owns the contiguous range [tid*36, tid*36+36).
    if (kv_part) {
        float* dst = kv_part + (size_t)blockIdx.x * 9216 + tid * 36;
        #pragma unroll
        for (int i = 0; i < 36; ++i) dst[i] = acc[i];
    } else {
        #pragma unroll
        for (int dd = 0; dd < 4; ++dd)
            #pragma unroll
            for (int e = 0; e < 9; ++e)
                atomicAdd(&kvg[h * 72 + (d0 + dd) * 9 + e], acc[dd * 9 + e]);
    }
}

// kvg[j] = sum_b kv_part[b][j], j in [0,9216). Grid: 36 x 256.
__global__ void kv_reduce_kernel(const float* __restrict__ kv_part,
                                 float* __restrict__ kvg)
{
    const int j = blockIdx.x * 256 + threadIdx.x;
    float s = 0.f;
    for (int b = 0; b < KV_BLOCKS; ++b)
        s += kv_part[(size_t)b * 9216 + j];
    kvg[j] = s;
}

// ---------------------------------------------------------------------------
// o[n, h*8+e] = (sum_d q*kv[h,d,e]) / (sum_d q*kv[h,d,8] + 1e-15)
// q_all pre-relu'd f16; kv staged transposed in LDS (conflict-free reads).
// o may alias q_all (each (n,h) slot read-then-written by one thread).
// ---------------------------------------------------------------------------
__global__ __launch_bounds__(256)
void attn_o_kernel(const f16* __restrict__ q_all, const float* __restrict__ kvg,
                   f16* __restrict__ o)
{
    __shared__ float kvt[72][128];   // [d*9+e][h]
    const int tid = threadIdx.x;
    for (int i = tid; i < 9216; i += 256) {
        const int hh = i & 127, j = i >> 7;    // j = 0..71
        kvt[j][hh] = kvg[hh * 72 + j];
    }
    __syncthreads();
    const int h = tid & 127, sub = tid >> 7;
    for (int nb = blockIdx.x; nb < N_NODES / 2; nb += gridDim.x) {
        const int n = nb * 2 + sub;
        const f16x8 qv8 = *(const f16x8*)(q_all + (size_t)n * 1024 + h * 8);
        float q[8];
        #pragma unroll
        for (int d = 0; d < 8; ++d) q[d] = (float)qv8[d];
        float num[8], den = 0.f;
        #pragma unroll
        for (int e = 0; e < 8; ++e) {
            float s = 0.f;
            #pragma unroll
            for (int d = 0; d < 8; ++d) s = fmaf(q[d], kvt[d * 9 + e][h], s);
            num[e] = s;
        }
        #pragma unroll
        for (int d = 0; d < 8; ++d) den = fmaf(q[d], kvt[d * 9 + 8][h], den);
        const float rinv = 1.f / (den + 1e-15f);
        f16x8 ov;
        #pragma unroll
        for (int e = 0; e < 8; ++e) ov[e] = (f16)(num[e] * rinv);
        *(f16x8*)(o + (size_t)n * 1024 + h * 8) = ov;
    }
}

// ---------------------------------------------------------------------------
// out = resid + LN(y)*g + b; optional f16 copy (out_h may alias y: same-index)
// ---------------------------------------------------------------------------
__global__ void ln_res_kernel(const f16* __restrict__ y, const float* __restrict__ resid,
                              const float* __restrict__ g, const float* __restrict__ b,
                              float* __restrict__ out, f16* __restrict__ out_h)
{
    const int row = blockIdx.x;
    const int tid = threadIdx.x;
    const f16* yr = y + (size_t)row * DMODEL;
    const float v0 = (float)yr[tid], v1 = (float)yr[tid + 256];
    __shared__ float red[4], red2[4];
    float s = v0 + v1;
    #pragma unroll
    for (int o = 32; o > 0; o >>= 1) s += __shfl_down(s, o);
    if ((tid & 63) == 0) red[tid >> 6] = s;
    __syncthreads();
    const float mean = (red[0] + red[1] + red[2] + red[3]) * (1.0f / DMODEL);
    const float d0 = v0 - mean, d1 = v1 - mean;
    float q = d0 * d0 + d1 * d1;
    #pragma unroll
    for (int o = 32; o > 0; o >>= 1) q += __shfl_down(q, o);
    if ((tid & 63) == 0) red2[tid >> 6] = q;
    __syncthreads();
    const float var = (red2[0] + red2[1] + red2[2] + red2[3]) * (1.0f / DMODEL);
    const float inv = rsqrtf(var + 1e-5f);
    const float* rr = resid + (size_t)row * DMODEL;
    float* orow = out + (size_t)row * DMODEL;
    const float o0 = rr[tid]       + d0 * inv * g[tid]       + b[tid];
    const float o1 = rr[tid + 256] + d1 * inv * g[tid + 256] + b[tid + 256];
    orow[tid] = o0;
    orow[tid + 256] = o1;
    if (out_h) {
        f16* oh = out_h + (size_t)row * DMODEL;
        oh[tid] = (f16)o0;
        oh[tid + 256] = (f16)o1;
    }
}

// ---------------------------------------------------------------------------
// Graph normalization + counting sort + aggregation
// ---------------------------------------------------------------------------
__global__ void deg_init_kernel(float* __restrict__ deg)
{
    const int i = blockIdx.x * 256 + threadIdx.x;
    if (i < N_NODES) deg[i] = 1.0f;
}

__global__ void deg_acc_kernel(const int* __restrict__ eirow, const float* __restrict__ ea,
                               float* __restrict__ deg)
{
    const int e = blockIdx.x * 256 + threadIdx.x;
    if (e < N_EDGES) atomicAdd(&deg[eirow[e]], ea[e]);
}

__global__ void dis_kernel(const float* __restrict__ deg, float* __restrict__ dis)
{
    const int i = blockIdx.x * 256 + threadIdx.x;
    if (i < N_NODES) dis[i] = rsqrtf(deg[i]);
}

__global__ void count_kernel(const int* __restrict__ eirow, int* __restrict__ cnt)
{
    const int e = blockIdx.x * 256 + threadIdx.x;
    if (e < N_EDGES) atomicAdd(&cnt[eirow[e]], 1);
}

__global__ void scan_kernel(const int* __restrict__ cnt, int* __restrict__ rowstart,
                            int* __restrict__ cursor)
{
    __shared__ int ls[1024];
    const int tid = threadIdx.x;
    const int base = tid * 20;
    int local[20];
    int s = 0;
    #pragma unroll
    for (int i = 0; i < 20; ++i) {
        const int idx = base + i;
        const int v = (idx < N_NODES) ? cnt[idx] : 0;
        local[i] = s;
        s += v;
    }
    ls[tid] = s;
    __syncthreads();
    for (int off = 1; off < 1024; off <<= 1) {
        const int v = (tid >= off) ? ls[tid - off] : 0;
        __syncthreads();
        ls[tid] += v;
        __syncthreads();
    }
    const int excl = (tid == 0) ? 0 : ls[tid - 1];
    #pragma unroll
    for (int i = 0; i < 20; ++i) {
        const int idx = base + i;
        if (idx < N_NODES) {
            const int st = excl + local[i];
            rowstart[idx] = st;
            cursor[idx] = st;
        }
    }
    if (tid == 1023) rowstart[N_NODES] = ls[1023];
}

__global__ void scatter_kernel(const int* __restrict__ eirow, int* __restrict__ cursor,
                               int* __restrict__ sorted)
{
    const int e = blockIdx.x * 256 + threadIdx.x;
    if (e < N_EDGES) {
        const int r = eirow[e];
        const int p = atomicAdd(&cursor[r], 1);
        sorted[p] = e;
    }
}

// One block per dest row; gathers src[col]*nw + self-loop; stores relu as f16.
__global__ void agg_kernel(const float* __restrict__ srcf, const int* __restrict__ eicol,
                           const float* __restrict__ ea, const float* __restrict__ dis,
                           const int* __restrict__ rowstart, const int* __restrict__ sorted,
                           f16* __restrict__ agg)
{
    const int i = blockIdx.x;
    const int tid = threadIdx.x;
    float acc0 = 0.f, acc1 = 0.f;
    const float di = dis[i];
    const int s = rowstart[i], epos = rowstart[i + 1];
    for (int p = s; p < epos; ++p) {
        const int e = sorted[p];
        const int c = eicol[e];
        const float w = di * ea[e] * dis[c];
        const float* sr = srcf + (size_t)c * DMODEL;
        acc0 += w * sr[tid];
        acc1 += w * sr[tid + 256];
    }
    const float wself = di * di;
    const float* sr = srcf + (size_t)i * DMODEL;
    acc0 += wself * sr[tid];
    acc1 += wself * sr[tid + 256];
    f16* ar = agg + (size_t)i * DMODEL;
    ar[tid]       = (f16)fmaxf(acc0, 0.f);
    ar[tid + 256] = (f16)fmaxf(acc1, 0.f);
}

// ---------------------------------------------------------------------------
// Workspace layout (bytes). Base peak = 152,285,888 (~145 MiB).
// Optional kv_part (two-stage kv reduction) appended: 23,040,000 ->
// 175,325,888; used only when ws_size permits (runtime guard).
// ---------------------------------------------------------------------------
static constexpr size_t OFF_H     = 0;
static constexpr size_t OFF_QKV   = 40960000ull;
static constexpr size_t OFF_SRC2  = 40960000ull;
static constexpr size_t OFF_FF    = 40960000ull;
static constexpr size_t OFF_FFH   = 61440000ull;
static constexpr size_t OFF_AGG   = 61440000ull;
static constexpr size_t OFF_ATTN  = 102400000ull;
static constexpr size_t OFF_XH    = 102400000ull;
static constexpr size_t OFF_HH    = 112640000ull;
static constexpr size_t WT_IN     = 143360000ull;   //   262,144
static constexpr size_t WT_QKV    = 143622144ull;   // 1,572,864
static constexpr size_t WT_PROJ   = 145195008ull;   // 1,048,576
static constexpr size_t WT_W1     = 146243584ull;   // 2,097,152
static constexpr size_t WT_W2     = 148340736ull;   // 2,097,152
static constexpr size_t WT_OUT    = 150437888ull;   //   131,072
static constexpr size_t OFF_KV    = 150568960ull;   //    36,864
static constexpr size_t OFF_DEG   = 150605824ull;
static constexpr size_t OFF_DIS   = 150685824ull;
static constexpr size_t OFF_RS    = 150765824ull;
static constexpr size_t OFF_CUR   = 150845888ull;
static constexpr size_t OFF_CNT   = 150925888ull;
static constexpr size_t OFF_SORT  = 151005888ull;   // 1,280,000 -> 152,285,888
static constexpr size_t OFF_KVP   = 152285888ull;   // 23,040,000 -> 175,325,888
static constexpr size_t WS_NEED_KVP = 175325888ull;

extern "C" void kernel_launch(void* const* d_in, const int* in_sizes, int n_in,
                              void* d_out, int out_size, void* d_ws, size_t ws_size,
                              hipStream_t stream)
{
    const float* x      = (const float*)d_in[0];
    const int*   ei     = (const int*)d_in[1];
    const float* ea     = (const float*)d_in[2];
    const float* pe     = (const float*)d_in[4];
    const float* W_in   = (const float*)d_in[5];
    const float* b_in   = (const float*)d_in[6];
    const float* W_qkv  = (const float*)d_in[7];
    const float* conv_w = (const float*)d_in[8];
    const float* W_proj = (const float*)d_in[9];
    const float* b_proj = (const float*)d_in[10];
    const float* g1     = (const float*)d_in[11];
    const float* beta1  = (const float*)d_in[12];
    const float* W1     = (const float*)d_in[13];
    const float* bf1    = (const float*)d_in[14];
    const float* W2     = (const float*)d_in[15];
    const float* bf2    = (const float*)d_in[16];
    const float* g2     = (const float*)d_in[17];
    const float* beta2  = (const float*)d_in[18];
    const float* W_out  = (const float*)d_in[19];
    const float* b_out  = (const float*)d_in[20];

    char* ws = (char*)d_ws;
    float* h      = (float*)(ws + OFF_H);
    float* src    = (float*)(ws + OFF_H);
    float* srcf   = (float*)(ws + OFF_H);
    f16*   qkv    = (f16*)(ws + OFF_QKV);
    f16*   src2   = (f16*)(ws + OFF_SRC2);
    f16*   ff     = (f16*)(ws + OFF_FF);
    f16*   ffh    = (f16*)(ws + OFF_FFH);
    f16*   agg    = (f16*)(ws + OFF_AGG);
    f16*   q_all  = (f16*)(ws + OFF_ATTN);     // q -> (in-place) attn output
    f16*   x_h    = (f16*)(ws + OFF_XH);
    f16*   h_h    = (f16*)(ws + OFF_HH);
    f16*   wt_in   = (f16*)(ws + WT_IN);
    f16*   wt_qkv  = (f16*)(ws + WT_QKV);
    f16*   wt_proj = (f16*)(ws + WT_PROJ);
    f16*   wt_w1   = (f16*)(ws + WT_W1);
    f16*   wt_w2   = (f16*)(ws + WT_W2);
    f16*   wt_out  = (f16*)(ws + WT_OUT);
    float* kvg    = (float*)(ws + OFF_KV);
    float* deg    = (float*)(ws + OFF_DEG);
    float* dis    = (float*)(ws + OFF_DIS);
    int*   rs     = (int*)(ws + OFF_RS);
    int*   cur    = (int*)(ws + OFF_CUR);
    int*   cnt    = (int*)(ws + OFF_CNT);
    int*   sorted = (int*)(ws + OFF_SORT);
    float* outp   = (float*)d_out;

    const bool twoStage = (ws_size >= WS_NEED_KVP);
    float* kv_part = twoStage ? (float*)(ws + OFF_KVP) : nullptr;

    const int* eirow = ei;
    const int* eicol = ei + N_EDGES;

    if (!twoStage)
        hipMemsetAsync(kvg, 0, 9216 * sizeof(float), stream);
    hipMemsetAsync(cnt, 0, N_NODES * sizeof(int), stream);

    // 0. weight transpose+convert (f32 [K][N] -> f16 [N][K])
    wt_kernel<<<dim3(DIN / 32,   DMODEL / 32), 256, 0, stream>>>(W_in,   wt_in,   DIN,    DMODEL);
    wt_kernel<<<dim3(DMODEL / 32, TD / 32),    256, 0, stream>>>(W_qkv,  wt_qkv,  DMODEL, TD);
    wt_kernel<<<dim3(1024 / 32,  DMODEL / 32), 256, 0, stream>>>(W_proj, wt_proj, 1024,   DMODEL);
    wt_kernel<<<dim3(DMODEL / 32, FFD / 32),   256, 0, stream>>>(W1,     wt_w1,   DMODEL, FFD);
    wt_kernel<<<dim3(FFD / 32,   DMODEL / 32), 256, 0, stream>>>(W2,     wt_w2,   FFD,    DMODEL);
    wt_kernel<<<dim3(DMODEL / 32, DOUT / 32),  256, 0, stream>>>(W_out,  wt_out,  DMODEL, DOUT);
    // 0b. x -> f16
    f2h_kernel<<<(N_NODES * DIN) / 1024, 256, 0, stream>>>(x, x_h, N_NODES * DIN);

    const int GY = (N_NODES + 127) / 128;   // 157

    // 1. h = x@W_in + b_in + pe (f32 out + f16 copy)
    gemm_mfma<float, 1, 1, 0><<<dim3(DMODEL / 128, GY), 256, 0, stream>>>(
        x_h, wt_in, b_in, pe, h, h_h, N_NODES, DMODEL, DIN);
    // 2. qkv = h@W_qkv (f16)
    gemm_mfma<f16, 0, 0, 0><<<dim3(TD / 128, GY), 256, 0, stream>>>(
        h_h, wt_qkv, nullptr, nullptr, qkv, nullptr, N_NODES, TD, DMODEL);
    // 3. fused conv + kv partials + q materialization
    kv_fused_kernel<<<KV_BLOCKS, 256, 0, stream>>>(qkv, conv_w, q_all, kvg, kv_part);
    // 3b. reduce partials -> kvg (two-stage path only)
    if (twoStage)
        kv_reduce_kernel<<<36, 256, 0, stream>>>(kv_part, kvg);
    // 4. attention readout (in-place over q_all)
    attn_o_kernel<<<2500, 256, 0, stream>>>(q_all, kvg, q_all);
    // 5. src2 = attn_o@W_proj + b_proj (f16)
    gemm_mfma<f16, 1, 0, 0><<<dim3(DMODEL / 128, GY), 256, 0, stream>>>(
        q_all, wt_proj, b_proj, nullptr, src2, nullptr, N_NODES, DMODEL, 1024);
    // 6. src = h + LN(src2)  (f32 in-place over h; f16 in-place over src2)
    ln_res_kernel<<<N_NODES, 256, 0, stream>>>(src2, h, g1, beta1, src, src2);
    // 7. ffh = relu(src@W1 + bf1) (f16)
    gemm_mfma<f16, 1, 0, 1><<<dim3(FFD / 128, GY), 256, 0, stream>>>(
        src2, wt_w1, bf1, nullptr, ffh, nullptr, N_NODES, FFD, DMODEL);
    // 8. ff = ffh@W2 + bf2 (f16)
    gemm_mfma<f16, 1, 0, 0><<<dim3(DMODEL / 128, GY), 256, 0, stream>>>(
        ffh, wt_w2, bf2, nullptr, ff, nullptr, N_NODES, DMODEL, FFD);
    // 9. srcf = src + LN(ff)  (f32 in-place over src)
    ln_res_kernel<<<N_NODES, 256, 0, stream>>>(ff, src, g2, beta2, srcf, nullptr);
    // 10. degree / normalization
    deg_init_kernel<<<(N_NODES + 255) / 256, 256, 0, stream>>>(deg);
    deg_acc_kernel<<<(N_EDGES + 255) / 256, 256, 0, stream>>>(eirow, ea, deg);
    dis_kernel<<<(N_NODES + 255) / 256, 256, 0, stream>>>(deg, dis);
    // 11. counting sort of edges by destination row
    count_kernel<<<(N_EDGES + 255) / 256, 256, 0, stream>>>(eirow, cnt);
    scan_kernel<<<1, 1024, 0, stream>>>(cnt, rs, cur);
    scatter_kernel<<<(N_EDGES + 255) / 256, 256, 0, stream>>>(eirow, cur, sorted);
    // 12. aggregation (stores relu as f16)
    agg_kernel<<<N_NODES, 256, 0, stream>>>(srcf, eicol, ea, dis, rs, sorted, agg);
    // 13. out = relu(agg)@W_out + b_out (f32)
    gemm_mfma<float, 1, 0, 0><<<dim3(DOUT / 128, GY), 256, 0, stream>>>(
        agg, wt_out, b_out, nullptr, outp, nullptr, N_NODES, DOUT, DMODEL);
}

// Round 11
// 790.255 us; speedup vs baseline: 4.6980x; 1.0153x over previous
//
#include <hip/hip_runtime.h>

#define N_NODES 20000
#define N_EDGES 320000
#define DIN     256
#define DMODEL  512
#define TD      1536   // 3*D
#define FFD     2048
#define DOUT    128

typedef _Float16 f16;
typedef f16 f16x8 __attribute__((ext_vector_type(8)));
typedef f16 f16x4 __attribute__((ext_vector_type(4)));
typedef f16 f16x2 __attribute__((ext_vector_type(2)));
typedef float f32x4 __attribute__((ext_vector_type(4)));

__device__ __forceinline__ void cstore(float* p, float v) { *p = v; }
__device__ __forceinline__ void cstore(f16* p, float v)   { *p = (f16)v; }

#if defined(__has_builtin)
#if __has_builtin(__builtin_amdgcn_global_load_lds)
#define USE_GLOAD_LDS 1
#endif
#endif

// ---------------------------------------------------------------------------
// fp16 MFMA GEMM: C = act(A[MxK]f16 @ B + bias [+ addmat]) with B given as
// Bt[N][K] f16 (pre-transposed). 128x128 tile, BK=32, 4 waves (2x2), 64x64
// per wave via 4x4 frags of mfma_f32_16x16x32_f16, fp32 accum.
// Staging: global_load_lds width=16 with PRE-SWIZZLED per-lane source
// (LDS dest is linear per-wave; swizzle kc ^= (row>>1)&3 applied to the
// global chunk index — same involution as the ds_read side).
// NOTE: A rows are read UNGUARDED up to the 128-aligned tile edge (<=96 rows
// past M); caller guarantees allocated memory there. Garbage rows only reach
// discarded (row>=M) outputs. K%32==0, N%128==0.
// ---------------------------------------------------------------------------
template<typename TC, int HAS_BIAS, int HAS_ADD, int DO_RELU>
__global__ __launch_bounds__(256)
void gemm_mfma(const f16* __restrict__ A, const f16* __restrict__ Bt,
               const float* __restrict__ bias, const float* __restrict__ addmat,
               TC* __restrict__ C, f16* __restrict__ Cbf,
               int M, int N, int K)
{
    __shared__ f16 As[128 * 32];
    __shared__ f16 Bs[128 * 32];
    const int tid  = threadIdx.x;
    const int lane = tid & 63;
    const int wid  = tid >> 6;
    const int wm = wid >> 1, wn = wid & 1;
    const int m0 = blockIdx.y * 128, n0 = blockIdx.x * 128;

    f32x4 acc[4][4];
    #pragma unroll
    for (int i = 0; i < 4; ++i)
        #pragma unroll
        for (int j = 0; j < 4; ++j)
            acc[i][j] = (f32x4)0.0f;

    const int r  = lane & 15;           // fragment row-within-16
    const int kg = lane >> 4;           // k-group 0..3
    const int px = (kg ^ ((r >> 1) & 3)) << 3;   // swizzled chunk (f16 units)

    for (int k0 = 0; k0 < K; k0 += 32) {
#ifdef USE_GLOAD_LDS
        #pragma unroll
        for (int j = 0; j < 2; ++j) {
            const int seg  = wid * 2 + j;               // 0..7, 16 rows each
            const int row  = seg * 16 + (lane >> 2);
            const int kc   = (lane & 3) ^ ((row >> 1) & 3);  // pre-swizzled src
            const f16* asrc = A  + (size_t)(m0 + row) * K + k0 + kc * 8;
            const f16* bsrc = Bt + (size_t)(n0 + row) * K + k0 + kc * 8;
            __builtin_amdgcn_global_load_lds(
                (const __attribute__((address_space(1))) void*)asrc,
                (__attribute__((address_space(3))) void*)&As[seg * 512], 16, 0, 0);
            __builtin_amdgcn_global_load_lds(
                (const __attribute__((address_space(1))) void*)bsrc,
                (__attribute__((address_space(3))) void*)&Bs[seg * 512], 16, 0, 0);
        }
#else
        #pragma unroll
        for (int it = 0; it < 2; ++it) {
            const int c   = tid + it * 256;      // 0..511 chunk id
            const int row = c >> 2, kc = c & 3;
            const int widx = row * 32 + ((kc ^ ((row >> 1) & 3)) << 3);
            f16x8 va = {0, 0, 0, 0, 0, 0, 0, 0};
            const int ga = m0 + row;
            if (ga < M) va = *(const f16x8*)(A + (size_t)ga * K + k0 + kc * 8);
            *(f16x8*)(&As[widx]) = va;
            const f16x8 vb = *(const f16x8*)(Bt + (size_t)(n0 + row) * K + k0 + kc * 8);
            *(f16x8*)(&Bs[widx]) = vb;
        }
#endif
        __syncthreads();
        f16x8 af[4], bfr[4];
        #pragma unroll
        for (int m = 0; m < 4; ++m)
            af[m] = *(const f16x8*)(&As[(wm * 64 + m * 16 + r) * 32 + px]);
        #pragma unroll
        for (int n = 0; n < 4; ++n)
            bfr[n] = *(const f16x8*)(&Bs[(wn * 64 + n * 16 + r) * 32 + px]);
        #pragma unroll
        for (int m = 0; m < 4; ++m)
            #pragma unroll
            for (int n = 0; n < 4; ++n)
                acc[m][n] = __builtin_amdgcn_mfma_f32_16x16x32_f16(
                    af[m], bfr[n], acc[m][n], 0, 0, 0);
        __syncthreads();
    }

    const int rq = lane >> 4;
    #pragma unroll
    for (int m = 0; m < 4; ++m) {
        #pragma unroll
        for (int rr = 0; rr < 4; ++rr) {
            const int row = m0 + wm * 64 + m * 16 + rq * 4 + rr;
            if (row >= M) continue;
            #pragma unroll
            for (int n = 0; n < 4; ++n) {
                const int col = n0 + wn * 64 + n * 16 + (lane & 15);
                float v = acc[m][n][rr];
                if (HAS_BIAS) v += bias[col];
                if (HAS_ADD)  v += addmat[(size_t)row * N + col];
                if (DO_RELU)  v = fmaxf(v, 0.f);
                cstore(&C[(size_t)row * N + col], v);
                if (Cbf) Cbf[(size_t)row * N + col] = (f16)v;
            }
        }
    }
}

// ---------------------------------------------------------------------------
// Weight transpose+convert: W[K][N] f32 -> Wt[N][K] f16. 32x32 LDS tiles.
// ---------------------------------------------------------------------------
__global__ void wt_kernel(const float* __restrict__ W, f16* __restrict__ Wt, int K, int N)
{
    __shared__ float t[32][33];
    const int k0 = blockIdx.x * 32, n0 = blockIdx.y * 32;
    const int tx = threadIdx.x & 31, ty = threadIdx.x >> 5;   // 256 thr: ty 0..7
    #pragma unroll
    for (int i = ty; i < 32; i += 8) {
        const int k = k0 + i;
        if (k < K && n0 + tx < N) t[i][tx] = W[(size_t)k * N + n0 + tx];
    }
    __syncthreads();
    #pragma unroll
    for (int i = ty; i < 32; i += 8) {
        const int n = n0 + i;
        if (n < N && k0 + tx < K) Wt[(size_t)n * K + k0 + tx] = (f16)t[tx][i];
    }
}

// f32 -> f16 elementwise (n % 4 == 0)
__global__ void f2h_kernel(const float* __restrict__ in, f16* __restrict__ out, int n)
{
    const int i = (blockIdx.x * 256 + threadIdx.x) * 4;
    if (i < n) {
        const float4 v = *(const float4*)(in + i);
        out[i + 0] = (f16)v.x; out[i + 1] = (f16)v.y;
        out[i + 2] = (f16)v.z; out[i + 3] = (f16)v.w;
    }
}

// ---------------------------------------------------------------------------
// Fused conv + kv-sum + q materialization (round-10 version, unchanged).
// Non-atomic per-block partials -> kv_part; atomic fallback if ws too small.
// ---------------------------------------------------------------------------
#define KV_CHUNK 32
#define KV_BLOCKS (N_NODES / KV_CHUNK)   // 625
__global__ __launch_bounds__(256, 2)
void kv_fused_kernel(const f16* __restrict__ qkv, const float* __restrict__ cw,
                     f16* __restrict__ q_all, float* __restrict__ kvg,
                     float* __restrict__ kv_part)
{
    __shared__ f16 rows[5][TD];
    const int tid = threadIdx.x;
    const int n0 = blockIdx.x * KV_CHUNK;
    const int h = tid >> 1, d0 = (tid & 1) * 4;

    float wk[4][5], wv[8][5], wq[8][5];
    if (h >= 64) {
        const int cb = (h - 64) * 24;
        #pragma unroll
        for (int dd = 0; dd < 4; ++dd)
            #pragma unroll
            for (int t = 0; t < 5; ++t)
                wk[dd][t] = cw[(cb + 8 + d0 + dd) * 5 + t];
        #pragma unroll
        for (int e = 0; e < 8; ++e)
            #pragma unroll
            for (int t = 0; t < 5; ++t)
                wv[e][t] = cw[(cb + 16 + e) * 5 + t];
    }
    if (tid >= 64 && tid < 128) {
        const int cb = (tid - 64) * 24;
        #pragma unroll
        for (int d = 0; d < 8; ++d)
            #pragma unroll
            for (int t = 0; t < 5; ++t)
                wq[d][t] = cw[(cb + d) * 5 + t];
    }

    for (int r = n0 - 2; r <= n0 + 2; ++r) {
        const int slot = ((r % 5) + 5) % 5;
        if (tid < 192) {
            f16x8 v = {0, 0, 0, 0, 0, 0, 0, 0};
            if (r >= 0 && r < N_NODES)
                v = *(const f16x8*)(qkv + (size_t)r * TD + tid * 8);
            *(f16x8*)(&rows[slot][tid * 8]) = v;
        }
    }
    __syncthreads();

    float acc[36] = {};

    for (int i = 0; i < KV_CHUNK; ++i) {
        const int n = n0 + i;

        f16x8 pre = {0, 0, 0, 0, 0, 0, 0, 0};
        const bool doPre = (i < KV_CHUNK - 1) && (tid < 192);
        if (doPre && (n + 3) < N_NODES)
            pre = *(const f16x8*)(qkv + (size_t)(n + 3) * TD + tid * 8);

        const f16* wr[5] = { rows[(((n - 2) % 5) + 5) % 5],
                             rows[(((n - 1) % 5) + 5) % 5],
                             rows[n % 5],
                             rows[(n + 1) % 5],
                             rows[(n + 2) % 5] };

        float kv4[4], vv[8];
        if (h < 64) {
            const int cb = h * 24;
            const f16x4 kd = *(const f16x4*)(wr[2] + cb + 8 + d0);
            const f16x8 vd = *(const f16x8*)(wr[2] + cb + 16);
            #pragma unroll
            for (int dd = 0; dd < 4; ++dd) kv4[dd] = fmaxf((float)kd[dd], 0.f);
            #pragma unroll
            for (int e = 0; e < 8; ++e) vv[e] = (float)vd[e];
        } else {
            const int cb = (h - 64) * 24;
            f16x4 ka[5]; f16x8 va[5];
            #pragma unroll
            for (int t = 0; t < 5; ++t) {
                ka[t] = *(const f16x4*)(wr[t] + cb + 8 + d0);
                va[t] = *(const f16x8*)(wr[t] + cb + 16);
            }
            #pragma unroll
            for (int dd = 0; dd < 4; ++dd) {
                float s = 0.f;
                #pragma unroll
                for (int t = 0; t < 5; ++t) s = fmaf(wk[dd][t], (float)ka[t][dd], s);
                kv4[dd] = fmaxf(s, 0.f);
            }
            #pragma unroll
            for (int e = 0; e < 8; ++e) {
                float s = 0.f;
                #pragma unroll
                for (int t = 0; t < 5; ++t) s = fmaf(wv[e][t], (float)va[t][e], s);
                vv[e] = s;
            }
        }
        #pragma unroll
        for (int dd = 0; dd < 4; ++dd) {
            #pragma unroll
            for (int e = 0; e < 8; ++e)
                acc[dd * 9 + e] = fmaf(kv4[dd], vv[e], acc[dd * 9 + e]);
            acc[dd * 9 + 8] += kv4[dd];
        }

        if (tid < 128) {
            f16x8 qv;
            if (tid < 64) {
                qv = *(const f16x8*)(wr[2] + tid * 24);
                #pragma unroll
                for (int d = 0; d < 8; ++d)
                    qv[d] = qv[d] > (f16)0 ? qv[d] : (f16)0;
            } else {
                const int cb = (tid - 64) * 24;
                f16x8 qa[5];
                #pragma unroll
                for (int t = 0; t < 5; ++t) qa[t] = *(const f16x8*)(wr[t] + cb);
                #pragma unroll
                for (int d = 0; d < 8; ++d) {
                    float s = 0.f;
                    #pragma unroll
                    for (int t = 0; t < 5; ++t) s = fmaf(wq[d][t], (float)qa[t][d], s);
                    qv[d] = (f16)fmaxf(s, 0.f);
                }
            }
            *(f16x8*)(q_all + (size_t)n * 1024 + tid * 8) = qv;
        }

        __syncthreads();
        if (doPre)
            *(f16x8*)(&rows[(n + 3) % 5][tid * 8]) = pre;
        __syncthreads();
    }

    if (kv_part) {
        float* dst = kv_part + (size_t)blockIdx.x * 9216 + tid * 36;
        #pragma unroll
        for (int i = 0; i < 36; ++i) dst[i] = acc[i];
    } else {
        #pragma unroll
        for (int dd = 0; dd < 4; ++dd)
            #pragma unroll
            for (int e = 0; e < 9; ++e)
                atomicAdd(&kvg[h * 72 + (d0 + dd) * 9 + e], acc[dd * 9 + e]);
    }
}

// kvg[j] = sum_b kv_part[b][j], j in [0,9216). Grid: 36 x 256.
__global__ void kv_reduce_kernel(const float* __restrict__ kv_part,
                                 float* __restrict__ kvg)
{
    const int j = blockIdx.x * 256 + threadIdx.x;
    float s = 0.f;
    for (int b = 0; b < KV_BLOCKS; ++b)
        s += kv_part[(size_t)b * 9216 + j];
    kvg[j] = s;
}

// ---------------------------------------------------------------------------
// o[n, h*8+e] = (sum_d q*kv[h,d,e]) / (sum_d q*kv[h,d,8] + 1e-15)
// ---------------------------------------------------------------------------
__global__ __launch_bounds__(256)
void attn_o_kernel(const f16* __restrict__ q_all, const float* __restrict__ kvg,
                   f16* __restrict__ o)
{
    __shared__ float kvt[72][128];   // [d*9+e][h]
    const int tid = threadIdx.x;
    for (int i = tid; i < 9216; i += 256) {
        const int hh = i & 127, j = i >> 7;    // j = 0..71
        kvt[j][hh] = kvg[hh * 72 + j];
    }
    __syncthreads();
    const int h = tid & 127, sub = tid >> 7;
    for (int nb = blockIdx.x; nb < N_NODES / 2; nb += gridDim.x) {
        const int n = nb * 2 + sub;
        const f16x8 qv8 = *(const f16x8*)(q_all + (size_t)n * 1024 + h * 8);
        float q[8];
        #pragma unroll
        for (int d = 0; d < 8; ++d) q[d] = (float)qv8[d];
        float num[8], den = 0.f;
        #pragma unroll
        for (int e = 0; e < 8; ++e) {
            float s = 0.f;
            #pragma unroll
            for (int d = 0; d < 8; ++d) s = fmaf(q[d], kvt[d * 9 + e][h], s);
            num[e] = s;
        }
        #pragma unroll
        for (int d = 0; d < 8; ++d) den = fmaf(q[d], kvt[d * 9 + 8][h], den);
        const float rinv = 1.f / (den + 1e-15f);
        f16x8 ov;
        #pragma unroll
        for (int e = 0; e < 8; ++e) ov[e] = (f16)(num[e] * rinv);
        *(f16x8*)(o + (size_t)n * 1024 + h * 8) = ov;
    }
}

// ---------------------------------------------------------------------------
// out = resid + LN(y)*g + b. out (f32) is OPTIONAL (nullptr skips); out_h
// (f16) optional, may alias y (same-index read-then-write).
// ---------------------------------------------------------------------------
__global__ void ln_res_kernel(const f16* __restrict__ y, const float* __restrict__ resid,
                              const float* __restrict__ g, const float* __restrict__ b,
                              float* __restrict__ out, f16* __restrict__ out_h)
{
    const int row = blockIdx.x;
    const int tid = threadIdx.x;
    const f16* yr = y + (size_t)row * DMODEL;
    const float v0 = (float)yr[tid], v1 = (float)yr[tid + 256];
    __shared__ float red[4], red2[4];
    float s = v0 + v1;
    #pragma unroll
    for (int o = 32; o > 0; o >>= 1) s += __shfl_down(s, o);
    if ((tid & 63) == 0) red[tid >> 6] = s;
    __syncthreads();
    const float mean = (red[0] + red[1] + red[2] + red[3]) * (1.0f / DMODEL);
    const float d0 = v0 - mean, d1 = v1 - mean;
    float q = d0 * d0 + d1 * d1;
    #pragma unroll
    for (int o = 32; o > 0; o >>= 1) q += __shfl_down(q, o);
    if ((tid & 63) == 0) red2[tid >> 6] = q;
    __syncthreads();
    const float var = (red2[0] + red2[1] + red2[2] + red2[3]) * (1.0f / DMODEL);
    const float inv = rsqrtf(var + 1e-5f);
    const float* rr = resid + (size_t)row * DMODEL;
    const float o0 = rr[tid]       + d0 * inv * g[tid]       + b[tid];
    const float o1 = rr[tid + 256] + d1 * inv * g[tid + 256] + b[tid + 256];
    if (out) {
        float* orow = out + (size_t)row * DMODEL;
        orow[tid] = o0;
        orow[tid + 256] = o1;
    }
    if (out_h) {
        f16* oh = out_h + (size_t)row * DMODEL;
        oh[tid] = (f16)o0;
        oh[tid + 256] = (f16)o1;
    }
}

// ---------------------------------------------------------------------------
// Graph normalization + counting sort + aggregation
// ---------------------------------------------------------------------------
__global__ void deg_init_kernel(float* __restrict__ deg)
{
    const int i = blockIdx.x * 256 + threadIdx.x;
    if (i < N_NODES) deg[i] = 1.0f;
}

__global__ void deg_acc_kernel(const int* __restrict__ eirow, const float* __restrict__ ea,
                               float* __restrict__ deg)
{
    const int e = blockIdx.x * 256 + threadIdx.x;
    if (e < N_EDGES) atomicAdd(&deg[eirow[e]], ea[e]);
}

__global__ void dis_kernel(const float* __restrict__ deg, float* __restrict__ dis)
{
    const int i = blockIdx.x * 256 + threadIdx.x;
    if (i < N_NODES) dis[i] = rsqrtf(deg[i]);
}

__global__ void count_kernel(const int* __restrict__ eirow, int* __restrict__ cnt)
{
    const int e = blockIdx.x * 256 + threadIdx.x;
    if (e < N_EDGES) atomicAdd(&cnt[eirow[e]], 1);
}

__global__ void scan_kernel(const int* __restrict__ cnt, int* __restrict__ rowstart,
                            int* __restrict__ cursor)
{
    __shared__ int ls[1024];
    const int tid = threadIdx.x;
    const int base = tid * 20;
    int local[20];
    int s = 0;
    #pragma unroll
    for (int i = 0; i < 20; ++i) {
        const int idx = base + i;
        const int v = (idx < N_NODES) ? cnt[idx] : 0;
        local[i] = s;
        s += v;
    }
    ls[tid] = s;
    __syncthreads();
    for (int off = 1; off < 1024; off <<= 1) {
        const int v = (tid >= off) ? ls[tid - off] : 0;
        __syncthreads();
        ls[tid] += v;
        __syncthreads();
    }
    const int excl = (tid == 0) ? 0 : ls[tid - 1];
    #pragma unroll
    for (int i = 0; i < 20; ++i) {
        const int idx = base + i;
        if (idx < N_NODES) {
            const int st = excl + local[i];
            rowstart[idx] = st;
            cursor[idx] = st;
        }
    }
    if (tid == 1023) rowstart[N_NODES] = ls[1023];
}

__global__ void scatter_kernel(const int* __restrict__ eirow, int* __restrict__ cursor,
                               int* __restrict__ sorted)
{
    const int e = blockIdx.x * 256 + threadIdx.x;
    if (e < N_EDGES) {
        const int r = eirow[e];
        const int p = atomicAdd(&cursor[r], 1);
        sorted[p] = e;
    }
}

// One block per dest row; gathers srcf_h[col] (f16 rows, 1KB) * nw +
// self-loop; stores relu as f16. Thread covers cols 2*tid, 2*tid+1.
__global__ void agg_kernel(const f16* __restrict__ srcf_h, const int* __restrict__ eicol,
                           const float* __restrict__ ea, const float* __restrict__ dis,
                           const int* __restrict__ rowstart, const int* __restrict__ sorted,
                           f16* __restrict__ agg)
{
    const int i = blockIdx.x;
    const int tid = threadIdx.x;
    float acc0 = 0.f, acc1 = 0.f;
    const float di = dis[i];
    const int s = rowstart[i], epos = rowstart[i + 1];
    for (int p = s; p < epos; ++p) {
        const int e = sorted[p];
        const int c = eicol[e];
        const float w = di * ea[e] * dis[c];
        const f16x2 v = *(const f16x2*)(srcf_h + (size_t)c * DMODEL + tid * 2);
        acc0 = fmaf(w, (float)v[0], acc0);
        acc1 = fmaf(w, (float)v[1], acc1);
    }
    const float wself = di * di;
    const f16x2 vs = *(const f16x2*)(srcf_h + (size_t)i * DMODEL + tid * 2);
    acc0 = fmaf(wself, (float)vs[0], acc0);
    acc1 = fmaf(wself, (float)vs[1], acc1);
    f16x2 o;
    o[0] = (f16)fmaxf(acc0, 0.f);
    o[1] = (f16)fmaxf(acc1, 0.f);
    *(f16x2*)(agg + (size_t)i * DMODEL + tid * 2) = o;
}

// ---------------------------------------------------------------------------
// Workspace layout (bytes). Base peak = 152,285,888 (~145 MiB).
// Optional kv_part appended: -> 175,325,888 (runtime guard).
// gload_lds reads A up to 96 rows past M; all A buffers have allocated slack.
// ---------------------------------------------------------------------------
static constexpr size_t OFF_H     = 0;
static constexpr size_t OFF_QKV   = 40960000ull;
static constexpr size_t OFF_SRC2  = 40960000ull;
static constexpr size_t OFF_FF    = 40960000ull;
static constexpr size_t OFF_FFH   = 61440000ull;
static constexpr size_t OFF_AGG   = 61440000ull;
static constexpr size_t OFF_ATTN  = 102400000ull;
static constexpr size_t OFF_XH    = 102400000ull;
static constexpr size_t OFF_HH    = 112640000ull;
static constexpr size_t WT_IN     = 143360000ull;   //   262,144
static constexpr size_t WT_QKV    = 143622144ull;   // 1,572,864
static constexpr size_t WT_PROJ   = 145195008ull;   // 1,048,576
static constexpr size_t WT_W1     = 146243584ull;   // 2,097,152
static constexpr size_t WT_W2     = 148340736ull;   // 2,097,152
static constexpr size_t WT_OUT    = 150437888ull;   //   131,072
static constexpr size_t OFF_KV    = 150568960ull;   //    36,864
static constexpr size_t OFF_DEG   = 150605824ull;
static constexpr size_t OFF_DIS   = 150685824ull;
static constexpr size_t OFF_RS    = 150765824ull;
static constexpr size_t OFF_CUR   = 150845888ull;
static constexpr size_t OFF_CNT   = 150925888ull;
static constexpr size_t OFF_SORT  = 151005888ull;   // 1,280,000 -> 152,285,888
static constexpr size_t OFF_KVP   = 152285888ull;   // 23,040,000 -> 175,325,888
static constexpr size_t WS_NEED_KVP = 175325888ull;

extern "C" void kernel_launch(void* const* d_in, const int* in_sizes, int n_in,
                              void* d_out, int out_size, void* d_ws, size_t ws_size,
                              hipStream_t stream)
{
    const float* x      = (const float*)d_in[0];
    const int*   ei     = (const int*)d_in[1];
    const float* ea     = (const float*)d_in[2];
    const float* pe     = (const float*)d_in[4];
    const float* W_in   = (const float*)d_in[5];
    const float* b_in   = (const float*)d_in[6];
    const float* W_qkv  = (const float*)d_in[7];
    const float* conv_w = (const float*)d_in[8];
    const float* W_proj = (const float*)d_in[9];
    const float* b_proj = (const float*)d_in[10];
    const float* g1     = (const float*)d_in[11];
    const float* beta1  = (const float*)d_in[12];
    const float* W1     = (const float*)d_in[13];
    const float* bf1    = (const float*)d_in[14];
    const float* W2     = (const float*)d_in[15];
    const float* bf2    = (const float*)d_in[16];
    const float* g2     = (const float*)d_in[17];
    const float* beta2  = (const float*)d_in[18];
    const float* W_out  = (const float*)d_in[19];
    const float* b_out  = (const float*)d_in[20];

    char* ws = (char*)d_ws;
    float* h      = (float*)(ws + OFF_H);
    float* src    = (float*)(ws + OFF_H);
    f16*   qkv    = (f16*)(ws + OFF_QKV);
    f16*   src2   = (f16*)(ws + OFF_SRC2);
    f16*   ff     = (f16*)(ws + OFF_FF);
    f16*   ffh    = (f16*)(ws + OFF_FFH);
    f16*   agg    = (f16*)(ws + OFF_AGG);
    f16*   q_all  = (f16*)(ws + OFF_ATTN);     // q -> (in-place) attn output
    f16*   x_h    = (f16*)(ws + OFF_XH);
    f16*   h_h    = (f16*)(ws + OFF_HH);
    f16*   wt_in   = (f16*)(ws + WT_IN);
    f16*   wt_qkv  = (f16*)(ws + WT_QKV);
    f16*   wt_proj = (f16*)(ws + WT_PROJ);
    f16*   wt_w1   = (f16*)(ws + WT_W1);
    f16*   wt_w2   = (f16*)(ws + WT_W2);
    f16*   wt_out  = (f16*)(ws + WT_OUT);
    float* kvg    = (float*)(ws + OFF_KV);
    float* deg    = (float*)(ws + OFF_DEG);
    float* dis    = (float*)(ws + OFF_DIS);
    int*   rs     = (int*)(ws + OFF_RS);
    int*   cur    = (int*)(ws + OFF_CUR);
    int*   cnt    = (int*)(ws + OFF_CNT);
    int*   sorted = (int*)(ws + OFF_SORT);
    float* outp   = (float*)d_out;

    const bool twoStage = (ws_size >= WS_NEED_KVP);
    float* kv_part = twoStage ? (float*)(ws + OFF_KVP) : nullptr;

    const int* eirow = ei;
    const int* eicol = ei + N_EDGES;

    if (!twoStage)
        hipMemsetAsync(kvg, 0, 9216 * sizeof(float), stream);
    hipMemsetAsync(cnt, 0, N_NODES * sizeof(int), stream);

    // 0. weight transpose+convert (f32 [K][N] -> f16 [N][K])
    wt_kernel<<<dim3(DIN / 32,   DMODEL / 32), 256, 0, stream>>>(W_in,   wt_in,   DIN,    DMODEL);
    wt_kernel<<<dim3(DMODEL / 32, TD / 32),    256, 0, stream>>>(W_qkv,  wt_qkv,  DMODEL, TD);
    wt_kernel<<<dim3(1024 / 32,  DMODEL / 32), 256, 0, stream>>>(W_proj, wt_proj, 1024,   DMODEL);
    wt_kernel<<<dim3(DMODEL / 32, FFD / 32),   256, 0, stream>>>(W1,     wt_w1,   DMODEL, FFD);
    wt_kernel<<<dim3(FFD / 32,   DMODEL / 32), 256, 0, stream>>>(W2,     wt_w2,   FFD,    DMODEL);
    wt_kernel<<<dim3(DMODEL / 32, DOUT / 32),  256, 0, stream>>>(W_out,  wt_out,  DMODEL, DOUT);
    // 0b. x -> f16
    f2h_kernel<<<(N_NODES * DIN) / 1024, 256, 0, stream>>>(x, x_h, N_NODES * DIN);

    const int GY = (N_NODES + 127) / 128;   // 157

    // 1. h = x@W_in + b_in + pe (f32 out + f16 copy)
    gemm_mfma<float, 1, 1, 0><<<dim3(DMODEL / 128, GY), 256, 0, stream>>>(
        x_h, wt_in, b_in, pe, h, h_h, N_NODES, DMODEL, DIN);
    // 2. qkv = h@W_qkv (f16)
    gemm_mfma<f16, 0, 0, 0><<<dim3(TD / 128, GY), 256, 0, stream>>>(
        h_h, wt_qkv, nullptr, nullptr, qkv, nullptr, N_NODES, TD, DMODEL);
    // 3. fused conv + kv partials + q materialization
    kv_fused_kernel<<<KV_BLOCKS, 256, 0, stream>>>(qkv, conv_w, q_all, kvg, kv_part);
    // 3b. reduce partials -> kvg (two-stage path only)
    if (twoStage)
        kv_reduce_kernel<<<36, 256, 0, stream>>>(kv_part, kvg);
    // 4. attention readout (in-place over q_all)
    attn_o_kernel<<<2500, 256, 0, stream>>>(q_all, kvg, q_all);
    // 5. src2 = attn_o@W_proj + b_proj (f16)
    gemm_mfma<f16, 1, 0, 0><<<dim3(DMODEL / 128, GY), 256, 0, stream>>>(
        q_all, wt_proj, b_proj, nullptr, src2, nullptr, N_NODES, DMODEL, 1024);
    // 6. src = h + LN(src2)  (f32 in-place over h; f16 in-place over src2)
    ln_res_kernel<<<N_NODES, 256, 0, stream>>>(src2, h, g1, beta1, src, src2);
    // 7. ffh = relu(src@W1 + bf1) (f16)
    gemm_mfma<f16, 1, 0, 1><<<dim3(FFD / 128, GY), 256, 0, stream>>>(
        src2, wt_w1, bf1, nullptr, ffh, nullptr, N_NODES, FFD, DMODEL);
    // 8. ff = ffh@W2 + bf2 (f16)
    gemm_mfma<f16, 1, 0, 0><<<dim3(DMODEL / 128, GY), 256, 0, stream>>>(
        ffh, wt_w2, bf2, nullptr, ff, nullptr, N_NODES, DMODEL, FFD);
    // 9. srcf_h = f16(src + LN(ff))  (f16 in-place over ff; f32 skipped)
    ln_res_kernel<<<N_NODES, 256, 0, stream>>>(ff, src, g2, beta2, nullptr, ff);
    // 10. degree / normalization
    deg_init_kernel<<<(N_NODES + 255) / 256, 256, 0, stream>>>(deg);
    deg_acc_kernel<<<(N_EDGES + 255) / 256, 256, 0, stream>>>(eirow, ea, deg);
    dis_kernel<<<(N_NODES + 255) / 256, 256, 0, stream>>>(deg, dis);
    // 11. counting sort of edges by destination row
    count_kernel<<<(N_EDGES + 255) / 256, 256, 0, stream>>>(eirow, cnt);
    scan_kernel<<<1, 1024, 0, stream>>>(cnt, rs, cur);
    scatter_kernel<<<(N_EDGES + 255) / 256, 256, 0, stream>>>(eirow, cur, sorted);
    // 12. aggregation (f16 gather, stores relu as f16)
    agg_kernel<<<N_NODES, 256, 0, stream>>>(ff, eicol, ea, dis, rs, sorted, agg);
    // 13. out = relu(agg)@W_out + b_out (f32)
    gemm_mfma<float, 1, 0, 0><<<dim3(DOUT / 128, GY), 256, 0, stream>>>(
        agg, wt_out, b_out, nullptr, outp, nullptr, N_NODES, DOUT, DMODEL);
}

// Round 12
// 704.016 us; speedup vs baseline: 5.2734x; 1.1225x over previous
//
#include <hip/hip_runtime.h>

#define N_NODES 20000
#define N_EDGES 320000
#define DIN     256
#define DMODEL  512
#define TD      1536   // 3*D
#define FFD     2048
#define DOUT    128

typedef _Float16 f16;
typedef f16 f16x8 __attribute__((ext_vector_type(8)));
typedef f16 f16x4 __attribute__((ext_vector_type(4)));
typedef f16 f16x2 __attribute__((ext_vector_type(2)));
typedef float f32x4 __attribute__((ext_vector_type(4)));

__device__ __forceinline__ void cstore(float* p, float v) { *p = v; }
__device__ __forceinline__ void cstore(f16* p, float v)   { *p = (f16)v; }

#if defined(__has_builtin)
#if __has_builtin(__builtin_amdgcn_global_load_lds)
#define USE_GLOAD_LDS 1
#endif
#endif

// ---------------------------------------------------------------------------
// fp16 MFMA GEMM (round-11 version, unchanged): 128x128 tile, BK=32, 4 waves,
// mfma_f32_16x16x32_f16, global_load_lds w=16 with pre-swizzled source.
// A rows read unguarded to the 128-aligned tile edge (allocated slack).
// ---------------------------------------------------------------------------
template<typename TC, int HAS_BIAS, int HAS_ADD, int DO_RELU>
__global__ __launch_bounds__(256)
void gemm_mfma(const f16* __restrict__ A, const f16* __restrict__ Bt,
               const float* __restrict__ bias, const float* __restrict__ addmat,
               TC* __restrict__ C, f16* __restrict__ Cbf,
               int M, int N, int K)
{
    __shared__ f16 As[128 * 32];
    __shared__ f16 Bs[128 * 32];
    const int tid  = threadIdx.x;
    const int lane = tid & 63;
    const int wid  = tid >> 6;
    const int wm = wid >> 1, wn = wid & 1;
    const int m0 = blockIdx.y * 128, n0 = blockIdx.x * 128;

    f32x4 acc[4][4];
    #pragma unroll
    for (int i = 0; i < 4; ++i)
        #pragma unroll
        for (int j = 0; j < 4; ++j)
            acc[i][j] = (f32x4)0.0f;

    const int r  = lane & 15;
    const int kg = lane >> 4;
    const int px = (kg ^ ((r >> 1) & 3)) << 3;

    for (int k0 = 0; k0 < K; k0 += 32) {
#ifdef USE_GLOAD_LDS
        #pragma unroll
        for (int j = 0; j < 2; ++j) {
            const int seg  = wid * 2 + j;               // 0..7, 16 rows each
            const int row  = seg * 16 + (lane >> 2);
            const int kc   = (lane & 3) ^ ((row >> 1) & 3);  // pre-swizzled src
            const f16* asrc = A  + (size_t)(m0 + row) * K + k0 + kc * 8;
            const f16* bsrc = Bt + (size_t)(n0 + row) * K + k0 + kc * 8;
            __builtin_amdgcn_global_load_lds(
                (const __attribute__((address_space(1))) void*)asrc,
                (__attribute__((address_space(3))) void*)&As[seg * 512], 16, 0, 0);
            __builtin_amdgcn_global_load_lds(
                (const __attribute__((address_space(1))) void*)bsrc,
                (__attribute__((address_space(3))) void*)&Bs[seg * 512], 16, 0, 0);
        }
#else
        #pragma unroll
        for (int it = 0; it < 2; ++it) {
            const int c   = tid + it * 256;
            const int row = c >> 2, kc = c & 3;
            const int widx = row * 32 + ((kc ^ ((row >> 1) & 3)) << 3);
            f16x8 va = {0, 0, 0, 0, 0, 0, 0, 0};
            const int ga = m0 + row;
            if (ga < M) va = *(const f16x8*)(A + (size_t)ga * K + k0 + kc * 8);
            *(f16x8*)(&As[widx]) = va;
            const f16x8 vb = *(const f16x8*)(Bt + (size_t)(n0 + row) * K + k0 + kc * 8);
            *(f16x8*)(&Bs[widx]) = vb;
        }
#endif
        __syncthreads();
        f16x8 af[4], bfr[4];
        #pragma unroll
        for (int m = 0; m < 4; ++m)
            af[m] = *(const f16x8*)(&As[(wm * 64 + m * 16 + r) * 32 + px]);
        #pragma unroll
        for (int n = 0; n < 4; ++n)
            bfr[n] = *(const f16x8*)(&Bs[(wn * 64 + n * 16 + r) * 32 + px]);
        #pragma unroll
        for (int m = 0; m < 4; ++m)
            #pragma unroll
            for (int n = 0; n < 4; ++n)
                acc[m][n] = __builtin_amdgcn_mfma_f32_16x16x32_f16(
                    af[m], bfr[n], acc[m][n], 0, 0, 0);
        __syncthreads();
    }

    const int rq = lane >> 4;
    #pragma unroll
    for (int m = 0; m < 4; ++m) {
        #pragma unroll
        for (int rr = 0; rr < 4; ++rr) {
            const int row = m0 + wm * 64 + m * 16 + rq * 4 + rr;
            if (row >= M) continue;
            #pragma unroll
            for (int n = 0; n < 4; ++n) {
                const int col = n0 + wn * 64 + n * 16 + (lane & 15);
                float v = acc[m][n][rr];
                if (HAS_BIAS) v += bias[col];
                if (HAS_ADD)  v += addmat[(size_t)row * N + col];
                if (DO_RELU)  v = fmaxf(v, 0.f);
                cstore(&C[(size_t)row * N + col], v);
                if (Cbf) Cbf[(size_t)row * N + col] = (f16)v;
            }
        }
    }
}

// ---------------------------------------------------------------------------
// Weight transpose+convert: W[K][N] f32 -> Wt[N][K] f16. 32x32 LDS tiles.
// ---------------------------------------------------------------------------
__global__ void wt_kernel(const float* __restrict__ W, f16* __restrict__ Wt, int K, int N)
{
    __shared__ float t[32][33];
    const int k0 = blockIdx.x * 32, n0 = blockIdx.y * 32;
    const int tx = threadIdx.x & 31, ty = threadIdx.x >> 5;
    #pragma unroll
    for (int i = ty; i < 32; i += 8) {
        const int k = k0 + i;
        if (k < K && n0 + tx < N) t[i][tx] = W[(size_t)k * N + n0 + tx];
    }
    __syncthreads();
    #pragma unroll
    for (int i = ty; i < 32; i += 8) {
        const int n = n0 + i;
        if (n < N && k0 + tx < K) Wt[(size_t)n * K + k0 + tx] = (f16)t[tx][i];
    }
}

// f32 -> f16 elementwise (n % 4 == 0)
__global__ void f2h_kernel(const float* __restrict__ in, f16* __restrict__ out, int n)
{
    const int i = (blockIdx.x * 256 + threadIdx.x) * 4;
    if (i < n) {
        const float4 v = *(const float4*)(in + i);
        out[i + 0] = (f16)v.x; out[i + 1] = (f16)v.y;
        out[i + 2] = (f16)v.z; out[i + 3] = (f16)v.w;
    }
}

// ---------------------------------------------------------------------------
// Fused conv + kv-sum + q materialization (round-10 version, unchanged).
// ---------------------------------------------------------------------------
#define KV_CHUNK 32
#define KV_BLOCKS (N_NODES / KV_CHUNK)   // 625
__global__ __launch_bounds__(256, 2)
void kv_fused_kernel(const f16* __restrict__ qkv, const float* __restrict__ cw,
                     f16* __restrict__ q_all, float* __restrict__ kvg,
                     float* __restrict__ kv_part)
{
    __shared__ f16 rows[5][TD];
    const int tid = threadIdx.x;
    const int n0 = blockIdx.x * KV_CHUNK;
    const int h = tid >> 1, d0 = (tid & 1) * 4;

    float wk[4][5], wv[8][5], wq[8][5];
    if (h >= 64) {
        const int cb = (h - 64) * 24;
        #pragma unroll
        for (int dd = 0; dd < 4; ++dd)
            #pragma unroll
            for (int t = 0; t < 5; ++t)
                wk[dd][t] = cw[(cb + 8 + d0 + dd) * 5 + t];
        #pragma unroll
        for (int e = 0; e < 8; ++e)
            #pragma unroll
            for (int t = 0; t < 5; ++t)
                wv[e][t] = cw[(cb + 16 + e) * 5 + t];
    }
    if (tid >= 64 && tid < 128) {
        const int cb = (tid - 64) * 24;
        #pragma unroll
        for (int d = 0; d < 8; ++d)
            #pragma unroll
            for (int t = 0; t < 5; ++t)
                wq[d][t] = cw[(cb + d) * 5 + t];
    }

    for (int r = n0 - 2; r <= n0 + 2; ++r) {
        const int slot = ((r % 5) + 5) % 5;
        if (tid < 192) {
            f16x8 v = {0, 0, 0, 0, 0, 0, 0, 0};
            if (r >= 0 && r < N_NODES)
                v = *(const f16x8*)(qkv + (size_t)r * TD + tid * 8);
            *(f16x8*)(&rows[slot][tid * 8]) = v;
        }
    }
    __syncthreads();

    float acc[36] = {};

    for (int i = 0; i < KV_CHUNK; ++i) {
        const int n = n0 + i;

        f16x8 pre = {0, 0, 0, 0, 0, 0, 0, 0};
        const bool doPre = (i < KV_CHUNK - 1) && (tid < 192);
        if (doPre && (n + 3) < N_NODES)
            pre = *(const f16x8*)(qkv + (size_t)(n + 3) * TD + tid * 8);

        const f16* wr[5] = { rows[(((n - 2) % 5) + 5) % 5],
                             rows[(((n - 1) % 5) + 5) % 5],
                             rows[n % 5],
                             rows[(n + 1) % 5],
                             rows[(n + 2) % 5] };

        float kv4[4], vv[8];
        if (h < 64) {
            const int cb = h * 24;
            const f16x4 kd = *(const f16x4*)(wr[2] + cb + 8 + d0);
            const f16x8 vd = *(const f16x8*)(wr[2] + cb + 16);
            #pragma unroll
            for (int dd = 0; dd < 4; ++dd) kv4[dd] = fmaxf((float)kd[dd], 0.f);
            #pragma unroll
            for (int e = 0; e < 8; ++e) vv[e] = (float)vd[e];
        } else {
            const int cb = (h - 64) * 24;
            f16x4 ka[5]; f16x8 va[5];
            #pragma unroll
            for (int t = 0; t < 5; ++t) {
                ka[t] = *(const f16x4*)(wr[t] + cb + 8 + d0);
                va[t] = *(const f16x8*)(wr[t] + cb + 16);
            }
            #pragma unroll
            for (int dd = 0; dd < 4; ++dd) {
                float s = 0.f;
                #pragma unroll
                for (int t = 0; t < 5; ++t) s = fmaf(wk[dd][t], (float)ka[t][dd], s);
                kv4[dd] = fmaxf(s, 0.f);
            }
            #pragma unroll
            for (int e = 0; e < 8; ++e) {
                float s = 0.f;
                #pragma unroll
                for (int t = 0; t < 5; ++t) s = fmaf(wv[e][t], (float)va[t][e], s);
                vv[e] = s;
            }
        }
        #pragma unroll
        for (int dd = 0; dd < 4; ++dd) {
            #pragma unroll
            for (int e = 0; e < 8; ++e)
                acc[dd * 9 + e] = fmaf(kv4[dd], vv[e], acc[dd * 9 + e]);
            acc[dd * 9 + 8] += kv4[dd];
        }

        if (tid < 128) {
            f16x8 qv;
            if (tid < 64) {
                qv = *(const f16x8*)(wr[2] + tid * 24);
                #pragma unroll
                for (int d = 0; d < 8; ++d)
                    qv[d] = qv[d] > (f16)0 ? qv[d] : (f16)0;
            } else {
                const int cb = (tid - 64) * 24;
                f16x8 qa[5];
                #pragma unroll
                for (int t = 0; t < 5; ++t) qa[t] = *(const f16x8*)(wr[t] + cb);
                #pragma unroll
                for (int d = 0; d < 8; ++d) {
                    float s = 0.f;
                    #pragma unroll
                    for (int t = 0; t < 5; ++t) s = fmaf(wq[d][t], (float)qa[t][d], s);
                    qv[d] = (f16)fmaxf(s, 0.f);
                }
            }
            *(f16x8*)(q_all + (size_t)n * 1024 + tid * 8) = qv;
        }

        __syncthreads();
        if (doPre)
            *(f16x8*)(&rows[(n + 3) % 5][tid * 8]) = pre;
        __syncthreads();
    }

    if (kv_part) {
        float* dst = kv_part + (size_t)blockIdx.x * 9216 + tid * 36;
        #pragma unroll
        for (int i = 0; i < 36; ++i) dst[i] = acc[i];
    } else {
        #pragma unroll
        for (int dd = 0; dd < 4; ++dd)
            #pragma unroll
            for (int e = 0; e < 9; ++e)
                atomicAdd(&kvg[h * 72 + (d0 + dd) * 9 + e], acc[dd * 9 + e]);
    }
}

// kvg[j] = sum_b kv_part[b][j], j in [0,9216). Grid: 36 x 256.
__global__ void kv_reduce_kernel(const float* __restrict__ kv_part,
                                 float* __restrict__ kvg)
{
    const int j = blockIdx.x * 256 + threadIdx.x;
    float s = 0.f;
    for (int b = 0; b < KV_BLOCKS; ++b)
        s += kv_part[(size_t)b * 9216 + j];
    kvg[j] = s;
}

// ---------------------------------------------------------------------------
// o[n, h*8+e] = (sum_d q*kv[h,d,e]) / (sum_d q*kv[h,d,8] + 1e-15)
// ---------------------------------------------------------------------------
__global__ __launch_bounds__(256)
void attn_o_kernel(const f16* __restrict__ q_all, const float* __restrict__ kvg,
                   f16* __restrict__ o)
{
    __shared__ float kvt[72][128];   // [d*9+e][h]
    const int tid = threadIdx.x;
    for (int i = tid; i < 9216; i += 256) {
        const int hh = i & 127, j = i >> 7;
        kvt[j][hh] = kvg[hh * 72 + j];
    }
    __syncthreads();
    const int h = tid & 127, sub = tid >> 7;
    for (int nb = blockIdx.x; nb < N_NODES / 2; nb += gridDim.x) {
        const int n = nb * 2 + sub;
        const f16x8 qv8 = *(const f16x8*)(q_all + (size_t)n * 1024 + h * 8);
        float q[8];
        #pragma unroll
        for (int d = 0; d < 8; ++d) q[d] = (float)qv8[d];
        float num[8], den = 0.f;
        #pragma unroll
        for (int e = 0; e < 8; ++e) {
            float s = 0.f;
            #pragma unroll
            for (int d = 0; d < 8; ++d) s = fmaf(q[d], kvt[d * 9 + e][h], s);
            num[e] = s;
        }
        #pragma unroll
        for (int d = 0; d < 8; ++d) den = fmaf(q[d], kvt[d * 9 + 8][h], den);
        const float rinv = 1.f / (den + 1e-15f);
        f16x8 ov;
        #pragma unroll
        for (int e = 0; e < 8; ++e) ov[e] = (f16)(num[e] * rinv);
        *(f16x8*)(o + (size_t)n * 1024 + h * 8) = ov;
    }
}

// ---------------------------------------------------------------------------
// out_h = f16(resid + LN(y)*g + b). resid is f16 (the f32 trunk is gone).
// out_h may alias y (same-index read-then-write).
// ---------------------------------------------------------------------------
__global__ void ln_res_kernel(const f16* __restrict__ y, const f16* __restrict__ resid,
                              const float* __restrict__ g, const float* __restrict__ b,
                              f16* __restrict__ out_h)
{
    const int row = blockIdx.x;
    const int tid = threadIdx.x;
    const f16* yr = y + (size_t)row * DMODEL;
    const float v0 = (float)yr[tid], v1 = (float)yr[tid + 256];
    __shared__ float red[4], red2[4];
    float s = v0 + v1;
    #pragma unroll
    for (int o = 32; o > 0; o >>= 1) s += __shfl_down(s, o);
    if ((tid & 63) == 0) red[tid >> 6] = s;
    __syncthreads();
    const float mean = (red[0] + red[1] + red[2] + red[3]) * (1.0f / DMODEL);
    const float d0 = v0 - mean, d1 = v1 - mean;
    float q = d0 * d0 + d1 * d1;
    #pragma unroll
    for (int o = 32; o > 0; o >>= 1) q += __shfl_down(q, o);
    if ((tid & 63) == 0) red2[tid >> 6] = q;
    __syncthreads();
    const float var = (red2[0] + red2[1] + red2[2] + red2[3]) * (1.0f / DMODEL);
    const float inv = rsqrtf(var + 1e-5f);
    const f16* rr = resid + (size_t)row * DMODEL;
    const float o0 = (float)rr[tid]       + d0 * inv * g[tid]       + b[tid];
    const float o1 = (float)rr[tid + 256] + d1 * inv * g[tid + 256] + b[tid + 256];
    f16* oh = out_h + (size_t)row * DMODEL;
    oh[tid] = (f16)o0;
    oh[tid + 256] = (f16)o1;
}

// ---------------------------------------------------------------------------
// Graph normalization + counting sort
// ---------------------------------------------------------------------------
__global__ void deg_init_kernel(float* __restrict__ deg)
{
    const int i = blockIdx.x * 256 + threadIdx.x;
    if (i < N_NODES) deg[i] = 1.0f;
}

__global__ void deg_acc_kernel(const int* __restrict__ eirow, const float* __restrict__ ea,
                               float* __restrict__ deg)
{
    const int e = blockIdx.x * 256 + threadIdx.x;
    if (e < N_EDGES) atomicAdd(&deg[eirow[e]], ea[e]);
}

__global__ void dis_kernel(const float* __restrict__ deg, float* __restrict__ dis)
{
    const int i = blockIdx.x * 256 + threadIdx.x;
    if (i < N_NODES) dis[i] = rsqrtf(deg[i]);
}

__global__ void count_kernel(const int* __restrict__ eirow, int* __restrict__ cnt)
{
    const int e = blockIdx.x * 256 + threadIdx.x;
    if (e < N_EDGES) atomicAdd(&cnt[eirow[e]], 1);
}

__global__ void scan_kernel(const int* __restrict__ cnt, int* __restrict__ rowstart,
                            int* __restrict__ cursor)
{
    __shared__ int ls[1024];
    const int tid = threadIdx.x;
    const int base = tid * 20;
    int local[20];
    int s = 0;
    #pragma unroll
    for (int i = 0; i < 20; ++i) {
        const int idx = base + i;
        const int v = (idx < N_NODES) ? cnt[idx] : 0;
        local[i] = s;
        s += v;
    }
    ls[tid] = s;
    __syncthreads();
    for (int off = 1; off < 1024; off <<= 1) {
        const int v = (tid >= off) ? ls[tid - off] : 0;
        __syncthreads();
        ls[tid] += v;
        __syncthreads();
    }
    const int excl = (tid == 0) ? 0 : ls[tid - 1];
    #pragma unroll
    for (int i = 0; i < 20; ++i) {
        const int idx = base + i;
        if (idx < N_NODES) {
            const int st = excl + local[i];
            rowstart[idx] = st;
            cursor[idx] = st;
        }
    }
    if (tid == 1023) rowstart[N_NODES] = ls[1023];
}

__global__ void scatter_kernel(const int* __restrict__ eirow, int* __restrict__ cursor,
                               int* __restrict__ sorted)
{
    const int e = blockIdx.x * 256 + threadIdx.x;
    if (e < N_EDGES) {
        const int r = eirow[e];
        const int p = atomicAdd(&cursor[r], 1);
        sorted[p] = e;
    }
}

// ---------------------------------------------------------------------------
// Aggregation v3 — latency-optimized:
//  1. up to 256 edges' (c, w) resolved in parallel into LDS (one latency round)
//  2. 4 waves each gather every 4th edge, one full 1KB row per wave-iter via
//     f16x8 (16B/lane); independent iterations -> loads in flight
//  3. cross-wave LDS reduce + self-loop + relu, f16 store
// ---------------------------------------------------------------------------
__global__ __launch_bounds__(256)
void agg_kernel(const f16* __restrict__ srcf_h, const int* __restrict__ eicol,
                const float* __restrict__ ea, const float* __restrict__ dis,
                const int* __restrict__ rowstart, const int* __restrict__ sorted,
                f16* __restrict__ agg)
{
    __shared__ int   cbuf[256];
    __shared__ float wbuf[256];
    __shared__ float part[4][512];
    const int i = blockIdx.x;
    const int tid = threadIdx.x;
    const int lane = tid & 63, wv = tid >> 6;
    const float di = dis[i];
    const int s = rowstart[i];
    const int deg = rowstart[i + 1] - s;

    float acc[8] = {};
    for (int base = 0; base < deg; base += 256) {
        const int m = min(256, deg - base);
        if (tid < m) {
            const int e = sorted[s + base + tid];
            const int c = eicol[e];
            cbuf[tid] = c;
            wbuf[tid] = di * ea[e] * dis[c];
        }
        __syncthreads();
        #pragma unroll 2
        for (int p = wv; p < m; p += 4) {
            const int c = cbuf[p];
            const float w = wbuf[p];
            const f16x8 v = *(const f16x8*)(srcf_h + (size_t)c * DMODEL + lane * 8);
            #pragma unroll
            for (int j = 0; j < 8; ++j) acc[j] = fmaf(w, (float)v[j], acc[j]);
        }
        __syncthreads();
    }
    #pragma unroll
    for (int j = 0; j < 8; ++j) part[wv][lane * 8 + j] = acc[j];
    __syncthreads();
    // final: thread t covers cols 2t, 2t+1
    const float wself = di * di;
    const f16x2 vs = *(const f16x2*)(srcf_h + (size_t)i * DMODEL + tid * 2);
    float a0 = wself * (float)vs[0], a1 = wself * (float)vs[1];
    #pragma unroll
    for (int w = 0; w < 4; ++w) {
        a0 += part[w][tid * 2];
        a1 += part[w][tid * 2 + 1];
    }
    f16x2 o;
    o[0] = (f16)fmaxf(a0, 0.f);
    o[1] = (f16)fmaxf(a1, 0.f);
    *(f16x2*)(agg + (size_t)i * DMODEL + tid * 2) = o;
}

// ---------------------------------------------------------------------------
// Workspace layout (bytes). Base peak = 152,285,888; kv_part appended with
// runtime guard (-> 175,325,888). f32 trunk removed; all-f16 activations.
// Lifetimes:
//   [0, 20.48M)        h_h f16 (steps 1-6: GEMM2 input + LN1 residual)
//   [20.48M, 40.96M)   ff f16 (8-12: LN2 in-place -> agg gather source)
//   [40.96M, 102.4M)   qkv f16 (2-3); src2 f16 @40.96M (5-9: LN1 out, GEMM7
//                      input, LN2 residual); ffh f16 @61.44M (7-8);
//                      agg f16 @61.44M (12-13)
//   [102.4M, 143.36M)  x_h (0b-1), q_all f16 (3-5, in-place attn out)
//   [143.36M, ...)     Wt_*, kvg, deg, dis, rs, cur, cnt, sorted, kv_part
// GEMM A reads up to 96 rows past M=20000 (unguarded); every A buffer has
// allocated slack behind it (verified per-buffer).
// ---------------------------------------------------------------------------
static constexpr size_t OFF_HH    = 0;              // f16 20,480,000
static constexpr size_t OFF_FF    = 20480000ull;    // f16 20,480,000
static constexpr size_t OFF_QKV   = 40960000ull;    // f16 61,440,000
static constexpr size_t OFF_SRC2  = 40960000ull;    // f16 20,480,000 (alias)
static constexpr size_t OFF_FFH   = 61440000ull;    // f16 81,920,000 (alias)
static constexpr size_t OFF_AGG   = 61440000ull;    // f16 40,960,000 (alias)
static constexpr size_t OFF_XH    = 102400000ull;   // f16 10,240,000
static constexpr size_t OFF_ATTN  = 102400000ull;   // f16 40,960,000 (alias)
static constexpr size_t WT_IN     = 143360000ull;   //   262,144
static constexpr size_t WT_QKV    = 143622144ull;   // 1,572,864
static constexpr size_t WT_PROJ   = 145195008ull;   // 1,048,576
static constexpr size_t WT_W1     = 146243584ull;   // 2,097,152
static constexpr size_t WT_W2     = 148340736ull;   // 2,097,152
static constexpr size_t WT_OUT    = 150437888ull;   //   131,072
static constexpr size_t OFF_KV    = 150568960ull;   //    36,864
static constexpr size_t OFF_DEG   = 150605824ull;
static constexpr size_t OFF_DIS   = 150685824ull;
static constexpr size_t OFF_RS    = 150765824ull;
static constexpr size_t OFF_CUR   = 150845888ull;
static constexpr size_t OFF_CNT   = 150925888ull;
static constexpr size_t OFF_SORT  = 151005888ull;   // 1,280,000 -> 152,285,888
static constexpr size_t OFF_KVP   = 152285888ull;   // 23,040,000 -> 175,325,888
static constexpr size_t WS_NEED_KVP = 175325888ull;

extern "C" void kernel_launch(void* const* d_in, const int* in_sizes, int n_in,
                              void* d_out, int out_size, void* d_ws, size_t ws_size,
                              hipStream_t stream)
{
    const float* x      = (const float*)d_in[0];
    const int*   ei     = (const int*)d_in[1];
    const float* ea     = (const float*)d_in[2];
    const float* pe     = (const float*)d_in[4];
    const float* W_in   = (const float*)d_in[5];
    const float* b_in   = (const float*)d_in[6];
    const float* W_qkv  = (const float*)d_in[7];
    const float* conv_w = (const float*)d_in[8];
    const float* W_proj = (const float*)d_in[9];
    const float* b_proj = (const float*)d_in[10];
    const float* g1     = (const float*)d_in[11];
    const float* beta1  = (const float*)d_in[12];
    const float* W1     = (const float*)d_in[13];
    const float* bf1    = (const float*)d_in[14];
    const float* W2     = (const float*)d_in[15];
    const float* bf2    = (const float*)d_in[16];
    const float* g2     = (const float*)d_in[17];
    const float* beta2  = (const float*)d_in[18];
    const float* W_out  = (const float*)d_in[19];
    const float* b_out  = (const float*)d_in[20];

    char* ws = (char*)d_ws;
    f16*   h_h    = (f16*)(ws + OFF_HH);
    f16*   ff     = (f16*)(ws + OFF_FF);
    f16*   qkv    = (f16*)(ws + OFF_QKV);
    f16*   src2   = (f16*)(ws + OFF_SRC2);
    f16*   ffh    = (f16*)(ws + OFF_FFH);
    f16*   agg    = (f16*)(ws + OFF_AGG);
    f16*   x_h    = (f16*)(ws + OFF_XH);
    f16*   q_all  = (f16*)(ws + OFF_ATTN);
    f16*   wt_in   = (f16*)(ws + WT_IN);
    f16*   wt_qkv  = (f16*)(ws + WT_QKV);
    f16*   wt_proj = (f16*)(ws + WT_PROJ);
    f16*   wt_w1   = (f16*)(ws + WT_W1);
    f16*   wt_w2   = (f16*)(ws + WT_W2);
    f16*   wt_out  = (f16*)(ws + WT_OUT);
    float* kvg    = (float*)(ws + OFF_KV);
    float* deg    = (float*)(ws + OFF_DEG);
    float* dis    = (float*)(ws + OFF_DIS);
    int*   rs     = (int*)(ws + OFF_RS);
    int*   cur    = (int*)(ws + OFF_CUR);
    int*   cnt    = (int*)(ws + OFF_CNT);
    int*   sorted = (int*)(ws + OFF_SORT);
    float* outp   = (float*)d_out;

    const bool twoStage = (ws_size >= WS_NEED_KVP);
    float* kv_part = twoStage ? (float*)(ws + OFF_KVP) : nullptr;

    const int* eirow = ei;
    const int* eicol = ei + N_EDGES;

    if (!twoStage)
        hipMemsetAsync(kvg, 0, 9216 * sizeof(float), stream);
    hipMemsetAsync(cnt, 0, N_NODES * sizeof(int), stream);

    // 0. weight transpose+convert (f32 [K][N] -> f16 [N][K])
    wt_kernel<<<dim3(DIN / 32,   DMODEL / 32), 256, 0, stream>>>(W_in,   wt_in,   DIN,    DMODEL);
    wt_kernel<<<dim3(DMODEL / 32, TD / 32),    256, 0, stream>>>(W_qkv,  wt_qkv,  DMODEL, TD);
    wt_kernel<<<dim3(1024 / 32,  DMODEL / 32), 256, 0, stream>>>(W_proj, wt_proj, 1024,   DMODEL);
    wt_kernel<<<dim3(DMODEL / 32, FFD / 32),   256, 0, stream>>>(W1,     wt_w1,   DMODEL, FFD);
    wt_kernel<<<dim3(FFD / 32,   DMODEL / 32), 256, 0, stream>>>(W2,     wt_w2,   FFD,    DMODEL);
    wt_kernel<<<dim3(DMODEL / 32, DOUT / 32),  256, 0, stream>>>(W_out,  wt_out,  DMODEL, DOUT);
    // 0b. x -> f16
    f2h_kernel<<<(N_NODES * DIN) / 1024, 256, 0, stream>>>(x, x_h, N_NODES * DIN);

    const int GY = (N_NODES + 127) / 128;   // 157

    // 1. h_h = f16(x@W_in + b_in + pe)
    gemm_mfma<f16, 1, 1, 0><<<dim3(DMODEL / 128, GY), 256, 0, stream>>>(
        x_h, wt_in, b_in, pe, h_h, nullptr, N_NODES, DMODEL, DIN);
    // 2. qkv = h_h@W_qkv (f16)
    gemm_mfma<f16, 0, 0, 0><<<dim3(TD / 128, GY), 256, 0, stream>>>(
        h_h, wt_qkv, nullptr, nullptr, qkv, nullptr, N_NODES, TD, DMODEL);
    // 3. fused conv + kv partials + q materialization
    kv_fused_kernel<<<KV_BLOCKS, 256, 0, stream>>>(qkv, conv_w, q_all, kvg, kv_part);
    if (twoStage)
        kv_reduce_kernel<<<36, 256, 0, stream>>>(kv_part, kvg);
    // 4. attention readout (in-place over q_all)
    attn_o_kernel<<<2500, 256, 0, stream>>>(q_all, kvg, q_all);
    // 5. src2 = attn_o@W_proj + b_proj (f16)
    gemm_mfma<f16, 1, 0, 0><<<dim3(DMODEL / 128, GY), 256, 0, stream>>>(
        q_all, wt_proj, b_proj, nullptr, src2, nullptr, N_NODES, DMODEL, 1024);
    // 6. src2 = f16(h_h + LN(src2))  (in-place)
    ln_res_kernel<<<N_NODES, 256, 0, stream>>>(src2, h_h, g1, beta1, src2);
    // 7. ffh = relu(src2@W1 + bf1) (f16)
    gemm_mfma<f16, 1, 0, 1><<<dim3(FFD / 128, GY), 256, 0, stream>>>(
        src2, wt_w1, bf1, nullptr, ffh, nullptr, N_NODES, FFD, DMODEL);
    // 8. ff = ffh@W2 + bf2 (f16)
    gemm_mfma<f16, 1, 0, 0><<<dim3(DMODEL / 128, GY), 256, 0, stream>>>(
        ffh, wt_w2, bf2, nullptr, ff, nullptr, N_NODES, DMODEL, FFD);
    // 9. ff = f16(src2 + LN(ff))  (in-place; agg gather source)
    ln_res_kernel<<<N_NODES, 256, 0, stream>>>(ff, src2, g2, beta2, ff);
    // 10. degree / normalization
    deg_init_kernel<<<(N_NODES + 255) / 256, 256, 0, stream>>>(deg);
    deg_acc_kernel<<<(N_EDGES + 255) / 256, 256, 0, stream>>>(eirow, ea, deg);
    dis_kernel<<<(N_NODES + 255) / 256, 256, 0, stream>>>(deg, dis);
    // 11. counting sort of edges by destination row
    count_kernel<<<(N_EDGES + 255) / 256, 256, 0, stream>>>(eirow, cnt);
    scan_kernel<<<1, 1024, 0, stream>>>(cnt, rs, cur);
    scatter_kernel<<<(N_EDGES + 255) / 256, 256, 0, stream>>>(eirow, cur, sorted);
    // 12. aggregation (4-wave, LDS-prefetched metadata, f16x8 gathers)
    agg_kernel<<<N_NODES, 256, 0, stream>>>(ff, eicol, ea, dis, rs, sorted, agg);
    // 13. out = relu(agg)@W_out + b_out (f32)
    gemm_mfma<float, 1, 0, 0><<<dim3(DOUT / 128, GY), 256, 0, stream>>>(
        agg, wt_out, b_out, nullptr, outp, nullptr, N_NODES, DOUT, DMODEL);
}

// Round 13
// 684.005 us; speedup vs baseline: 5.4277x; 1.0293x over previous
//
#include <hip/hip_runtime.h>

#define N_NODES 20000
#define N_EDGES 320000
#define DIN     256
#define DMODEL  512
#define TD      1536   // 3*D
#define FFD     2048
#define DOUT    128

typedef _Float16 f16;
typedef f16 f16x8 __attribute__((ext_vector_type(8)));
typedef f16 f16x4 __attribute__((ext_vector_type(4)));
typedef f16 f16x2 __attribute__((ext_vector_type(2)));
typedef float f32x4 __attribute__((ext_vector_type(4)));

__device__ __forceinline__ void cstore(float* p, float v) { *p = v; }
__device__ __forceinline__ void cstore(f16* p, float v)   { *p = (f16)v; }

#if defined(__has_builtin)
#if __has_builtin(__builtin_amdgcn_global_load_lds)
#define USE_GLOAD_LDS 1
#endif
#endif

// ---------------------------------------------------------------------------
// fp16 MFMA GEMM v3: 128x128 tile, BK=32, 4 waves, mfma_f32_16x16x32_f16.
// 2-phase DOUBLE-BUFFERED K-loop with counted vmcnt(4): next tile's 4
// global_load_lds stay in flight across a RAW s_barrier while the current
// tile computes — HBM latency hides under ds_read+MFMA (T3-min + T4).
// Pre-swizzled source (kc ^= (row>>1)&3), linear LDS dest (m173 pattern).
// A rows read unguarded to the 128-aligned tile edge (allocated slack).
// K%32==0, N%128==0, M guarded at C-write.
// ---------------------------------------------------------------------------
template<typename TC, int HAS_BIAS, int HAS_ADD, int DO_RELU>
__global__ __launch_bounds__(256)
void gemm_mfma(const f16* __restrict__ A, const f16* __restrict__ Bt,
               const float* __restrict__ bias, const float* __restrict__ addmat,
               TC* __restrict__ C, f16* __restrict__ Cbf,
               int M, int N, int K)
{
    __shared__ f16 As[2][128 * 32];
    __shared__ f16 Bs[2][128 * 32];
    const int tid  = threadIdx.x;
    const int lane = tid & 63;
    const int wid  = tid >> 6;
    const int wm = wid >> 1, wn = wid & 1;
    const int m0 = blockIdx.y * 128, n0 = blockIdx.x * 128;

    f32x4 acc[4][4];
    #pragma unroll
    for (int i = 0; i < 4; ++i)
        #pragma unroll
        for (int j = 0; j < 4; ++j)
            acc[i][j] = (f32x4)0.0f;

    const int r  = lane & 15;
    const int kg = lane >> 4;
    const int px = (kg ^ ((r >> 1) & 3)) << 3;

#ifdef USE_GLOAD_LDS
    // per-wave staging geometry (loop-invariant)
    const int seg0 = wid * 2, seg1 = wid * 2 + 1;       // 16 rows each
    const int row0 = seg0 * 16 + (lane >> 2);
    const int row1 = seg1 * 16 + (lane >> 2);
    const int kc0  = (lane & 3) ^ ((row0 >> 1) & 3);    // pre-swizzled chunk
    const int kc1  = (lane & 3) ^ ((row1 >> 1) & 3);
    const f16* a0 = A  + (size_t)(m0 + row0) * K + kc0 * 8;
    const f16* a1 = A  + (size_t)(m0 + row1) * K + kc1 * 8;
    const f16* b0 = Bt + (size_t)(n0 + row0) * K + kc0 * 8;
    const f16* b1 = Bt + (size_t)(n0 + row1) * K + kc1 * 8;

    auto stage = [&](int buf, int k0) {
        __builtin_amdgcn_global_load_lds(
            (const __attribute__((address_space(1))) void*)(a0 + k0),
            (__attribute__((address_space(3))) void*)&As[buf][seg0 * 512], 16, 0, 0);
        __builtin_amdgcn_global_load_lds(
            (const __attribute__((address_space(1))) void*)(a1 + k0),
            (__attribute__((address_space(3))) void*)&As[buf][seg1 * 512], 16, 0, 0);
        __builtin_amdgcn_global_load_lds(
            (const __attribute__((address_space(1))) void*)(b0 + k0),
            (__attribute__((address_space(3))) void*)&Bs[buf][seg0 * 512], 16, 0, 0);
        __builtin_amdgcn_global_load_lds(
            (const __attribute__((address_space(1))) void*)(b1 + k0),
            (__attribute__((address_space(3))) void*)&Bs[buf][seg1 * 512], 16, 0, 0);
    };

    const int NT = K >> 5;
    stage(0, 0);
    for (int kt = 0; kt < NT; ++kt) {
        const int cur = kt & 1;
        if (kt + 1 < NT) {
            stage(cur ^ 1, (kt + 1) << 5);
            asm volatile("s_waitcnt vmcnt(4)" ::: "memory");   // cur loads done; next in flight
        } else {
            asm volatile("s_waitcnt vmcnt(0)" ::: "memory");
        }
        __builtin_amdgcn_s_barrier();
        __builtin_amdgcn_sched_barrier(0);
        f16x8 af[4], bfr[4];
        #pragma unroll
        for (int m = 0; m < 4; ++m)
            af[m] = *(const f16x8*)(&As[cur][(wm * 64 + m * 16 + r) * 32 + px]);
        #pragma unroll
        for (int n = 0; n < 4; ++n)
            bfr[n] = *(const f16x8*)(&Bs[cur][(wn * 64 + n * 16 + r) * 32 + px]);
        #pragma unroll
        for (int m = 0; m < 4; ++m)
            #pragma unroll
            for (int n = 0; n < 4; ++n)
                acc[m][n] = __builtin_amdgcn_mfma_f32_16x16x32_f16(
                    af[m], bfr[n], acc[m][n], 0, 0, 0);
        __builtin_amdgcn_sched_barrier(0);
        __builtin_amdgcn_s_barrier();
    }
#else
    for (int k0 = 0; k0 < K; k0 += 32) {
        #pragma unroll
        for (int it = 0; it < 2; ++it) {
            const int c   = tid + it * 256;
            const int row = c >> 2, kc = c & 3;
            const int widx = row * 32 + ((kc ^ ((row >> 1) & 3)) << 3);
            f16x8 va = {0, 0, 0, 0, 0, 0, 0, 0};
            const int ga = m0 + row;
            if (ga < M) va = *(const f16x8*)(A + (size_t)ga * K + k0 + kc * 8);
            *(f16x8*)(&As[0][widx]) = va;
            const f16x8 vb = *(const f16x8*)(Bt + (size_t)(n0 + row) * K + k0 + kc * 8);
            *(f16x8*)(&Bs[0][widx]) = vb;
        }
        __syncthreads();
        f16x8 af[4], bfr[4];
        #pragma unroll
        for (int m = 0; m < 4; ++m)
            af[m] = *(const f16x8*)(&As[0][(wm * 64 + m * 16 + r) * 32 + px]);
        #pragma unroll
        for (int n = 0; n < 4; ++n)
            bfr[n] = *(const f16x8*)(&Bs[0][(wn * 64 + n * 16 + r) * 32 + px]);
        #pragma unroll
        for (int m = 0; m < 4; ++m)
            #pragma unroll
            for (int n = 0; n < 4; ++n)
                acc[m][n] = __builtin_amdgcn_mfma_f32_16x16x32_f16(
                    af[m], bfr[n], acc[m][n], 0, 0, 0);
        __syncthreads();
    }
#endif

    const int rq = lane >> 4;
    #pragma unroll
    for (int m = 0; m < 4; ++m) {
        #pragma unroll
        for (int rr = 0; rr < 4; ++rr) {
            const int row = m0 + wm * 64 + m * 16 + rq * 4 + rr;
            if (row >= M) continue;
            #pragma unroll
            for (int n = 0; n < 4; ++n) {
                const int col = n0 + wn * 64 + n * 16 + (lane & 15);
                float v = acc[m][n][rr];
                if (HAS_BIAS) v += bias[col];
                if (HAS_ADD)  v += addmat[(size_t)row * N + col];
                if (DO_RELU)  v = fmaxf(v, 0.f);
                cstore(&C[(size_t)row * N + col], v);
                if (Cbf) Cbf[(size_t)row * N + col] = (f16)v;
            }
        }
    }
}

// ---------------------------------------------------------------------------
// Weight transpose+convert: W[K][N] f32 -> Wt[N][K] f16. 32x32 LDS tiles.
// ---------------------------------------------------------------------------
__global__ void wt_kernel(const float* __restrict__ W, f16* __restrict__ Wt, int K, int N)
{
    __shared__ float t[32][33];
    const int k0 = blockIdx.x * 32, n0 = blockIdx.y * 32;
    const int tx = threadIdx.x & 31, ty = threadIdx.x >> 5;
    #pragma unroll
    for (int i = ty; i < 32; i += 8) {
        const int k = k0 + i;
        if (k < K && n0 + tx < N) t[i][tx] = W[(size_t)k * N + n0 + tx];
    }
    __syncthreads();
    #pragma unroll
    for (int i = ty; i < 32; i += 8) {
        const int n = n0 + i;
        if (n < N && k0 + tx < K) Wt[(size_t)n * K + k0 + tx] = (f16)t[tx][i];
    }
}

// f32 -> f16 elementwise (n % 4 == 0)
__global__ void f2h_kernel(const float* __restrict__ in, f16* __restrict__ out, int n)
{
    const int i = (blockIdx.x * 256 + threadIdx.x) * 4;
    if (i < n) {
        const float4 v = *(const float4*)(in + i);
        out[i + 0] = (f16)v.x; out[i + 1] = (f16)v.y;
        out[i + 2] = (f16)v.z; out[i + 3] = (f16)v.w;
    }
}

// ---------------------------------------------------------------------------
// Fused conv + kv-sum + q materialization (unchanged).
// ---------------------------------------------------------------------------
#define KV_CHUNK 32
#define KV_BLOCKS (N_NODES / KV_CHUNK)   // 625
__global__ __launch_bounds__(256, 2)
void kv_fused_kernel(const f16* __restrict__ qkv, const float* __restrict__ cw,
                     f16* __restrict__ q_all, float* __restrict__ kvg,
                     float* __restrict__ kv_part)
{
    __shared__ f16 rows[5][TD];
    const int tid = threadIdx.x;
    const int n0 = blockIdx.x * KV_CHUNK;
    const int h = tid >> 1, d0 = (tid & 1) * 4;

    float wk[4][5], wv[8][5], wq[8][5];
    if (h >= 64) {
        const int cb = (h - 64) * 24;
        #pragma unroll
        for (int dd = 0; dd < 4; ++dd)
            #pragma unroll
            for (int t = 0; t < 5; ++t)
                wk[dd][t] = cw[(cb + 8 + d0 + dd) * 5 + t];
        #pragma unroll
        for (int e = 0; e < 8; ++e)
            #pragma unroll
            for (int t = 0; t < 5; ++t)
                wv[e][t] = cw[(cb + 16 + e) * 5 + t];
    }
    if (tid >= 64 && tid < 128) {
        const int cb = (tid - 64) * 24;
        #pragma unroll
        for (int d = 0; d < 8; ++d)
            #pragma unroll
            for (int t = 0; t < 5; ++t)
                wq[d][t] = cw[(cb + d) * 5 + t];
    }

    for (int r = n0 - 2; r <= n0 + 2; ++r) {
        const int slot = ((r % 5) + 5) % 5;
        if (tid < 192) {
            f16x8 v = {0, 0, 0, 0, 0, 0, 0, 0};
            if (r >= 0 && r < N_NODES)
                v = *(const f16x8*)(qkv + (size_t)r * TD + tid * 8);
            *(f16x8*)(&rows[slot][tid * 8]) = v;
        }
    }
    __syncthreads();

    float acc[36] = {};

    for (int i = 0; i < KV_CHUNK; ++i) {
        const int n = n0 + i;

        f16x8 pre = {0, 0, 0, 0, 0, 0, 0, 0};
        const bool doPre = (i < KV_CHUNK - 1) && (tid < 192);
        if (doPre && (n + 3) < N_NODES)
            pre = *(const f16x8*)(qkv + (size_t)(n + 3) * TD + tid * 8);

        const f16* wr[5] = { rows[(((n - 2) % 5) + 5) % 5],
                             rows[(((n - 1) % 5) + 5) % 5],
                             rows[n % 5],
                             rows[(n + 1) % 5],
                             rows[(n + 2) % 5] };

        float kv4[4], vv[8];
        if (h < 64) {
            const int cb = h * 24;
            const f16x4 kd = *(const f16x4*)(wr[2] + cb + 8 + d0);
            const f16x8 vd = *(const f16x8*)(wr[2] + cb + 16);
            #pragma unroll
            for (int dd = 0; dd < 4; ++dd) kv4[dd] = fmaxf((float)kd[dd], 0.f);
            #pragma unroll
            for (int e = 0; e < 8; ++e) vv[e] = (float)vd[e];
        } else {
            const int cb = (h - 64) * 24;
            f16x4 ka[5]; f16x8 va[5];
            #pragma unroll
            for (int t = 0; t < 5; ++t) {
                ka[t] = *(const f16x4*)(wr[t] + cb + 8 + d0);
                va[t] = *(const f16x8*)(wr[t] + cb + 16);
            }
            #pragma unroll
            for (int dd = 0; dd < 4; ++dd) {
                float s = 0.f;
                #pragma unroll
                for (int t = 0; t < 5; ++t) s = fmaf(wk[dd][t], (float)ka[t][dd], s);
                kv4[dd] = fmaxf(s, 0.f);
            }
            #pragma unroll
            for (int e = 0; e < 8; ++e) {
                float s = 0.f;
                #pragma unroll
                for (int t = 0; t < 5; ++t) s = fmaf(wv[e][t], (float)va[t][e], s);
                vv[e] = s;
            }
        }
        #pragma unroll
        for (int dd = 0; dd < 4; ++dd) {
            #pragma unroll
            for (int e = 0; e < 8; ++e)
                acc[dd * 9 + e] = fmaf(kv4[dd], vv[e], acc[dd * 9 + e]);
            acc[dd * 9 + 8] += kv4[dd];
        }

        if (tid < 128) {
            f16x8 qv;
            if (tid < 64) {
                qv = *(const f16x8*)(wr[2] + tid * 24);
                #pragma unroll
                for (int d = 0; d < 8; ++d)
                    qv[d] = qv[d] > (f16)0 ? qv[d] : (f16)0;
            } else {
                const int cb = (tid - 64) * 24;
                f16x8 qa[5];
                #pragma unroll
                for (int t = 0; t < 5; ++t) qa[t] = *(const f16x8*)(wr[t] + cb);
                #pragma unroll
                for (int d = 0; d < 8; ++d) {
                    float s = 0.f;
                    #pragma unroll
                    for (int t = 0; t < 5; ++t) s = fmaf(wq[d][t], (float)qa[t][d], s);
                    qv[d] = (f16)fmaxf(s, 0.f);
                }
            }
            *(f16x8*)(q_all + (size_t)n * 1024 + tid * 8) = qv;
        }

        __syncthreads();
        if (doPre)
            *(f16x8*)(&rows[(n + 3) % 5][tid * 8]) = pre;
        __syncthreads();
    }

    if (kv_part) {
        float* dst = kv_part + (size_t)blockIdx.x * 9216 + tid * 36;
        #pragma unroll
        for (int i = 0; i < 36; ++i) dst[i] = acc[i];
    } else {
        #pragma unroll
        for (int dd = 0; dd < 4; ++dd)
            #pragma unroll
            for (int e = 0; e < 9; ++e)
                atomicAdd(&kvg[h * 72 + (d0 + dd) * 9 + e], acc[dd * 9 + e]);
    }
}

// kvg[j] = sum_b kv_part[b][j], j in [0,9216). Grid: 36 x 256.
__global__ void kv_reduce_kernel(const float* __restrict__ kv_part,
                                 float* __restrict__ kvg)
{
    const int j = blockIdx.x * 256 + threadIdx.x;
    float s = 0.f;
    for (int b = 0; b < KV_BLOCKS; ++b)
        s += kv_part[(size_t)b * 9216 + j];
    kvg[j] = s;
}

// ---------------------------------------------------------------------------
// o[n, h*8+e] = (sum_d q*kv[h,d,e]) / (sum_d q*kv[h,d,8] + 1e-15)
// ---------------------------------------------------------------------------
__global__ __launch_bounds__(256)
void attn_o_kernel(const f16* __restrict__ q_all, const float* __restrict__ kvg,
                   f16* __restrict__ o)
{
    __shared__ float kvt[72][128];   // [d*9+e][h]
    const int tid = threadIdx.x;
    for (int i = tid; i < 9216; i += 256) {
        const int hh = i & 127, j = i >> 7;
        kvt[j][hh] = kvg[hh * 72 + j];
    }
    __syncthreads();
    const int h = tid & 127, sub = tid >> 7;
    for (int nb = blockIdx.x; nb < N_NODES / 2; nb += gridDim.x) {
        const int n = nb * 2 + sub;
        const f16x8 qv8 = *(const f16x8*)(q_all + (size_t)n * 1024 + h * 8);
        float q[8];
        #pragma unroll
        for (int d = 0; d < 8; ++d) q[d] = (float)qv8[d];
        float num[8], den = 0.f;
        #pragma unroll
        for (int e = 0; e < 8; ++e) {
            float s = 0.f;
            #pragma unroll
            for (int d = 0; d < 8; ++d) s = fmaf(q[d], kvt[d * 9 + e][h], s);
            num[e] = s;
        }
        #pragma unroll
        for (int d = 0; d < 8; ++d) den = fmaf(q[d], kvt[d * 9 + 8][h], den);
        const float rinv = 1.f / (den + 1e-15f);
        f16x8 ov;
        #pragma unroll
        for (int e = 0; e < 8; ++e) ov[e] = (f16)(num[e] * rinv);
        *(f16x8*)(o + (size_t)n * 1024 + h * 8) = ov;
    }
}

// ---------------------------------------------------------------------------
// out_h = f16(resid + LN(y)*g + b). resid f16. out_h may alias y.
// ---------------------------------------------------------------------------
__global__ void ln_res_kernel(const f16* __restrict__ y, const f16* __restrict__ resid,
                              const float* __restrict__ g, const float* __restrict__ b,
                              f16* __restrict__ out_h)
{
    const int row = blockIdx.x;
    const int tid = threadIdx.x;
    const f16* yr = y + (size_t)row * DMODEL;
    const float v0 = (float)yr[tid], v1 = (float)yr[tid + 256];
    __shared__ float red[4], red2[4];
    float s = v0 + v1;
    #pragma unroll
    for (int o = 32; o > 0; o >>= 1) s += __shfl_down(s, o);
    if ((tid & 63) == 0) red[tid >> 6] = s;
    __syncthreads();
    const float mean = (red[0] + red[1] + red[2] + red[3]) * (1.0f / DMODEL);
    const float d0 = v0 - mean, d1 = v1 - mean;
    float q = d0 * d0 + d1 * d1;
    #pragma unroll
    for (int o = 32; o > 0; o >>= 1) q += __shfl_down(q, o);
    if ((tid & 63) == 0) red2[tid >> 6] = q;
    __syncthreads();
    const float var = (red2[0] + red2[1] + red2[2] + red2[3]) * (1.0f / DMODEL);
    const float inv = rsqrtf(var + 1e-5f);
    const f16* rr = resid + (size_t)row * DMODEL;
    const float o0 = (float)rr[tid]       + d0 * inv * g[tid]       + b[tid];
    const float o1 = (float)rr[tid + 256] + d1 * inv * g[tid + 256] + b[tid + 256];
    f16* oh = out_h + (size_t)row * DMODEL;
    oh[tid] = (f16)o0;
    oh[tid + 256] = (f16)o1;
}

// ---------------------------------------------------------------------------
// Graph normalization + counting sort
// ---------------------------------------------------------------------------
__global__ void deg_init_kernel(float* __restrict__ deg)
{
    const int i = blockIdx.x * 256 + threadIdx.x;
    if (i < N_NODES) deg[i] = 1.0f;
}

__global__ void deg_acc_kernel(const int* __restrict__ eirow, const float* __restrict__ ea,
                               float* __restrict__ deg)
{
    const int e = blockIdx.x * 256 + threadIdx.x;
    if (e < N_EDGES) atomicAdd(&deg[eirow[e]], ea[e]);
}

__global__ void dis_kernel(const float* __restrict__ deg, float* __restrict__ dis)
{
    const int i = blockIdx.x * 256 + threadIdx.x;
    if (i < N_NODES) dis[i] = rsqrtf(deg[i]);
}

__global__ void count_kernel(const int* __restrict__ eirow, int* __restrict__ cnt)
{
    const int e = blockIdx.x * 256 + threadIdx.x;
    if (e < N_EDGES) atomicAdd(&cnt[eirow[e]], 1);
}

__global__ void scan_kernel(const int* __restrict__ cnt, int* __restrict__ rowstart,
                            int* __restrict__ cursor)
{
    __shared__ int ls[1024];
    const int tid = threadIdx.x;
    const int base = tid * 20;
    int local[20];
    int s = 0;
    #pragma unroll
    for (int i = 0; i < 20; ++i) {
        const int idx = base + i;
        const int v = (idx < N_NODES) ? cnt[idx] : 0;
        local[i] = s;
        s += v;
    }
    ls[tid] = s;
    __syncthreads();
    for (int off = 1; off < 1024; off <<= 1) {
        const int v = (tid >= off) ? ls[tid - off] : 0;
        __syncthreads();
        ls[tid] += v;
        __syncthreads();
    }
    const int excl = (tid == 0) ? 0 : ls[tid - 1];
    #pragma unroll
    for (int i = 0; i < 20; ++i) {
        const int idx = base + i;
        if (idx < N_NODES) {
            const int st = excl + local[i];
            rowstart[idx] = st;
            cursor[idx] = st;
        }
    }
    if (tid == 1023) rowstart[N_NODES] = ls[1023];
}

__global__ void scatter_kernel(const int* __restrict__ eirow, int* __restrict__ cursor,
                               int* __restrict__ sorted)
{
    const int e = blockIdx.x * 256 + threadIdx.x;
    if (e < N_EDGES) {
        const int r = eirow[e];
        const int p = atomicAdd(&cursor[r], 1);
        sorted[p] = e;
    }
}

// ---------------------------------------------------------------------------
// Aggregation v3 (unchanged): LDS metadata prefetch + 4-wave row gathers.
// ---------------------------------------------------------------------------
__global__ __launch_bounds__(256)
void agg_kernel(const f16* __restrict__ srcf_h, const int* __restrict__ eicol,
                const float* __restrict__ ea, const float* __restrict__ dis,
                const int* __restrict__ rowstart, const int* __restrict__ sorted,
                f16* __restrict__ agg)
{
    __shared__ int   cbuf[256];
    __shared__ float wbuf[256];
    __shared__ float part[4][512];
    const int i = blockIdx.x;
    const int tid = threadIdx.x;
    const int lane = tid & 63, wv = tid >> 6;
    const float di = dis[i];
    const int s = rowstart[i];
    const int deg = rowstart[i + 1] - s;

    float acc[8] = {};
    for (int base = 0; base < deg; base += 256) {
        const int m = min(256, deg - base);
        if (tid < m) {
            const int e = sorted[s + base + tid];
            const int c = eicol[e];
            cbuf[tid] = c;
            wbuf[tid] = di * ea[e] * dis[c];
        }
        __syncthreads();
        #pragma unroll 2
        for (int p = wv; p < m; p += 4) {
            const int c = cbuf[p];
            const float w = wbuf[p];
            const f16x8 v = *(const f16x8*)(srcf_h + (size_t)c * DMODEL + lane * 8);
            #pragma unroll
            for (int j = 0; j < 8; ++j) acc[j] = fmaf(w, (float)v[j], acc[j]);
        }
        __syncthreads();
    }
    #pragma unroll
    for (int j = 0; j < 8; ++j) part[wv][lane * 8 + j] = acc[j];
    __syncthreads();
    const float wself = di * di;
    const f16x2 vs = *(const f16x2*)(srcf_h + (size_t)i * DMODEL + tid * 2);
    float a0 = wself * (float)vs[0], a1 = wself * (float)vs[1];
    #pragma unroll
    for (int w = 0; w < 4; ++w) {
        a0 += part[w][tid * 2];
        a1 += part[w][tid * 2 + 1];
    }
    f16x2 o;
    o[0] = (f16)fmaxf(a0, 0.f);
    o[1] = (f16)fmaxf(a1, 0.f);
    *(f16x2*)(agg + (size_t)i * DMODEL + tid * 2) = o;
}

// ---------------------------------------------------------------------------
// Workspace layout (bytes) — unchanged from round 12.
// ---------------------------------------------------------------------------
static constexpr size_t OFF_HH    = 0;              // f16 20,480,000
static constexpr size_t OFF_FF    = 20480000ull;    // f16 20,480,000
static constexpr size_t OFF_QKV   = 40960000ull;    // f16 61,440,000
static constexpr size_t OFF_SRC2  = 40960000ull;    // f16 20,480,000 (alias)
static constexpr size_t OFF_FFH   = 61440000ull;    // f16 81,920,000 (alias)
static constexpr size_t OFF_AGG   = 61440000ull;    // f16 40,960,000 (alias)
static constexpr size_t OFF_XH    = 102400000ull;   // f16 10,240,000
static constexpr size_t OFF_ATTN  = 102400000ull;   // f16 40,960,000 (alias)
static constexpr size_t WT_IN     = 143360000ull;
static constexpr size_t WT_QKV    = 143622144ull;
static constexpr size_t WT_PROJ   = 145195008ull;
static constexpr size_t WT_W1     = 146243584ull;
static constexpr size_t WT_W2     = 148340736ull;
static constexpr size_t WT_OUT    = 150437888ull;
static constexpr size_t OFF_KV    = 150568960ull;
static constexpr size_t OFF_DEG   = 150605824ull;
static constexpr size_t OFF_DIS   = 150685824ull;
static constexpr size_t OFF_RS    = 150765824ull;
static constexpr size_t OFF_CUR   = 150845888ull;
static constexpr size_t OFF_CNT   = 150925888ull;
static constexpr size_t OFF_SORT  = 151005888ull;   // -> 152,285,888
static constexpr size_t OFF_KVP   = 152285888ull;   // -> 175,325,888
static constexpr size_t WS_NEED_KVP = 175325888ull;

extern "C" void kernel_launch(void* const* d_in, const int* in_sizes, int n_in,
                              void* d_out, int out_size, void* d_ws, size_t ws_size,
                              hipStream_t stream)
{
    const float* x      = (const float*)d_in[0];
    const int*   ei     = (const int*)d_in[1];
    const float* ea     = (const float*)d_in[2];
    const float* pe     = (const float*)d_in[4];
    const float* W_in   = (const float*)d_in[5];
    const float* b_in   = (const float*)d_in[6];
    const float* W_qkv  = (const float*)d_in[7];
    const float* conv_w = (const float*)d_in[8];
    const float* W_proj = (const float*)d_in[9];
    const float* b_proj = (const float*)d_in[10];
    const float* g1     = (const float*)d_in[11];
    const float* beta1  = (const float*)d_in[12];
    const float* W1     = (const float*)d_in[13];
    const float* bf1    = (const float*)d_in[14];
    const float* W2     = (const float*)d_in[15];
    const float* bf2    = (const float*)d_in[16];
    const float* g2     = (const float*)d_in[17];
    const float* beta2  = (const float*)d_in[18];
    const float* W_out  = (const float*)d_in[19];
    const float* b_out  = (const float*)d_in[20];

    char* ws = (char*)d_ws;
    f16*   h_h    = (f16*)(ws + OFF_HH);
    f16*   ff     = (f16*)(ws + OFF_FF);
    f16*   qkv    = (f16*)(ws + OFF_QKV);
    f16*   src2   = (f16*)(ws + OFF_SRC2);
    f16*   ffh    = (f16*)(ws + OFF_FFH);
    f16*   agg    = (f16*)(ws + OFF_AGG);
    f16*   x_h    = (f16*)(ws + OFF_XH);
    f16*   q_all  = (f16*)(ws + OFF_ATTN);
    f16*   wt_in   = (f16*)(ws + WT_IN);
    f16*   wt_qkv  = (f16*)(ws + WT_QKV);
    f16*   wt_proj = (f16*)(ws + WT_PROJ);
    f16*   wt_w1   = (f16*)(ws + WT_W1);
    f16*   wt_w2   = (f16*)(ws + WT_W2);
    f16*   wt_out  = (f16*)(ws + WT_OUT);
    float* kvg    = (float*)(ws + OFF_KV);
    float* deg    = (float*)(ws + OFF_DEG);
    float* dis    = (float*)(ws + OFF_DIS);
    int*   rs     = (int*)(ws + OFF_RS);
    int*   cur    = (int*)(ws + OFF_CUR);
    int*   cnt    = (int*)(ws + OFF_CNT);
    int*   sorted = (int*)(ws + OFF_SORT);
    float* outp   = (float*)d_out;

    const bool twoStage = (ws_size >= WS_NEED_KVP);
    float* kv_part = twoStage ? (float*)(ws + OFF_KVP) : nullptr;

    const int* eirow = ei;
    const int* eicol = ei + N_EDGES;

    if (!twoStage)
        hipMemsetAsync(kvg, 0, 9216 * sizeof(float), stream);
    hipMemsetAsync(cnt, 0, N_NODES * sizeof(int), stream);

    // 0. weight transpose+convert (f32 [K][N] -> f16 [N][K])
    wt_kernel<<<dim3(DIN / 32,   DMODEL / 32), 256, 0, stream>>>(W_in,   wt_in,   DIN,    DMODEL);
    wt_kernel<<<dim3(DMODEL / 32, TD / 32),    256, 0, stream>>>(W_qkv,  wt_qkv,  DMODEL, TD);
    wt_kernel<<<dim3(1024 / 32,  DMODEL / 32), 256, 0, stream>>>(W_proj, wt_proj, 1024,   DMODEL);
    wt_kernel<<<dim3(DMODEL / 32, FFD / 32),   256, 0, stream>>>(W1,     wt_w1,   DMODEL, FFD);
    wt_kernel<<<dim3(FFD / 32,   DMODEL / 32), 256, 0, stream>>>(W2,     wt_w2,   FFD,    DMODEL);
    wt_kernel<<<dim3(DMODEL / 32, DOUT / 32),  256, 0, stream>>>(W_out,  wt_out,  DMODEL, DOUT);
    // 0b. x -> f16
    f2h_kernel<<<(N_NODES * DIN) / 1024, 256, 0, stream>>>(x, x_h, N_NODES * DIN);

    const int GY = (N_NODES + 127) / 128;   // 157

    // 1. h_h = f16(x@W_in + b_in + pe)
    gemm_mfma<f16, 1, 1, 0><<<dim3(DMODEL / 128, GY), 256, 0, stream>>>(
        x_h, wt_in, b_in, pe, h_h, nullptr, N_NODES, DMODEL, DIN);
    // 2. qkv = h_h@W_qkv (f16)
    gemm_mfma<f16, 0, 0, 0><<<dim3(TD / 128, GY), 256, 0, stream>>>(
        h_h, wt_qkv, nullptr, nullptr, qkv, nullptr, N_NODES, TD, DMODEL);
    // 3. fused conv + kv partials + q materialization
    kv_fused_kernel<<<KV_BLOCKS, 256, 0, stream>>>(qkv, conv_w, q_all, kvg, kv_part);
    if (twoStage)
        kv_reduce_kernel<<<36, 256, 0, stream>>>(kv_part, kvg);
    // 4. attention readout (in-place over q_all)
    attn_o_kernel<<<2500, 256, 0, stream>>>(q_all, kvg, q_all);
    // 5. src2 = attn_o@W_proj + b_proj (f16)
    gemm_mfma<f16, 1, 0, 0><<<dim3(DMODEL / 128, GY), 256, 0, stream>>>(
        q_all, wt_proj, b_proj, nullptr, src2, nullptr, N_NODES, DMODEL, 1024);
    // 6. src2 = f16(h_h + LN(src2))  (in-place)
    ln_res_kernel<<<N_NODES, 256, 0, stream>>>(src2, h_h, g1, beta1, src2);
    // 7. ffh = relu(src2@W1 + bf1) (f16)
    gemm_mfma<f16, 1, 0, 1><<<dim3(FFD / 128, GY), 256, 0, stream>>>(
        src2, wt_w1, bf1, nullptr, ffh, nullptr, N_NODES, FFD, DMODEL);
    // 8. ff = ffh@W2 + bf2 (f16)
    gemm_mfma<f16, 1, 0, 0><<<dim3(DMODEL / 128, GY), 256, 0, stream>>>(
        ffh, wt_w2, bf2, nullptr, ff, nullptr, N_NODES, DMODEL, FFD);
    // 9. ff = f16(src2 + LN(ff))  (in-place; agg gather source)
    ln_res_kernel<<<N_NODES, 256, 0, stream>>>(ff, src2, g2, beta2, ff);
    // 10. degree / normalization
    deg_init_kernel<<<(N_NODES + 255) / 256, 256, 0, stream>>>(deg);
    deg_acc_kernel<<<(N_EDGES + 255) / 256, 256, 0, stream>>>(eirow, ea, deg);
    dis_kernel<<<(N_NODES + 255) / 256, 256, 0, stream>>>(deg, dis);
    // 11. counting sort of edges by destination row
    count_kernel<<<(N_EDGES + 255) / 256, 256, 0, stream>>>(eirow, cnt);
    scan_kernel<<<1, 1024, 0, stream>>>(cnt, rs, cur);
    scatter_kernel<<<(N_EDGES + 255) / 256, 256, 0, stream>>>(eirow, cur, sorted);
    // 12. aggregation
    agg_kernel<<<N_NODES, 256, 0, stream>>>(ff, eicol, ea, dis, rs, sorted, agg);
    // 13. out = relu(agg)@W_out + b_out (f32)
    gemm_mfma<float, 1, 0, 0><<<dim3(DOUT / 128, GY), 256, 0, stream>>>(
        agg, wt_out, b_out, nullptr, outp, nullptr, N_NODES, DOUT, DMODEL);
}

// Round 14
// 622.041 us; speedup vs baseline: 5.9684x; 1.0996x over previous
//
#include <hip/hip_runtime.h>

#define N_NODES 20000
#define N_EDGES 320000
#define DIN     256
#define DMODEL  512
#define TD      1536   // 3*D
#define FFD     2048
#define DOUT    128

typedef _Float16 f16;
typedef f16 f16x8 __attribute__((ext_vector_type(8)));
typedef f16 f16x4 __attribute__((ext_vector_type(4)));
typedef f16 f16x2 __attribute__((ext_vector_type(2)));
typedef float f32x4 __attribute__((ext_vector_type(4)));

__device__ __forceinline__ void cstore(float* p, float v) { *p = v; }
__device__ __forceinline__ void cstore(f16* p, float v)   { *p = (f16)v; }

#if defined(__has_builtin)
#if __has_builtin(__builtin_amdgcn_global_load_lds)
#define USE_GLOAD_LDS 1
#endif
#endif

// ---------------------------------------------------------------------------
// fp16 MFMA GEMM v4: 128x128 tile, BK=32, 4 waves, mfma_f32_16x16x32_f16.
// TRIPLE-buffered K-loop, 2 tiles in flight (vmcnt(8)): issue-to-use distance
// ~2 iterations covers HBM latency (m126 ~900cyc). Raw s_barrier + counted
// vmcnt (T4); pre-swizzled gload_lds source, linear LDS dest (m173).
// f16-C epilogue repacks through LDS -> coalesced f16x8 stores.
// A rows read unguarded to the 128-aligned tile edge (allocated slack).
// K%32==0 (K>=64), N%128==0, M guarded at C-write and addmat-read.
// ---------------------------------------------------------------------------
template<typename TC, int HAS_BIAS, int HAS_ADD, int DO_RELU>
__global__ __launch_bounds__(256)
void gemm_mfma(const f16* __restrict__ A, const f16* __restrict__ Bt,
               const float* __restrict__ bias, const float* __restrict__ addmat,
               TC* __restrict__ C, int M, int N, int K)
{
    __shared__ f16 smem[24576];   // 48KB: A bufs [0,12288), B bufs [12288,24576)
    const int tid  = threadIdx.x;
    const int lane = tid & 63;
    const int wid  = tid >> 6;
    const int wm = wid >> 1, wn = wid & 1;
    const int m0 = blockIdx.y * 128, n0 = blockIdx.x * 128;

    f32x4 acc[4][4];
    #pragma unroll
    for (int i = 0; i < 4; ++i)
        #pragma unroll
        for (int j = 0; j < 4; ++j)
            acc[i][j] = (f32x4)0.0f;

    const int r  = lane & 15;
    const int kg = lane >> 4;
    const int px = (kg ^ ((r >> 1) & 3)) << 3;

#ifdef USE_GLOAD_LDS
    const int seg0 = wid * 2, seg1 = wid * 2 + 1;       // 16 rows each
    const int row0 = seg0 * 16 + (lane >> 2);
    const int row1 = seg1 * 16 + (lane >> 2);
    const int kc0  = (lane & 3) ^ ((row0 >> 1) & 3);    // pre-swizzled chunk
    const int kc1  = (lane & 3) ^ ((row1 >> 1) & 3);
    const f16* a0 = A  + (size_t)(m0 + row0) * K + kc0 * 8;
    const f16* a1 = A  + (size_t)(m0 + row1) * K + kc1 * 8;
    const f16* b0 = Bt + (size_t)(n0 + row0) * K + kc0 * 8;
    const f16* b1 = Bt + (size_t)(n0 + row1) * K + kc1 * 8;

    auto stage = [&](int buf, int k0) {
        f16* as = smem + buf * 4096;
        f16* bs = smem + 12288 + buf * 4096;
        __builtin_amdgcn_global_load_lds(
            (const __attribute__((address_space(1))) void*)(a0 + k0),
            (__attribute__((address_space(3))) void*)&as[seg0 * 512], 16, 0, 0);
        __builtin_amdgcn_global_load_lds(
            (const __attribute__((address_space(1))) void*)(a1 + k0),
            (__attribute__((address_space(3))) void*)&as[seg1 * 512], 16, 0, 0);
        __builtin_amdgcn_global_load_lds(
            (const __attribute__((address_space(1))) void*)(b0 + k0),
            (__attribute__((address_space(3))) void*)&bs[seg0 * 512], 16, 0, 0);
        __builtin_amdgcn_global_load_lds(
            (const __attribute__((address_space(1))) void*)(b1 + k0),
            (__attribute__((address_space(3))) void*)&bs[seg1 * 512], 16, 0, 0);
    };

    const int NT = K >> 5;
    stage(0, 0);
    if (NT > 1) stage(1, 32);
    for (int kt = 0; kt < NT; ++kt) {
        const int cur = kt % 3;
        if (kt + 2 < NT) {
            stage((kt + 2) % 3, (kt + 2) << 5);
            asm volatile("s_waitcnt vmcnt(8)" ::: "memory");  // tile kt done; kt+1,kt+2 in flight
        } else if (kt + 1 < NT) {
            asm volatile("s_waitcnt vmcnt(4)" ::: "memory");
        } else {
            asm volatile("s_waitcnt vmcnt(0)" ::: "memory");
        }
        __builtin_amdgcn_s_barrier();
        __builtin_amdgcn_sched_barrier(0);
        const f16* as = smem + cur * 4096;
        const f16* bs = smem + 12288 + cur * 4096;
        f16x8 af[4], bfr[4];
        #pragma unroll
        for (int m = 0; m < 4; ++m)
            af[m] = *(const f16x8*)(&as[(wm * 64 + m * 16 + r) * 32 + px]);
        #pragma unroll
        for (int n = 0; n < 4; ++n)
            bfr[n] = *(const f16x8*)(&bs[(wn * 64 + n * 16 + r) * 32 + px]);
        #pragma unroll
        for (int m = 0; m < 4; ++m)
            #pragma unroll
            for (int n = 0; n < 4; ++n)
                acc[m][n] = __builtin_amdgcn_mfma_f32_16x16x32_f16(
                    af[m], bfr[n], acc[m][n], 0, 0, 0);
        __builtin_amdgcn_sched_barrier(0);
        __builtin_amdgcn_s_barrier();
    }
#else
    for (int k0 = 0; k0 < K; k0 += 32) {
        #pragma unroll
        for (int it = 0; it < 2; ++it) {
            const int c   = tid + it * 256;
            const int row = c >> 2, kc = c & 3;
            const int widx = row * 32 + ((kc ^ ((row >> 1) & 3)) << 3);
            f16x8 va = {0, 0, 0, 0, 0, 0, 0, 0};
            const int ga = m0 + row;
            if (ga < M) va = *(const f16x8*)(A + (size_t)ga * K + k0 + kc * 8);
            *(f16x8*)(&smem[widx]) = va;
            const f16x8 vb = *(const f16x8*)(Bt + (size_t)(n0 + row) * K + k0 + kc * 8);
            *(f16x8*)(&smem[12288 + widx]) = vb;
        }
        __syncthreads();
        f16x8 af[4], bfr[4];
        #pragma unroll
        for (int m = 0; m < 4; ++m)
            af[m] = *(const f16x8*)(&smem[(wm * 64 + m * 16 + r) * 32 + px]);
        #pragma unroll
        for (int n = 0; n < 4; ++n)
            bfr[n] = *(const f16x8*)(&smem[12288 + (wn * 64 + n * 16 + r) * 32 + px]);
        #pragma unroll
        for (int m = 0; m < 4; ++m)
            #pragma unroll
            for (int n = 0; n < 4; ++n)
                acc[m][n] = __builtin_amdgcn_mfma_f32_16x16x32_f16(
                    af[m], bfr[n], acc[m][n], 0, 0, 0);
        __syncthreads();
    }
#endif

    const int rq = lane >> 4;
    if constexpr (sizeof(TC) == 2) {
        // f16 output: repack via LDS (trailing barrier of last K-iter protects)
        #pragma unroll
        for (int m = 0; m < 4; ++m) {
            #pragma unroll
            for (int rr = 0; rr < 4; ++rr) {
                const int rl = wm * 64 + m * 16 + rq * 4 + rr;
                #pragma unroll
                for (int n = 0; n < 4; ++n) {
                    const int cl = wn * 64 + n * 16 + (lane & 15);
                    float v = acc[m][n][rr];
                    if (HAS_BIAS) v += bias[n0 + cl];
                    if (HAS_ADD && (m0 + rl) < M) v += addmat[(size_t)(m0 + rl) * N + n0 + cl];
                    if (DO_RELU) v = fmaxf(v, 0.f);
                    smem[rl * 128 + cl] = (f16)v;
                }
            }
        }
        __syncthreads();
        #pragma unroll
        for (int i = 0; i < 8; ++i) {
            const int ch  = tid + i * 256;          // 0..2047
            const int row = ch >> 4;
            const int cc  = (ch & 15) << 3;
            if (m0 + row < M)
                *(f16x8*)((f16*)C + (size_t)(m0 + row) * N + n0 + cc) =
                    *(const f16x8*)(&smem[row * 128 + cc]);
        }
    } else {
        #pragma unroll
        for (int m = 0; m < 4; ++m) {
            #pragma unroll
            for (int rr = 0; rr < 4; ++rr) {
                const int row = m0 + wm * 64 + m * 16 + rq * 4 + rr;
                if (row >= M) continue;
                #pragma unroll
                for (int n = 0; n < 4; ++n) {
                    const int col = n0 + wn * 64 + n * 16 + (lane & 15);
                    float v = acc[m][n][rr];
                    if (HAS_BIAS) v += bias[col];
                    if (HAS_ADD)  v += addmat[(size_t)row * N + col];
                    if (DO_RELU)  v = fmaxf(v, 0.f);
                    cstore(&C[(size_t)row * N + col], v);
                }
            }
        }
    }
}

// ---------------------------------------------------------------------------
// Weight transpose+convert: W[K][N] f32 -> Wt[N][K] f16. 32x32 LDS tiles.
// ---------------------------------------------------------------------------
__global__ void wt_kernel(const float* __restrict__ W, f16* __restrict__ Wt, int K, int N)
{
    __shared__ float t[32][33];
    const int k0 = blockIdx.x * 32, n0 = blockIdx.y * 32;
    const int tx = threadIdx.x & 31, ty = threadIdx.x >> 5;
    #pragma unroll
    for (int i = ty; i < 32; i += 8) {
        const int k = k0 + i;
        if (k < K && n0 + tx < N) t[i][tx] = W[(size_t)k * N + n0 + tx];
    }
    __syncthreads();
    #pragma unroll
    for (int i = ty; i < 32; i += 8) {
        const int n = n0 + i;
        if (n < N && k0 + tx < K) Wt[(size_t)n * K + k0 + tx] = (f16)t[tx][i];
    }
}

// f32 -> f16 elementwise (n % 4 == 0)
__global__ void f2h_kernel(const float* __restrict__ in, f16* __restrict__ out, int n)
{
    const int i = (blockIdx.x * 256 + threadIdx.x) * 4;
    if (i < n) {
        const float4 v = *(const float4*)(in + i);
        out[i + 0] = (f16)v.x; out[i + 1] = (f16)v.y;
        out[i + 2] = (f16)v.z; out[i + 3] = (f16)v.w;
    }
}

// ---------------------------------------------------------------------------
// Fused conv + kv-sum + q materialization (unchanged).
// ---------------------------------------------------------------------------
#define KV_CHUNK 32
#define KV_BLOCKS (N_NODES / KV_CHUNK)   // 625
__global__ __launch_bounds__(256, 2)
void kv_fused_kernel(const f16* __restrict__ qkv, const float* __restrict__ cw,
                     f16* __restrict__ q_all, float* __restrict__ kvg,
                     float* __restrict__ kv_part)
{
    __shared__ f16 rows[5][TD];
    const int tid = threadIdx.x;
    const int n0 = blockIdx.x * KV_CHUNK;
    const int h = tid >> 1, d0 = (tid & 1) * 4;

    float wk[4][5], wv[8][5], wq[8][5];
    if (h >= 64) {
        const int cb = (h - 64) * 24;
        #pragma unroll
        for (int dd = 0; dd < 4; ++dd)
            #pragma unroll
            for (int t = 0; t < 5; ++t)
                wk[dd][t] = cw[(cb + 8 + d0 + dd) * 5 + t];
        #pragma unroll
        for (int e = 0; e < 8; ++e)
            #pragma unroll
            for (int t = 0; t < 5; ++t)
                wv[e][t] = cw[(cb + 16 + e) * 5 + t];
    }
    if (tid >= 64 && tid < 128) {
        const int cb = (tid - 64) * 24;
        #pragma unroll
        for (int d = 0; d < 8; ++d)
            #pragma unroll
            for (int t = 0; t < 5; ++t)
                wq[d][t] = cw[(cb + d) * 5 + t];
    }

    for (int r = n0 - 2; r <= n0 + 2; ++r) {
        const int slot = ((r % 5) + 5) % 5;
        if (tid < 192) {
            f16x8 v = {0, 0, 0, 0, 0, 0, 0, 0};
            if (r >= 0 && r < N_NODES)
                v = *(const f16x8*)(qkv + (size_t)r * TD + tid * 8);
            *(f16x8*)(&rows[slot][tid * 8]) = v;
        }
    }
    __syncthreads();

    float acc[36] = {};

    for (int i = 0; i < KV_CHUNK; ++i) {
        const int n = n0 + i;

        f16x8 pre = {0, 0, 0, 0, 0, 0, 0, 0};
        const bool doPre = (i < KV_CHUNK - 1) && (tid < 192);
        if (doPre && (n + 3) < N_NODES)
            pre = *(const f16x8*)(qkv + (size_t)(n + 3) * TD + tid * 8);

        const f16* wr[5] = { rows[(((n - 2) % 5) + 5) % 5],
                             rows[(((n - 1) % 5) + 5) % 5],
                             rows[n % 5],
                             rows[(n + 1) % 5],
                             rows[(n + 2) % 5] };

        float kv4[4], vv[8];
        if (h < 64) {
            const int cb = h * 24;
            const f16x4 kd = *(const f16x4*)(wr[2] + cb + 8 + d0);
            const f16x8 vd = *(const f16x8*)(wr[2] + cb + 16);
            #pragma unroll
            for (int dd = 0; dd < 4; ++dd) kv4[dd] = fmaxf((float)kd[dd], 0.f);
            #pragma unroll
            for (int e = 0; e < 8; ++e) vv[e] = (float)vd[e];
        } else {
            const int cb = (h - 64) * 24;
            f16x4 ka[5]; f16x8 va[5];
            #pragma unroll
            for (int t = 0; t < 5; ++t) {
                ka[t] = *(const f16x4*)(wr[t] + cb + 8 + d0);
                va[t] = *(const f16x8*)(wr[t] + cb + 16);
            }
            #pragma unroll
            for (int dd = 0; dd < 4; ++dd) {
                float s = 0.f;
                #pragma unroll
                for (int t = 0; t < 5; ++t) s = fmaf(wk[dd][t], (float)ka[t][dd], s);
                kv4[dd] = fmaxf(s, 0.f);
            }
            #pragma unroll
            for (int e = 0; e < 8; ++e) {
                float s = 0.f;
                #pragma unroll
                for (int t = 0; t < 5; ++t) s = fmaf(wv[e][t], (float)va[t][e], s);
                vv[e] = s;
            }
        }
        #pragma unroll
        for (int dd = 0; dd < 4; ++dd) {
            #pragma unroll
            for (int e = 0; e < 8; ++e)
                acc[dd * 9 + e] = fmaf(kv4[dd], vv[e], acc[dd * 9 + e]);
            acc[dd * 9 + 8] += kv4[dd];
        }

        if (tid < 128) {
            f16x8 qv;
            if (tid < 64) {
                qv = *(const f16x8*)(wr[2] + tid * 24);
                #pragma unroll
                for (int d = 0; d < 8; ++d)
                    qv[d] = qv[d] > (f16)0 ? qv[d] : (f16)0;
            } else {
                const int cb = (tid - 64) * 24;
                f16x8 qa[5];
                #pragma unroll
                for (int t = 0; t < 5; ++t) qa[t] = *(const f16x8*)(wr[t] + cb);
                #pragma unroll
                for (int d = 0; d < 8; ++d) {
                    float s = 0.f;
                    #pragma unroll
                    for (int t = 0; t < 5; ++t) s = fmaf(wq[d][t], (float)qa[t][d], s);
                    qv[d] = (f16)fmaxf(s, 0.f);
                }
            }
            *(f16x8*)(q_all + (size_t)n * 1024 + tid * 8) = qv;
        }

        __syncthreads();
        if (doPre)
            *(f16x8*)(&rows[(n + 3) % 5][tid * 8]) = pre;
        __syncthreads();
    }

    if (kv_part) {
        float* dst = kv_part + (size_t)blockIdx.x * 9216 + tid * 36;
        #pragma unroll
        for (int i = 0; i < 36; ++i) dst[i] = acc[i];
    } else {
        #pragma unroll
        for (int dd = 0; dd < 4; ++dd)
            #pragma unroll
            for (int e = 0; e < 9; ++e)
                atomicAdd(&kvg[h * 72 + (d0 + dd) * 9 + e], acc[dd * 9 + e]);
    }
}

// kvg[j] = sum_b kv_part[b][j], j in [0,9216). Grid: 36 x 256.
__global__ void kv_reduce_kernel(const float* __restrict__ kv_part,
                                 float* __restrict__ kvg)
{
    const int j = blockIdx.x * 256 + threadIdx.x;
    float s = 0.f;
    for (int b = 0; b < KV_BLOCKS; ++b)
        s += kv_part[(size_t)b * 9216 + j];
    kvg[j] = s;
}

// ---------------------------------------------------------------------------
// o[n, h*8+e] = (sum_d q*kv[h,d,e]) / (sum_d q*kv[h,d,8] + 1e-15)
// ---------------------------------------------------------------------------
__global__ __launch_bounds__(256)
void attn_o_kernel(const f16* __restrict__ q_all, const float* __restrict__ kvg,
                   f16* __restrict__ o)
{
    __shared__ float kvt[72][128];   // [d*9+e][h]
    const int tid = threadIdx.x;
    for (int i = tid; i < 9216; i += 256) {
        const int hh = i & 127, j = i >> 7;
        kvt[j][hh] = kvg[hh * 72 + j];
    }
    __syncthreads();
    const int h = tid & 127, sub = tid >> 7;
    for (int nb = blockIdx.x; nb < N_NODES / 2; nb += gridDim.x) {
        const int n = nb * 2 + sub;
        const f16x8 qv8 = *(const f16x8*)(q_all + (size_t)n * 1024 + h * 8);
        float q[8];
        #pragma unroll
        for (int d = 0; d < 8; ++d) q[d] = (float)qv8[d];
        float num[8], den = 0.f;
        #pragma unroll
        for (int e = 0; e < 8; ++e) {
            float s = 0.f;
            #pragma unroll
            for (int d = 0; d < 8; ++d) s = fmaf(q[d], kvt[d * 9 + e][h], s);
            num[e] = s;
        }
        #pragma unroll
        for (int d = 0; d < 8; ++d) den = fmaf(q[d], kvt[d * 9 + 8][h], den);
        const float rinv = 1.f / (den + 1e-15f);
        f16x8 ov;
        #pragma unroll
        for (int e = 0; e < 8; ++e) ov[e] = (f16)(num[e] * rinv);
        *(f16x8*)(o + (size_t)n * 1024 + h * 8) = ov;
    }
}

// ---------------------------------------------------------------------------
// out_h = f16(resid + LN(y)*g + b). resid f16. out_h may alias y.
// ---------------------------------------------------------------------------
__global__ void ln_res_kernel(const f16* __restrict__ y, const f16* __restrict__ resid,
                              const float* __restrict__ g, const float* __restrict__ b,
                              f16* __restrict__ out_h)
{
    const int row = blockIdx.x;
    const int tid = threadIdx.x;
    const f16* yr = y + (size_t)row * DMODEL;
    const float v0 = (float)yr[tid], v1 = (float)yr[tid + 256];
    __shared__ float red[4], red2[4];
    float s = v0 + v1;
    #pragma unroll
    for (int o = 32; o > 0; o >>= 1) s += __shfl_down(s, o);
    if ((tid & 63) == 0) red[tid >> 6] = s;
    __syncthreads();
    const float mean = (red[0] + red[1] + red[2] + red[3]) * (1.0f / DMODEL);
    const float d0 = v0 - mean, d1 = v1 - mean;
    float q = d0 * d0 + d1 * d1;
    #pragma unroll
    for (int o = 32; o > 0; o >>= 1) q += __shfl_down(q, o);
    if ((tid & 63) == 0) red2[tid >> 6] = q;
    __syncthreads();
    const float var = (red2[0] + red2[1] + red2[2] + red2[3]) * (1.0f / DMODEL);
    const float inv = rsqrtf(var + 1e-5f);
    const f16* rr = resid + (size_t)row * DMODEL;
    const float o0 = (float)rr[tid]       + d0 * inv * g[tid]       + b[tid];
    const float o1 = (float)rr[tid + 256] + d1 * inv * g[tid + 256] + b[tid + 256];
    f16* oh = out_h + (size_t)row * DMODEL;
    oh[tid] = (f16)o0;
    oh[tid + 256] = (f16)o1;
}

// ---------------------------------------------------------------------------
// Graph normalization + counting sort
// ---------------------------------------------------------------------------
__global__ void deg_init_kernel(float* __restrict__ deg)
{
    const int i = blockIdx.x * 256 + threadIdx.x;
    if (i < N_NODES) deg[i] = 1.0f;
}

__global__ void deg_acc_kernel(const int* __restrict__ eirow, const float* __restrict__ ea,
                               float* __restrict__ deg)
{
    const int e = blockIdx.x * 256 + threadIdx.x;
    if (e < N_EDGES) atomicAdd(&deg[eirow[e]], ea[e]);
}

__global__ void dis_kernel(const float* __restrict__ deg, float* __restrict__ dis)
{
    const int i = blockIdx.x * 256 + threadIdx.x;
    if (i < N_NODES) dis[i] = rsqrtf(deg[i]);
}

__global__ void count_kernel(const int* __restrict__ eirow, int* __restrict__ cnt)
{
    const int e = blockIdx.x * 256 + threadIdx.x;
    if (e < N_EDGES) atomicAdd(&cnt[eirow[e]], 1);
}

__global__ void scan_kernel(const int* __restrict__ cnt, int* __restrict__ rowstart,
                            int* __restrict__ cursor)
{
    __shared__ int ls[1024];
    const int tid = threadIdx.x;
    const int base = tid * 20;
    int local[20];
    int s = 0;
    #pragma unroll
    for (int i = 0; i < 20; ++i) {
        const int idx = base + i;
        const int v = (idx < N_NODES) ? cnt[idx] : 0;
        local[i] = s;
        s += v;
    }
    ls[tid] = s;
    __syncthreads();
    for (int off = 1; off < 1024; off <<= 1) {
        const int v = (tid >= off) ? ls[tid - off] : 0;
        __syncthreads();
        ls[tid] += v;
        __syncthreads();
    }
    const int excl = (tid == 0) ? 0 : ls[tid - 1];
    #pragma unroll
    for (int i = 0; i < 20; ++i) {
        const int idx = base + i;
        if (idx < N_NODES) {
            const int st = excl + local[i];
            rowstart[idx] = st;
            cursor[idx] = st;
        }
    }
    if (tid == 1023) rowstart[N_NODES] = ls[1023];
}

__global__ void scatter_kernel(const int* __restrict__ eirow, int* __restrict__ cursor,
                               int* __restrict__ sorted)
{
    const int e = blockIdx.x * 256 + threadIdx.x;
    if (e < N_EDGES) {
        const int r = eirow[e];
        const int p = atomicAdd(&cursor[r], 1);
        sorted[p] = e;
    }
}

// ---------------------------------------------------------------------------
// Aggregation v3 (unchanged): LDS metadata prefetch + 4-wave row gathers.
// ---------------------------------------------------------------------------
__global__ __launch_bounds__(256)
void agg_kernel(const f16* __restrict__ srcf_h, const int* __restrict__ eicol,
                const float* __restrict__ ea, const float* __restrict__ dis,
                const int* __restrict__ rowstart, const int* __restrict__ sorted,
                f16* __restrict__ agg)
{
    __shared__ int   cbuf[256];
    __shared__ float wbuf[256];
    __shared__ float part[4][512];
    const int i = blockIdx.x;
    const int tid = threadIdx.x;
    const int lane = tid & 63, wv = tid >> 6;
    const float di = dis[i];
    const int s = rowstart[i];
    const int deg = rowstart[i + 1] - s;

    float acc[8] = {};
    for (int base = 0; base < deg; base += 256) {
        const int m = min(256, deg - base);
        if (tid < m) {
            const int e = sorted[s + base + tid];
            const int c = eicol[e];
            cbuf[tid] = c;
            wbuf[tid] = di * ea[e] * dis[c];
        }
        __syncthreads();
        #pragma unroll 2
        for (int p = wv; p < m; p += 4) {
            const int c = cbuf[p];
            const float w = wbuf[p];
            const f16x8 v = *(const f16x8*)(srcf_h + (size_t)c * DMODEL + lane * 8);
            #pragma unroll
            for (int j = 0; j < 8; ++j) acc[j] = fmaf(w, (float)v[j], acc[j]);
        }
        __syncthreads();
    }
    #pragma unroll
    for (int j = 0; j < 8; ++j) part[wv][lane * 8 + j] = acc[j];
    __syncthreads();
    const float wself = di * di;
    const f16x2 vs = *(const f16x2*)(srcf_h + (size_t)i * DMODEL + tid * 2);
    float a0 = wself * (float)vs[0], a1 = wself * (float)vs[1];
    #pragma unroll
    for (int w = 0; w < 4; ++w) {
        a0 += part[w][tid * 2];
        a1 += part[w][tid * 2 + 1];
    }
    f16x2 o;
    o[0] = (f16)fmaxf(a0, 0.f);
    o[1] = (f16)fmaxf(a1, 0.f);
    *(f16x2*)(agg + (size_t)i * DMODEL + tid * 2) = o;
}

// ---------------------------------------------------------------------------
// Workspace layout (bytes) — unchanged from round 12/13.
// ---------------------------------------------------------------------------
static constexpr size_t OFF_HH    = 0;              // f16 20,480,000
static constexpr size_t OFF_FF    = 20480000ull;    // f16 20,480,000
static constexpr size_t OFF_QKV   = 40960000ull;    // f16 61,440,000
static constexpr size_t OFF_SRC2  = 40960000ull;    // f16 20,480,000 (alias)
static constexpr size_t OFF_FFH   = 61440000ull;    // f16 81,920,000 (alias)
static constexpr size_t OFF_AGG   = 61440000ull;    // f16 40,960,000 (alias)
static constexpr size_t OFF_XH    = 102400000ull;   // f16 10,240,000
static constexpr size_t OFF_ATTN  = 102400000ull;   // f16 40,960,000 (alias)
static constexpr size_t WT_IN     = 143360000ull;
static constexpr size_t WT_QKV    = 143622144ull;
static constexpr size_t WT_PROJ   = 145195008ull;
static constexpr size_t WT_W1     = 146243584ull;
static constexpr size_t WT_W2     = 148340736ull;
static constexpr size_t WT_OUT    = 150437888ull;
static constexpr size_t OFF_KV    = 150568960ull;
static constexpr size_t OFF_DEG   = 150605824ull;
static constexpr size_t OFF_DIS   = 150685824ull;
static constexpr size_t OFF_RS    = 150765824ull;
static constexpr size_t OFF_CUR   = 150845888ull;
static constexpr size_t OFF_CNT   = 150925888ull;
static constexpr size_t OFF_SORT  = 151005888ull;   // -> 152,285,888
static constexpr size_t OFF_KVP   = 152285888ull;   // -> 175,325,888
static constexpr size_t WS_NEED_KVP = 175325888ull;

extern "C" void kernel_launch(void* const* d_in, const int* in_sizes, int n_in,
                              void* d_out, int out_size, void* d_ws, size_t ws_size,
                              hipStream_t stream)
{
    const float* x      = (const float*)d_in[0];
    const int*   ei     = (const int*)d_in[1];
    const float* ea     = (const float*)d_in[2];
    const float* pe     = (const float*)d_in[4];
    const float* W_in   = (const float*)d_in[5];
    const float* b_in   = (const float*)d_in[6];
    const float* W_qkv  = (const float*)d_in[7];
    const float* conv_w = (const float*)d_in[8];
    const float* W_proj = (const float*)d_in[9];
    const float* b_proj = (const float*)d_in[10];
    const float* g1     = (const float*)d_in[11];
    const float* beta1  = (const float*)d_in[12];
    const float* W1     = (const float*)d_in[13];
    const float* bf1    = (const float*)d_in[14];
    const float* W2     = (const float*)d_in[15];
    const float* bf2    = (const float*)d_in[16];
    const float* g2     = (const float*)d_in[17];
    const float* beta2  = (const float*)d_in[18];
    const float* W_out  = (const float*)d_in[19];
    const float* b_out  = (const float*)d_in[20];

    char* ws = (char*)d_ws;
    f16*   h_h    = (f16*)(ws + OFF_HH);
    f16*   ff     = (f16*)(ws + OFF_FF);
    f16*   qkv    = (f16*)(ws + OFF_QKV);
    f16*   src2   = (f16*)(ws + OFF_SRC2);
    f16*   ffh    = (f16*)(ws + OFF_FFH);
    f16*   agg    = (f16*)(ws + OFF_AGG);
    f16*   x_h    = (f16*)(ws + OFF_XH);
    f16*   q_all  = (f16*)(ws + OFF_ATTN);
    f16*   wt_in   = (f16*)(ws + WT_IN);
    f16*   wt_qkv  = (f16*)(ws + WT_QKV);
    f16*   wt_proj = (f16*)(ws + WT_PROJ);
    f16*   wt_w1   = (f16*)(ws + WT_W1);
    f16*   wt_w2   = (f16*)(ws + WT_W2);
    f16*   wt_out  = (f16*)(ws + WT_OUT);
    float* kvg    = (float*)(ws + OFF_KV);
    float* deg    = (float*)(ws + OFF_DEG);
    float* dis    = (float*)(ws + OFF_DIS);
    int*   rs     = (int*)(ws + OFF_RS);
    int*   cur    = (int*)(ws + OFF_CUR);
    int*   cnt    = (int*)(ws + OFF_CNT);
    int*   sorted = (int*)(ws + OFF_SORT);
    float* outp   = (float*)d_out;

    const bool twoStage = (ws_size >= WS_NEED_KVP);
    float* kv_part = twoStage ? (float*)(ws + OFF_KVP) : nullptr;

    const int* eirow = ei;
    const int* eicol = ei + N_EDGES;

    if (!twoStage)
        hipMemsetAsync(kvg, 0, 9216 * sizeof(float), stream);
    hipMemsetAsync(cnt, 0, N_NODES * sizeof(int), stream);

    // 0. weight transpose+convert (f32 [K][N] -> f16 [N][K])
    wt_kernel<<<dim3(DIN / 32,   DMODEL / 32), 256, 0, stream>>>(W_in,   wt_in,   DIN,    DMODEL);
    wt_kernel<<<dim3(DMODEL / 32, TD / 32),    256, 0, stream>>>(W_qkv,  wt_qkv,  DMODEL, TD);
    wt_kernel<<<dim3(1024 / 32,  DMODEL / 32), 256, 0, stream>>>(W_proj, wt_proj, 1024,   DMODEL);
    wt_kernel<<<dim3(DMODEL / 32, FFD / 32),   256, 0, stream>>>(W1,     wt_w1,   DMODEL, FFD);
    wt_kernel<<<dim3(FFD / 32,   DMODEL / 32), 256, 0, stream>>>(W2,     wt_w2,   FFD,    DMODEL);
    wt_kernel<<<dim3(DMODEL / 32, DOUT / 32),  256, 0, stream>>>(W_out,  wt_out,  DMODEL, DOUT);
    // 0b. x -> f16
    f2h_kernel<<<(N_NODES * DIN) / 1024, 256, 0, stream>>>(x, x_h, N_NODES * DIN);

    const int GY = (N_NODES + 127) / 128;   // 157

    // 1. h_h = f16(x@W_in + b_in + pe)
    gemm_mfma<f16, 1, 1, 0><<<dim3(DMODEL / 128, GY), 256, 0, stream>>>(
        x_h, wt_in, b_in, pe, h_h, N_NODES, DMODEL, DIN);
    // 2. qkv = h_h@W_qkv (f16)
    gemm_mfma<f16, 0, 0, 0><<<dim3(TD / 128, GY), 256, 0, stream>>>(
        h_h, wt_qkv, nullptr, nullptr, qkv, N_NODES, TD, DMODEL);
    // 3. fused conv + kv partials + q materialization
    kv_fused_kernel<<<KV_BLOCKS, 256, 0, stream>>>(qkv, conv_w, q_all, kvg, kv_part);
    if (twoStage)
        kv_reduce_kernel<<<36, 256, 0, stream>>>(kv_part, kvg);
    // 4. attention readout (in-place over q_all)
    attn_o_kernel<<<2500, 256, 0, stream>>>(q_all, kvg, q_all);
    // 5. src2 = attn_o@W_proj + b_proj (f16)
    gemm_mfma<f16, 1, 0, 0><<<dim3(DMODEL / 128, GY), 256, 0, stream>>>(
        q_all, wt_proj, b_proj, nullptr, src2, N_NODES, DMODEL, 1024);
    // 6. src2 = f16(h_h + LN(src2))  (in-place)
    ln_res_kernel<<<N_NODES, 256, 0, stream>>>(src2, h_h, g1, beta1, src2);
    // 7. ffh = relu(src2@W1 + bf1) (f16)
    gemm_mfma<f16, 1, 0, 1><<<dim3(FFD / 128, GY), 256, 0, stream>>>(
        src2, wt_w1, bf1, nullptr, ffh, N_NODES, FFD, DMODEL);
    // 8. ff = ffh@W2 + bf2 (f16)
    gemm_mfma<f16, 1, 0, 0><<<dim3(DMODEL / 128, GY), 256, 0, stream>>>(
        ffh, wt_w2, bf2, nullptr, ff, N_NODES, DMODEL, FFD);
    // 9. ff = f16(src2 + LN(ff))  (in-place; agg gather source)
    ln_res_kernel<<<N_NODES, 256, 0, stream>>>(ff, src2, g2, beta2, ff);
    // 10. degree / normalization
    deg_init_kernel<<<(N_NODES + 255) / 256, 256, 0, stream>>>(deg);
    deg_acc_kernel<<<(N_EDGES + 255) / 256, 256, 0, stream>>>(eirow, ea, deg);
    dis_kernel<<<(N_NODES + 255) / 256, 256, 0, stream>>>(deg, dis);
    // 11. counting sort of edges by destination row
    count_kernel<<<(N_EDGES + 255) / 256, 256, 0, stream>>>(eirow, cnt);
    scan_kernel<<<1, 1024, 0, stream>>>(cnt, rs, cur);
    scatter_kernel<<<(N_EDGES + 255) / 256, 256, 0, stream>>>(eirow, cur, sorted);
    // 12. aggregation
    agg_kernel<<<N_NODES, 256, 0, stream>>>(ff, eicol, ea, dis, rs, sorted, agg);
    // 13. out = relu(agg)@W_out + b_out (f32)
    gemm_mfma<float, 1, 0, 0><<<dim3(DOUT / 128, GY), 256, 0, stream>>>(
        agg, wt_out, b_out, nullptr, outp, N_NODES, DOUT, DMODEL);
}

// Round 15
// 611.082 us; speedup vs baseline: 6.0754x; 1.0179x over previous
//
#include <hip/hip_runtime.h>

#define N_NODES 20000
#define N_EDGES 320000
#define DIN     256
#define DMODEL  512
#define TD      1536   // 3*D
#define FFD     2048
#define DOUT    128

typedef _Float16 f16;
typedef f16 f16x8 __attribute__((ext_vector_type(8)));
typedef f16 f16x4 __attribute__((ext_vector_type(4)));
typedef f16 f16x2 __attribute__((ext_vector_type(2)));
typedef float f32x4 __attribute__((ext_vector_type(4)));

__device__ __forceinline__ void cstore(float* p, float v) { *p = v; }
__device__ __forceinline__ void cstore(f16* p, float v)   { *p = (f16)v; }

#if defined(__has_builtin)
#if __has_builtin(__builtin_amdgcn_global_load_lds)
#define USE_GLOAD_LDS 1
#endif
#endif

// ---------------------------------------------------------------------------
// fp16 MFMA GEMM v5: 128x128 tile, BK=32, 4 waves, mfma_f32_16x16x32_f16.
// Triple-buffered K-loop, 2 tiles in flight (vmcnt(8)); raw s_barrier +
// counted vmcnt (T4); pre-swizzled gload_lds source (m173).
// NEW: 1D grid + bijective XCD swizzle (T1/m204): each XCD owns contiguous
// logical tiles with n fastest -> all N-blocks sharing an A-row-panel run on
// the SAME XCD -> A-panel L2 reuse (round-14 FETCH showed 4x A re-fetch).
// f16-C epilogue repacks through LDS -> coalesced f16x8 stores.
// A rows read unguarded to the 128-aligned tile edge (allocated slack).
// K%32==0 (K>=64), N%128==0, M guarded at C-write and addmat-read.
// ---------------------------------------------------------------------------
template<typename TC, int HAS_BIAS, int HAS_ADD, int DO_RELU>
__global__ __launch_bounds__(256)
void gemm_mfma(const f16* __restrict__ A, const f16* __restrict__ Bt,
               const float* __restrict__ bias, const float* __restrict__ addmat,
               TC* __restrict__ C, int M, int N, int K)
{
    __shared__ f16 smem[24576];   // 48KB: A bufs [0,12288), B bufs [12288,24576)
    const int tid  = threadIdx.x;
    const int lane = tid & 63;
    const int wid  = tid >> 6;
    const int wm = wid >> 1, wn = wid & 1;

    // bijective XCD swizzle (XCD ~ bid%8): contiguous wgid chunk per XCD,
    // n fastest => A-panel sharers co-located on one XCD's L2.
    const int nwg  = gridDim.x;
    const int bid  = blockIdx.x;
    const int q    = nwg >> 3, rres = nwg & 7;
    const int xcd  = bid & 7,  slot = bid >> 3;
    const int wgid = (xcd < rres ? xcd * (q + 1)
                                 : rres * (q + 1) + (xcd - rres) * q) + slot;
    const int ntn  = N >> 7;
    const int m0 = (wgid / ntn) * 128, n0 = (wgid % ntn) * 128;

    f32x4 acc[4][4];
    #pragma unroll
    for (int i = 0; i < 4; ++i)
        #pragma unroll
        for (int j = 0; j < 4; ++j)
            acc[i][j] = (f32x4)0.0f;

    const int r  = lane & 15;
    const int kg = lane >> 4;
    const int px = (kg ^ ((r >> 1) & 3)) << 3;

#ifdef USE_GLOAD_LDS
    const int seg0 = wid * 2, seg1 = wid * 2 + 1;       // 16 rows each
    const int row0 = seg0 * 16 + (lane >> 2);
    const int row1 = seg1 * 16 + (lane >> 2);
    const int kc0  = (lane & 3) ^ ((row0 >> 1) & 3);    // pre-swizzled chunk
    const int kc1  = (lane & 3) ^ ((row1 >> 1) & 3);
    const f16* a0 = A  + (size_t)(m0 + row0) * K + kc0 * 8;
    const f16* a1 = A  + (size_t)(m0 + row1) * K + kc1 * 8;
    const f16* b0 = Bt + (size_t)(n0 + row0) * K + kc0 * 8;
    const f16* b1 = Bt + (size_t)(n0 + row1) * K + kc1 * 8;

    auto stage = [&](int buf, int k0) {
        f16* as = smem + buf * 4096;
        f16* bs = smem + 12288 + buf * 4096;
        __builtin_amdgcn_global_load_lds(
            (const __attribute__((address_space(1))) void*)(a0 + k0),
            (__attribute__((address_space(3))) void*)&as[seg0 * 512], 16, 0, 0);
        __builtin_amdgcn_global_load_lds(
            (const __attribute__((address_space(1))) void*)(a1 + k0),
            (__attribute__((address_space(3))) void*)&as[seg1 * 512], 16, 0, 0);
        __builtin_amdgcn_global_load_lds(
            (const __attribute__((address_space(1))) void*)(b0 + k0),
            (__attribute__((address_space(3))) void*)&bs[seg0 * 512], 16, 0, 0);
        __builtin_amdgcn_global_load_lds(
            (const __attribute__((address_space(1))) void*)(b1 + k0),
            (__attribute__((address_space(3))) void*)&bs[seg1 * 512], 16, 0, 0);
    };

    const int NT = K >> 5;
    stage(0, 0);
    if (NT > 1) stage(1, 32);
    for (int kt = 0; kt < NT; ++kt) {
        const int cur = kt % 3;
        if (kt + 2 < NT) {
            stage((kt + 2) % 3, (kt + 2) << 5);
            asm volatile("s_waitcnt vmcnt(8)" ::: "memory");  // tile kt done
        } else if (kt + 1 < NT) {
            asm volatile("s_waitcnt vmcnt(4)" ::: "memory");
        } else {
            asm volatile("s_waitcnt vmcnt(0)" ::: "memory");
        }
        __builtin_amdgcn_s_barrier();
        __builtin_amdgcn_sched_barrier(0);
        const f16* as = smem + cur * 4096;
        const f16* bs = smem + 12288 + cur * 4096;
        f16x8 af[4], bfr[4];
        #pragma unroll
        for (int m = 0; m < 4; ++m)
            af[m] = *(const f16x8*)(&as[(wm * 64 + m * 16 + r) * 32 + px]);
        #pragma unroll
        for (int n = 0; n < 4; ++n)
            bfr[n] = *(const f16x8*)(&bs[(wn * 64 + n * 16 + r) * 32 + px]);
        #pragma unroll
        for (int m = 0; m < 4; ++m)
            #pragma unroll
            for (int n = 0; n < 4; ++n)
                acc[m][n] = __builtin_amdgcn_mfma_f32_16x16x32_f16(
                    af[m], bfr[n], acc[m][n], 0, 0, 0);
        __builtin_amdgcn_sched_barrier(0);
        __builtin_amdgcn_s_barrier();
    }
#else
    for (int k0 = 0; k0 < K; k0 += 32) {
        #pragma unroll
        for (int it = 0; it < 2; ++it) {
            const int c   = tid + it * 256;
            const int row = c >> 2, kc = c & 3;
            const int widx = row * 32 + ((kc ^ ((row >> 1) & 3)) << 3);
            f16x8 va = {0, 0, 0, 0, 0, 0, 0, 0};
            const int ga = m0 + row;
            if (ga < M) va = *(const f16x8*)(A + (size_t)ga * K + k0 + kc * 8);
            *(f16x8*)(&smem[widx]) = va;
            const f16x8 vb = *(const f16x8*)(Bt + (size_t)(n0 + row) * K + k0 + kc * 8);
            *(f16x8*)(&smem[12288 + widx]) = vb;
        }
        __syncthreads();
        f16x8 af[4], bfr[4];
        #pragma unroll
        for (int m = 0; m < 4; ++m)
            af[m] = *(const f16x8*)(&smem[(wm * 64 + m * 16 + r) * 32 + px]);
        #pragma unroll
        for (int n = 0; n < 4; ++n)
            bfr[n] = *(const f16x8*)(&smem[12288 + (wn * 64 + n * 16 + r) * 32 + px]);
        #pragma unroll
        for (int m = 0; m < 4; ++m)
            #pragma unroll
            for (int n = 0; n < 4; ++n)
                acc[m][n] = __builtin_amdgcn_mfma_f32_16x16x32_f16(
                    af[m], bfr[n], acc[m][n], 0, 0, 0);
        __syncthreads();
    }
#endif

    const int rq = lane >> 4;
    if constexpr (sizeof(TC) == 2) {
        // f16 output: repack via LDS (trailing barrier of last K-iter protects)
        #pragma unroll
        for (int m = 0; m < 4; ++m) {
            #pragma unroll
            for (int rr = 0; rr < 4; ++rr) {
                const int rl = wm * 64 + m * 16 + rq * 4 + rr;
                #pragma unroll
                for (int n = 0; n < 4; ++n) {
                    const int cl = wn * 64 + n * 16 + (lane & 15);
                    float v = acc[m][n][rr];
                    if (HAS_BIAS) v += bias[n0 + cl];
                    if (HAS_ADD && (m0 + rl) < M) v += addmat[(size_t)(m0 + rl) * N + n0 + cl];
                    if (DO_RELU) v = fmaxf(v, 0.f);
                    smem[rl * 128 + cl] = (f16)v;
                }
            }
        }
        __syncthreads();
        #pragma unroll
        for (int i = 0; i < 8; ++i) {
            const int ch  = tid + i * 256;          // 0..2047
            const int row = ch >> 4;
            const int cc  = (ch & 15) << 3;
            if (m0 + row < M)
                *(f16x8*)((f16*)C + (size_t)(m0 + row) * N + n0 + cc) =
                    *(const f16x8*)(&smem[row * 128 + cc]);
        }
    } else {
        #pragma unroll
        for (int m = 0; m < 4; ++m) {
            #pragma unroll
            for (int rr = 0; rr < 4; ++rr) {
                const int row = m0 + wm * 64 + m * 16 + rq * 4 + rr;
                if (row >= M) continue;
                #pragma unroll
                for (int n = 0; n < 4; ++n) {
                    const int col = n0 + wn * 64 + n * 16 + (lane & 15);
                    float v = acc[m][n][rr];
                    if (HAS_BIAS) v += bias[col];
                    if (HAS_ADD)  v += addmat[(size_t)row * N + col];
                    if (DO_RELU)  v = fmaxf(v, 0.f);
                    cstore(&C[(size_t)row * N + col], v);
                }
            }
        }
    }
}

// ---------------------------------------------------------------------------
// Weight transpose+convert: W[K][N] f32 -> Wt[N][K] f16. 32x32 LDS tiles.
// ---------------------------------------------------------------------------
__global__ void wt_kernel(const float* __restrict__ W, f16* __restrict__ Wt, int K, int N)
{
    __shared__ float t[32][33];
    const int k0 = blockIdx.x * 32, n0 = blockIdx.y * 32;
    const int tx = threadIdx.x & 31, ty = threadIdx.x >> 5;
    #pragma unroll
    for (int i = ty; i < 32; i += 8) {
        const int k = k0 + i;
        if (k < K && n0 + tx < N) t[i][tx] = W[(size_t)k * N + n0 + tx];
    }
    __syncthreads();
    #pragma unroll
    for (int i = ty; i < 32; i += 8) {
        const int n = n0 + i;
        if (n < N && k0 + tx < K) Wt[(size_t)n * K + k0 + tx] = (f16)t[tx][i];
    }
}

// f32 -> f16 elementwise (n % 4 == 0)
__global__ void f2h_kernel(const float* __restrict__ in, f16* __restrict__ out, int n)
{
    const int i = (blockIdx.x * 256 + threadIdx.x) * 4;
    if (i < n) {
        const float4 v = *(const float4*)(in + i);
        out[i + 0] = (f16)v.x; out[i + 1] = (f16)v.y;
        out[i + 2] = (f16)v.z; out[i + 3] = (f16)v.w;
    }
}

// ---------------------------------------------------------------------------
// Fused conv + kv-sum + q materialization (unchanged).
// ---------------------------------------------------------------------------
#define KV_CHUNK 32
#define KV_BLOCKS (N_NODES / KV_CHUNK)   // 625
__global__ __launch_bounds__(256, 2)
void kv_fused_kernel(const f16* __restrict__ qkv, const float* __restrict__ cw,
                     f16* __restrict__ q_all, float* __restrict__ kvg,
                     float* __restrict__ kv_part)
{
    __shared__ f16 rows[5][TD];
    const int tid = threadIdx.x;
    const int n0 = blockIdx.x * KV_CHUNK;
    const int h = tid >> 1, d0 = (tid & 1) * 4;

    float wk[4][5], wv[8][5], wq[8][5];
    if (h >= 64) {
        const int cb = (h - 64) * 24;
        #pragma unroll
        for (int dd = 0; dd < 4; ++dd)
            #pragma unroll
            for (int t = 0; t < 5; ++t)
                wk[dd][t] = cw[(cb + 8 + d0 + dd) * 5 + t];
        #pragma unroll
        for (int e = 0; e < 8; ++e)
            #pragma unroll
            for (int t = 0; t < 5; ++t)
                wv[e][t] = cw[(cb + 16 + e) * 5 + t];
    }
    if (tid >= 64 && tid < 128) {
        const int cb = (tid - 64) * 24;
        #pragma unroll
        for (int d = 0; d < 8; ++d)
            #pragma unroll
            for (int t = 0; t < 5; ++t)
                wq[d][t] = cw[(cb + d) * 5 + t];
    }

    for (int r = n0 - 2; r <= n0 + 2; ++r) {
        const int slot = ((r % 5) + 5) % 5;
        if (tid < 192) {
            f16x8 v = {0, 0, 0, 0, 0, 0, 0, 0};
            if (r >= 0 && r < N_NODES)
                v = *(const f16x8*)(qkv + (size_t)r * TD + tid * 8);
            *(f16x8*)(&rows[slot][tid * 8]) = v;
        }
    }
    __syncthreads();

    float acc[36] = {};

    for (int i = 0; i < KV_CHUNK; ++i) {
        const int n = n0 + i;

        f16x8 pre = {0, 0, 0, 0, 0, 0, 0, 0};
        const bool doPre = (i < KV_CHUNK - 1) && (tid < 192);
        if (doPre && (n + 3) < N_NODES)
            pre = *(const f16x8*)(qkv + (size_t)(n + 3) * TD + tid * 8);

        const f16* wr[5] = { rows[(((n - 2) % 5) + 5) % 5],
                             rows[(((n - 1) % 5) + 5) % 5],
                             rows[n % 5],
                             rows[(n + 1) % 5],
                             rows[(n + 2) % 5] };

        float kv4[4], vv[8];
        if (h < 64) {
            const int cb = h * 24;
            const f16x4 kd = *(const f16x4*)(wr[2] + cb + 8 + d0);
            const f16x8 vd = *(const f16x8*)(wr[2] + cb + 16);
            #pragma unroll
            for (int dd = 0; dd < 4; ++dd) kv4[dd] = fmaxf((float)kd[dd], 0.f);
            #pragma unroll
            for (int e = 0; e < 8; ++e) vv[e] = (float)vd[e];
        } else {
            const int cb = (h - 64) * 24;
            f16x4 ka[5]; f16x8 va[5];
            #pragma unroll
            for (int t = 0; t < 5; ++t) {
                ka[t] = *(const f16x4*)(wr[t] + cb + 8 + d0);
                va[t] = *(const f16x8*)(wr[t] + cb + 16);
            }
            #pragma unroll
            for (int dd = 0; dd < 4; ++dd) {
                float s = 0.f;
                #pragma unroll
                for (int t = 0; t < 5; ++t) s = fmaf(wk[dd][t], (float)ka[t][dd], s);
                kv4[dd] = fmaxf(s, 0.f);
            }
            #pragma unroll
            for (int e = 0; e < 8; ++e) {
                float s = 0.f;
                #pragma unroll
                for (int t = 0; t < 5; ++t) s = fmaf(wv[e][t], (float)va[t][e], s);
                vv[e] = s;
            }
        }
        #pragma unroll
        for (int dd = 0; dd < 4; ++dd) {
            #pragma unroll
            for (int e = 0; e < 8; ++e)
                acc[dd * 9 + e] = fmaf(kv4[dd], vv[e], acc[dd * 9 + e]);
            acc[dd * 9 + 8] += kv4[dd];
        }

        if (tid < 128) {
            f16x8 qv;
            if (tid < 64) {
                qv = *(const f16x8*)(wr[2] + tid * 24);
                #pragma unroll
                for (int d = 0; d < 8; ++d)
                    qv[d] = qv[d] > (f16)0 ? qv[d] : (f16)0;
            } else {
                const int cb = (tid - 64) * 24;
                f16x8 qa[5];
                #pragma unroll
                for (int t = 0; t < 5; ++t) qa[t] = *(const f16x8*)(wr[t] + cb);
                #pragma unroll
                for (int d = 0; d < 8; ++d) {
                    float s = 0.f;
                    #pragma unroll
                    for (int t = 0; t < 5; ++t) s = fmaf(wq[d][t], (float)qa[t][d], s);
                    qv[d] = (f16)fmaxf(s, 0.f);
                }
            }
            *(f16x8*)(q_all + (size_t)n * 1024 + tid * 8) = qv;
        }

        __syncthreads();
        if (doPre)
            *(f16x8*)(&rows[(n + 3) % 5][tid * 8]) = pre;
        __syncthreads();
    }

    if (kv_part) {
        float* dst = kv_part + (size_t)blockIdx.x * 9216 + tid * 36;
        #pragma unroll
        for (int i = 0; i < 36; ++i) dst[i] = acc[i];
    } else {
        #pragma unroll
        for (int dd = 0; dd < 4; ++dd)
            #pragma unroll
            for (int e = 0; e < 9; ++e)
                atomicAdd(&kvg[h * 72 + (d0 + dd) * 9 + e], acc[dd * 9 + e]);
    }
}

// kvg[j] = sum_b kv_part[b][j], j in [0,9216). Grid: 36 x 256.
__global__ void kv_reduce_kernel(const float* __restrict__ kv_part,
                                 float* __restrict__ kvg)
{
    const int j = blockIdx.x * 256 + threadIdx.x;
    float s = 0.f;
    for (int b = 0; b < KV_BLOCKS; ++b)
        s += kv_part[(size_t)b * 9216 + j];
    kvg[j] = s;
}

// ---------------------------------------------------------------------------
// o[n, h*8+e] = (sum_d q*kv[h,d,e]) / (sum_d q*kv[h,d,8] + 1e-15)
// ---------------------------------------------------------------------------
__global__ __launch_bounds__(256)
void attn_o_kernel(const f16* __restrict__ q_all, const float* __restrict__ kvg,
                   f16* __restrict__ o)
{
    __shared__ float kvt[72][128];   // [d*9+e][h]
    const int tid = threadIdx.x;
    for (int i = tid; i < 9216; i += 256) {
        const int hh = i & 127, j = i >> 7;
        kvt[j][hh] = kvg[hh * 72 + j];
    }
    __syncthreads();
    const int h = tid & 127, sub = tid >> 7;
    for (int nb = blockIdx.x; nb < N_NODES / 2; nb += gridDim.x) {
        const int n = nb * 2 + sub;
        const f16x8 qv8 = *(const f16x8*)(q_all + (size_t)n * 1024 + h * 8);
        float q[8];
        #pragma unroll
        for (int d = 0; d < 8; ++d) q[d] = (float)qv8[d];
        float num[8], den = 0.f;
        #pragma unroll
        for (int e = 0; e < 8; ++e) {
            float s = 0.f;
            #pragma unroll
            for (int d = 0; d < 8; ++d) s = fmaf(q[d], kvt[d * 9 + e][h], s);
            num[e] = s;
        }
        #pragma unroll
        for (int d = 0; d < 8; ++d) den = fmaf(q[d], kvt[d * 9 + 8][h], den);
        const float rinv = 1.f / (den + 1e-15f);
        f16x8 ov;
        #pragma unroll
        for (int e = 0; e < 8; ++e) ov[e] = (f16)(num[e] * rinv);
        *(f16x8*)(o + (size_t)n * 1024 + h * 8) = ov;
    }
}

// ---------------------------------------------------------------------------
// out_h = f16(resid + LN(y)*g + b). resid f16. out_h may alias y.
// ---------------------------------------------------------------------------
__global__ void ln_res_kernel(const f16* __restrict__ y, const f16* __restrict__ resid,
                              const float* __restrict__ g, const float* __restrict__ b,
                              f16* __restrict__ out_h)
{
    const int row = blockIdx.x;
    const int tid = threadIdx.x;
    const f16* yr = y + (size_t)row * DMODEL;
    const float v0 = (float)yr[tid], v1 = (float)yr[tid + 256];
    __shared__ float red[4], red2[4];
    float s = v0 + v1;
    #pragma unroll
    for (int o = 32; o > 0; o >>= 1) s += __shfl_down(s, o);
    if ((tid & 63) == 0) red[tid >> 6] = s;
    __syncthreads();
    const float mean = (red[0] + red[1] + red[2] + red[3]) * (1.0f / DMODEL);
    const float d0 = v0 - mean, d1 = v1 - mean;
    float q = d0 * d0 + d1 * d1;
    #pragma unroll
    for (int o = 32; o > 0; o >>= 1) q += __shfl_down(q, o);
    if ((tid & 63) == 0) red2[tid >> 6] = q;
    __syncthreads();
    const float var = (red2[0] + red2[1] + red2[2] + red2[3]) * (1.0f / DMODEL);
    const float inv = rsqrtf(var + 1e-5f);
    const f16* rr = resid + (size_t)row * DMODEL;
    const float o0 = (float)rr[tid]       + d0 * inv * g[tid]       + b[tid];
    const float o1 = (float)rr[tid + 256] + d1 * inv * g[tid + 256] + b[tid + 256];
    f16* oh = out_h + (size_t)row * DMODEL;
    oh[tid] = (f16)o0;
    oh[tid + 256] = (f16)o1;
}

// ---------------------------------------------------------------------------
// Graph normalization + counting sort
// ---------------------------------------------------------------------------
__global__ void deg_init_kernel(float* __restrict__ deg)
{
    const int i = blockIdx.x * 256 + threadIdx.x;
    if (i < N_NODES) deg[i] = 1.0f;
}

__global__ void deg_acc_kernel(const int* __restrict__ eirow, const float* __restrict__ ea,
                               float* __restrict__ deg)
{
    const int e = blockIdx.x * 256 + threadIdx.x;
    if (e < N_EDGES) atomicAdd(&deg[eirow[e]], ea[e]);
}

__global__ void dis_kernel(const float* __restrict__ deg, float* __restrict__ dis)
{
    const int i = blockIdx.x * 256 + threadIdx.x;
    if (i < N_NODES) dis[i] = rsqrtf(deg[i]);
}

__global__ void count_kernel(const int* __restrict__ eirow, int* __restrict__ cnt)
{
    const int e = blockIdx.x * 256 + threadIdx.x;
    if (e < N_EDGES) atomicAdd(&cnt[eirow[e]], 1);
}

__global__ void scan_kernel(const int* __restrict__ cnt, int* __restrict__ rowstart,
                            int* __restrict__ cursor)
{
    __shared__ int ls[1024];
    const int tid = threadIdx.x;
    const int base = tid * 20;
    int local[20];
    int s = 0;
    #pragma unroll
    for (int i = 0; i < 20; ++i) {
        const int idx = base + i;
        const int v = (idx < N_NODES) ? cnt[idx] : 0;
        local[i] = s;
        s += v;
    }
    ls[tid] = s;
    __syncthreads();
    for (int off = 1; off < 1024; off <<= 1) {
        const int v = (tid >= off) ? ls[tid - off] : 0;
        __syncthreads();
        ls[tid] += v;
        __syncthreads();
    }
    const int excl = (tid == 0) ? 0 : ls[tid - 1];
    #pragma unroll
    for (int i = 0; i < 20; ++i) {
        const int idx = base + i;
        if (idx < N_NODES) {
            const int st = excl + local[i];
            rowstart[idx] = st;
            cursor[idx] = st;
        }
    }
    if (tid == 1023) rowstart[N_NODES] = ls[1023];
}

__global__ void scatter_kernel(const int* __restrict__ eirow, int* __restrict__ cursor,
                               int* __restrict__ sorted)
{
    const int e = blockIdx.x * 256 + threadIdx.x;
    if (e < N_EDGES) {
        const int r = eirow[e];
        const int p = atomicAdd(&cursor[r], 1);
        sorted[p] = e;
    }
}

// ---------------------------------------------------------------------------
// Aggregation v3 (unchanged): LDS metadata prefetch + 4-wave row gathers.
// ---------------------------------------------------------------------------
__global__ __launch_bounds__(256)
void agg_kernel(const f16* __restrict__ srcf_h, const int* __restrict__ eicol,
                const float* __restrict__ ea, const float* __restrict__ dis,
                const int* __restrict__ rowstart, const int* __restrict__ sorted,
                f16* __restrict__ agg)
{
    __shared__ int   cbuf[256];
    __shared__ float wbuf[256];
    __shared__ float part[4][512];
    const int i = blockIdx.x;
    const int tid = threadIdx.x;
    const int lane = tid & 63, wv = tid >> 6;
    const float di = dis[i];
    const int s = rowstart[i];
    const int deg = rowstart[i + 1] - s;

    float acc[8] = {};
    for (int base = 0; base < deg; base += 256) {
        const int m = min(256, deg - base);
        if (tid < m) {
            const int e = sorted[s + base + tid];
            const int c = eicol[e];
            cbuf[tid] = c;
            wbuf[tid] = di * ea[e] * dis[c];
        }
        __syncthreads();
        #pragma unroll 2
        for (int p = wv; p < m; p += 4) {
            const int c = cbuf[p];
            const float w = wbuf[p];
            const f16x8 v = *(const f16x8*)(srcf_h + (size_t)c * DMODEL + lane * 8);
            #pragma unroll
            for (int j = 0; j < 8; ++j) acc[j] = fmaf(w, (float)v[j], acc[j]);
        }
        __syncthreads();
    }
    #pragma unroll
    for (int j = 0; j < 8; ++j) part[wv][lane * 8 + j] = acc[j];
    __syncthreads();
    const float wself = di * di;
    const f16x2 vs = *(const f16x2*)(srcf_h + (size_t)i * DMODEL + tid * 2);
    float a0 = wself * (float)vs[0], a1 = wself * (float)vs[1];
    #pragma unroll
    for (int w = 0; w < 4; ++w) {
        a0 += part[w][tid * 2];
        a1 += part[w][tid * 2 + 1];
    }
    f16x2 o;
    o[0] = (f16)fmaxf(a0, 0.f);
    o[1] = (f16)fmaxf(a1, 0.f);
    *(f16x2*)(agg + (size_t)i * DMODEL + tid * 2) = o;
}

// ---------------------------------------------------------------------------
// Workspace layout (bytes) — unchanged from round 12-14.
// ---------------------------------------------------------------------------
static constexpr size_t OFF_HH    = 0;              // f16 20,480,000
static constexpr size_t OFF_FF    = 20480000ull;    // f16 20,480,000
static constexpr size_t OFF_QKV   = 40960000ull;    // f16 61,440,000
static constexpr size_t OFF_SRC2  = 40960000ull;    // f16 20,480,000 (alias)
static constexpr size_t OFF_FFH   = 61440000ull;    // f16 81,920,000 (alias)
static constexpr size_t OFF_AGG   = 61440000ull;    // f16 40,960,000 (alias)
static constexpr size_t OFF_XH    = 102400000ull;   // f16 10,240,000
static constexpr size_t OFF_ATTN  = 102400000ull;   // f16 40,960,000 (alias)
static constexpr size_t WT_IN     = 143360000ull;
static constexpr size_t WT_QKV    = 143622144ull;
static constexpr size_t WT_PROJ   = 145195008ull;
static constexpr size_t WT_W1     = 146243584ull;
static constexpr size_t WT_W2     = 148340736ull;
static constexpr size_t WT_OUT    = 150437888ull;
static constexpr size_t OFF_KV    = 150568960ull;
static constexpr size_t OFF_DEG   = 150605824ull;
static constexpr size_t OFF_DIS   = 150685824ull;
static constexpr size_t OFF_RS    = 150765824ull;
static constexpr size_t OFF_CUR   = 150845888ull;
static constexpr size_t OFF_CNT   = 150925888ull;
static constexpr size_t OFF_SORT  = 151005888ull;   // -> 152,285,888
static constexpr size_t OFF_KVP   = 152285888ull;   // -> 175,325,888
static constexpr size_t WS_NEED_KVP = 175325888ull;

extern "C" void kernel_launch(void* const* d_in, const int* in_sizes, int n_in,
                              void* d_out, int out_size, void* d_ws, size_t ws_size,
                              hipStream_t stream)
{
    const float* x      = (const float*)d_in[0];
    const int*   ei     = (const int*)d_in[1];
    const float* ea     = (const float*)d_in[2];
    const float* pe     = (const float*)d_in[4];
    const float* W_in   = (const float*)d_in[5];
    const float* b_in   = (const float*)d_in[6];
    const float* W_qkv  = (const float*)d_in[7];
    const float* conv_w = (const float*)d_in[8];
    const float* W_proj = (const float*)d_in[9];
    const float* b_proj = (const float*)d_in[10];
    const float* g1     = (const float*)d_in[11];
    const float* beta1  = (const float*)d_in[12];
    const float* W1     = (const float*)d_in[13];
    const float* bf1    = (const float*)d_in[14];
    const float* W2     = (const float*)d_in[15];
    const float* bf2    = (const float*)d_in[16];
    const float* g2     = (const float*)d_in[17];
    const float* beta2  = (const float*)d_in[18];
    const float* W_out  = (const float*)d_in[19];
    const float* b_out  = (const float*)d_in[20];

    char* ws = (char*)d_ws;
    f16*   h_h    = (f16*)(ws + OFF_HH);
    f16*   ff     = (f16*)(ws + OFF_FF);
    f16*   qkv    = (f16*)(ws + OFF_QKV);
    f16*   src2   = (f16*)(ws + OFF_SRC2);
    f16*   ffh    = (f16*)(ws + OFF_FFH);
    f16*   agg    = (f16*)(ws + OFF_AGG);
    f16*   x_h    = (f16*)(ws + OFF_XH);
    f16*   q_all  = (f16*)(ws + OFF_ATTN);
    f16*   wt_in   = (f16*)(ws + WT_IN);
    f16*   wt_qkv  = (f16*)(ws + WT_QKV);
    f16*   wt_proj = (f16*)(ws + WT_PROJ);
    f16*   wt_w1   = (f16*)(ws + WT_W1);
    f16*   wt_w2   = (f16*)(ws + WT_W2);
    f16*   wt_out  = (f16*)(ws + WT_OUT);
    float* kvg    = (float*)(ws + OFF_KV);
    float* deg    = (float*)(ws + OFF_DEG);
    float* dis    = (float*)(ws + OFF_DIS);
    int*   rs     = (int*)(ws + OFF_RS);
    int*   cur    = (int*)(ws + OFF_CUR);
    int*   cnt    = (int*)(ws + OFF_CNT);
    int*   sorted = (int*)(ws + OFF_SORT);
    float* outp   = (float*)d_out;

    const bool twoStage = (ws_size >= WS_NEED_KVP);
    float* kv_part = twoStage ? (float*)(ws + OFF_KVP) : nullptr;

    const int* eirow = ei;
    const int* eicol = ei + N_EDGES;

    if (!twoStage)
        hipMemsetAsync(kvg, 0, 9216 * sizeof(float), stream);
    hipMemsetAsync(cnt, 0, N_NODES * sizeof(int), stream);

    // 0. weight transpose+convert (f32 [K][N] -> f16 [N][K])
    wt_kernel<<<dim3(DIN / 32,   DMODEL / 32), 256, 0, stream>>>(W_in,   wt_in,   DIN,    DMODEL);
    wt_kernel<<<dim3(DMODEL / 32, TD / 32),    256, 0, stream>>>(W_qkv,  wt_qkv,  DMODEL, TD);
    wt_kernel<<<dim3(1024 / 32,  DMODEL / 32), 256, 0, stream>>>(W_proj, wt_proj, 1024,   DMODEL);
    wt_kernel<<<dim3(DMODEL / 32, FFD / 32),   256, 0, stream>>>(W1,     wt_w1,   DMODEL, FFD);
    wt_kernel<<<dim3(FFD / 32,   DMODEL / 32), 256, 0, stream>>>(W2,     wt_w2,   FFD,    DMODEL);
    wt_kernel<<<dim3(DMODEL / 32, DOUT / 32),  256, 0, stream>>>(W_out,  wt_out,  DMODEL, DOUT);
    // 0b. x -> f16
    f2h_kernel<<<(N_NODES * DIN) / 1024, 256, 0, stream>>>(x, x_h, N_NODES * DIN);

    const int MT = (N_NODES + 127) / 128;   // 157

    // 1. h_h = f16(x@W_in + b_in + pe)
    gemm_mfma<f16, 1, 1, 0><<<MT * (DMODEL / 128), 256, 0, stream>>>(
        x_h, wt_in, b_in, pe, h_h, N_NODES, DMODEL, DIN);
    // 2. qkv = h_h@W_qkv (f16)
    gemm_mfma<f16, 0, 0, 0><<<MT * (TD / 128), 256, 0, stream>>>(
        h_h, wt_qkv, nullptr, nullptr, qkv, N_NODES, TD, DMODEL);
    // 3. fused conv + kv partials + q materialization
    kv_fused_kernel<<<KV_BLOCKS, 256, 0, stream>>>(qkv, conv_w, q_all, kvg, kv_part);
    if (twoStage)
        kv_reduce_kernel<<<36, 256, 0, stream>>>(kv_part, kvg);
    // 4. attention readout (in-place over q_all)
    attn_o_kernel<<<2500, 256, 0, stream>>>(q_all, kvg, q_all);
    // 5. src2 = attn_o@W_proj + b_proj (f16)
    gemm_mfma<f16, 1, 0, 0><<<MT * (DMODEL / 128), 256, 0, stream>>>(
        q_all, wt_proj, b_proj, nullptr, src2, N_NODES, DMODEL, 1024);
    // 6. src2 = f16(h_h + LN(src2))  (in-place)
    ln_res_kernel<<<N_NODES, 256, 0, stream>>>(src2, h_h, g1, beta1, src2);
    // 7. ffh = relu(src2@W1 + bf1) (f16)
    gemm_mfma<f16, 1, 0, 1><<<MT * (FFD / 128), 256, 0, stream>>>(
        src2, wt_w1, bf1, nullptr, ffh, N_NODES, FFD, DMODEL);
    // 8. ff = ffh@W2 + bf2 (f16)
    gemm_mfma<f16, 1, 0, 0><<<MT * (DMODEL / 128), 256, 0, stream>>>(
        ffh, wt_w2, bf2, nullptr, ff, N_NODES, DMODEL, FFD);
    // 9. ff = f16(src2 + LN(ff))  (in-place; agg gather source)
    ln_res_kernel<<<N_NODES, 256, 0, stream>>>(ff, src2, g2, beta2, ff);
    // 10. degree / normalization
    deg_init_kernel<<<(N_NODES + 255) / 256, 256, 0, stream>>>(deg);
    deg_acc_kernel<<<(N_EDGES + 255) / 256, 256, 0, stream>>>(eirow, ea, deg);
    dis_kernel<<<(N_NODES + 255) / 256, 256, 0, stream>>>(deg, dis);
    // 11. counting sort of edges by destination row
    count_kernel<<<(N_EDGES + 255) / 256, 256, 0, stream>>>(eirow, cnt);
    scan_kernel<<<1, 1024, 0, stream>>>(cnt, rs, cur);
    scatter_kernel<<<(N_EDGES + 255) / 256, 256, 0, stream>>>(eirow, cur, sorted);
    // 12. aggregation
    agg_kernel<<<N_NODES, 256, 0, stream>>>(ff, eicol, ea, dis, rs, sorted, agg);
    // 13. out = relu(agg)@W_out + b_out (f32)
    gemm_mfma<float, 1, 0, 0><<<MT * (DOUT / 128), 256, 0, stream>>>(
        agg, wt_out, b_out, nullptr, outp, N_NODES, DOUT, DMODEL);
}